// Round 1
// baseline (5974.663 us; speedup 1.0000x reference)
//
#include <hip/hip_runtime.h>

// ---------------- problem constants ----------------
// B=32, T=250, FEAT=128, CLASSES=25, UNITS=512, CELL=64, HEADS=4, IN_LSTM=409

// ---------------- scratch layout (floats) ----------------
constexpr size_t OFF_FEATP  = 0;                              // [8000][128]
constexpr size_t OFF_WXI    = OFF_FEATP + (size_t)8000 * 128; // [409][2048] gate-interleaved
constexpr size_t OFF_WHI    = OFF_WXI + (size_t)409 * 2048;   // [512][2048]
constexpr size_t OFF_BLI    = OFF_WHI + (size_t)512 * 2048;   // [2048]
constexpr size_t OFF_ZP0    = OFF_BLI + 2048;                 // [2][32][2048] parity
constexpr size_t OFF_ZP1    = OFF_ZP0 + 131072;               // [2][32][2048]
constexpr size_t OFF_OH0    = OFF_ZP1 + 131072;               // [2][32][512]
constexpr size_t OFF_OH1    = OFF_OH0 + 32768;                // [2][32][512]
constexpr size_t OFF_HP0    = OFF_OH1 + 32768;                // [32][320]
constexpr size_t OFF_HP1    = OFF_HP0 + 10240;                // [32][320]
constexpr size_t OFF_OUTPRE = OFF_HP1 + 10240;                // [32][512]
constexpr size_t OFF_HT     = OFF_OUTPRE + 16384;             // [2][512][32] parity
constexpr size_t OFF_RVT    = OFF_HT + 32768;                 // [2][256][32] parity
constexpr size_t OFF_BAR    = OFF_RVT + 16384;                // tag region (4096 ints)
constexpr size_t WS_FLOATS  = OFF_BAR + 4096;

constexpr int DYN_FLOATS = 34816;                 // 136 KB dynamic LDS
constexpr int DYN_BYTES  = DYN_FLOATS * 4;

// ---- per-producer monotonic tags (ints). Tag i of group G lives at
// G + (i>>2)*16 + (i&3): 4 tags per 64B line, so a min-scan over 4k tags is
// k batched dwordx4 loads. Single writer per slot -> plain sc store, no RMW.
constexpr int TG_HT = 0;     // 64: AZ bid   -> t+1 after azGates(t)  (HT_t + reads done)
constexpr int TG_Z0 = 256;   // 64: BL j     -> s+1 after ZP0_s slice (+ HT_{s-1} reads done)
constexpr int TG_Z1 = 512;   // 32: BH j     -> s+1
constexpr int TG_OH = 640;   // 32: OL k=0..15 / OHI 16+k -> t+1 after OH_t slice
constexpr int TG_HP = 768;   // 16: PL 0..9 / PHI 10..14 -> t+1 after HP slice; 15 = pad(INT_MAX)
constexpr int TG_OP = 832;   // 16: AO k     -> t after aoOut(t)  (OUTPRE_t + rv/OH reads done)
constexpr int TG_RV = 896;   // 32: CA b     -> t+1 after caAtt(t) (RVT_t + HP reads done)
constexpr int TG_CO = 1024;  // 32: CA b     -> t after caOut(t)  (OUTPRE reads done)

__device__ __forceinline__ float sigm(float x) { return 1.f / (1.f + __expf(-x)); }
__device__ __forceinline__ int imin2(int a, int b) { return a < b ? a : b; }

typedef int iv4 __attribute__((ext_vector_type(4)));
__device__ __forceinline__ int vmin_red(iv4 a) {
  return imin2(imin2(a[0], a[1]), imin2(a[2], a[3]));
}

// ---- LLC-coherent accesses (bypass L1+L2). Loads batched in asm with the
// waitcnt inside so they cannot be serialized into dependent round-trips.
__device__ __forceinline__ void st_sc(float* p, float v) {
  __hip_atomic_store(p, v, __ATOMIC_RELAXED, __HIP_MEMORY_SCOPE_AGENT);
}
__device__ __forceinline__ float ld_sc(const float* p) {
  return __hip_atomic_load(p, __ATOMIC_RELAXED, __HIP_MEMORY_SCOPE_AGENT);
}
__device__ __forceinline__ void st_tag(int* p, int v) {
  __hip_atomic_store(p, v, __ATOMIC_RELAXED, __HIP_MEMORY_SCOPE_AGENT);
}
__device__ __forceinline__ int ld_tag(const int* p) {
  return __hip_atomic_load(p, __ATOMIC_RELAXED, __HIP_MEMORY_SCOPE_AGENT);
}
__device__ __forceinline__ void ld8x2_sc(const double* b0, double* v) {
  const double *p0 = b0, *p1 = b0 + 512, *p2 = b0 + 1024, *p3 = b0 + 1536,
               *p4 = b0 + 2048, *p5 = b0 + 2560, *p6 = b0 + 3072, *p7 = b0 + 3584;
  asm volatile(
      "global_load_dwordx2 %0, %8, off sc0 sc1\n\t"
      "global_load_dwordx2 %1, %9, off sc0 sc1\n\t"
      "global_load_dwordx2 %2, %10, off sc0 sc1\n\t"
      "global_load_dwordx2 %3, %11, off sc0 sc1\n\t"
      "global_load_dwordx2 %4, %12, off sc0 sc1\n\t"
      "global_load_dwordx2 %5, %13, off sc0 sc1\n\t"
      "global_load_dwordx2 %6, %14, off sc0 sc1\n\t"
      "global_load_dwordx2 %7, %15, off sc0 sc1\n\t"
      "s_waitcnt vmcnt(0)"
      : "=&v"(v[0]), "=&v"(v[1]), "=&v"(v[2]), "=&v"(v[3]),
        "=&v"(v[4]), "=&v"(v[5]), "=&v"(v[6]), "=&v"(v[7])
      : "v"(p0), "v"(p1), "v"(p2), "v"(p3), "v"(p4), "v"(p5), "v"(p6), "v"(p7)
      : "memory");
}
// 8 rv loads + 2 partial loads, one waitcnt (AO staging)
__device__ __forceinline__ void ld10x2_sc(const double* b0, const double* z0,
                                          const double* z1, double* v) {
  const double *p0 = b0, *p1 = b0 + 512, *p2 = b0 + 1024, *p3 = b0 + 1536,
               *p4 = b0 + 2048, *p5 = b0 + 2560, *p6 = b0 + 3072, *p7 = b0 + 3584;
  asm volatile(
      "global_load_dwordx2 %0, %10, off sc0 sc1\n\t"
      "global_load_dwordx2 %1, %11, off sc0 sc1\n\t"
      "global_load_dwordx2 %2, %12, off sc0 sc1\n\t"
      "global_load_dwordx2 %3, %13, off sc0 sc1\n\t"
      "global_load_dwordx2 %4, %14, off sc0 sc1\n\t"
      "global_load_dwordx2 %5, %15, off sc0 sc1\n\t"
      "global_load_dwordx2 %6, %16, off sc0 sc1\n\t"
      "global_load_dwordx2 %7, %17, off sc0 sc1\n\t"
      "global_load_dwordx2 %8, %18, off sc0 sc1\n\t"
      "global_load_dwordx2 %9, %19, off sc0 sc1\n\t"
      "s_waitcnt vmcnt(0)"
      : "=&v"(v[0]), "=&v"(v[1]), "=&v"(v[2]), "=&v"(v[3]), "=&v"(v[4]),
        "=&v"(v[5]), "=&v"(v[6]), "=&v"(v[7]), "=&v"(v[8]), "=&v"(v[9])
      : "v"(p0), "v"(p1), "v"(p2), "v"(p3), "v"(p4), "v"(p5), "v"(p6), "v"(p7),
        "v"(z0), "v"(z1)
      : "memory");
}
__device__ __forceinline__ void ldpair_sc(const float* a, const float* b,
                                          float& x, float& y) {
  asm volatile(
      "global_load_dword %0, %2, off sc0 sc1\n\t"
      "global_load_dword %1, %3, off sc0 sc1\n\t"
      "s_waitcnt vmcnt(0)"
      : "=&v"(x), "=&v"(y) : "v"(a), "v"(b) : "memory");
}
__device__ __forceinline__ void ldpair64_sc(const double* a, const double* b,
                                            double& x, double& y) {
  asm volatile(
      "global_load_dwordx2 %0, %2, off sc0 sc1\n\t"
      "global_load_dwordx2 %1, %3, off sc0 sc1\n\t"
      "s_waitcnt vmcnt(0)"
      : "=&v"(x), "=&v"(y) : "v"(a), "v"(b) : "memory");
}
__device__ __forceinline__ void ldpair_int_sc(const int* a, const int* b,
                                              int& x, int& y) {
  asm volatile(
      "global_load_dword %0, %2, off sc0 sc1\n\t"
      "global_load_dword %1, %3, off sc0 sc1\n\t"
      "s_waitcnt vmcnt(0)"
      : "=&v"(x), "=&v"(y) : "v"(a), "v"(b) : "memory");
}
// min over 16 tags (4 lines), one batched round trip
__device__ __forceinline__ int min16_tags(const int* b) {
  iv4 a0, a1, a2, a3;
  asm volatile(
      "global_load_dwordx4 %0, %4, off sc0 sc1\n\t"
      "global_load_dwordx4 %1, %4, off offset:64 sc0 sc1\n\t"
      "global_load_dwordx4 %2, %4, off offset:128 sc0 sc1\n\t"
      "global_load_dwordx4 %3, %4, off offset:192 sc0 sc1\n\t"
      "s_waitcnt vmcnt(0)"
      : "=&v"(a0), "=&v"(a1), "=&v"(a2), "=&v"(a3)
      : "v"(b) : "memory");
  return imin2(imin2(vmin_red(a0), vmin_red(a1)),
               imin2(vmin_red(a2), vmin_red(a3)));
}
// min over 32 tags (8 lines), one batched round trip
__device__ __forceinline__ int min32_tags(const int* b) {
  iv4 a0, a1, a2, a3, a4, a5, a6, a7;
  asm volatile(
      "global_load_dwordx4 %0, %8, off sc0 sc1\n\t"
      "global_load_dwordx4 %1, %8, off offset:64 sc0 sc1\n\t"
      "global_load_dwordx4 %2, %8, off offset:128 sc0 sc1\n\t"
      "global_load_dwordx4 %3, %8, off offset:192 sc0 sc1\n\t"
      "global_load_dwordx4 %4, %8, off offset:256 sc0 sc1\n\t"
      "global_load_dwordx4 %5, %8, off offset:320 sc0 sc1\n\t"
      "global_load_dwordx4 %6, %8, off offset:384 sc0 sc1\n\t"
      "global_load_dwordx4 %7, %8, off offset:448 sc0 sc1\n\t"
      "s_waitcnt vmcnt(0)"
      : "=&v"(a0), "=&v"(a1), "=&v"(a2), "=&v"(a3),
        "=&v"(a4), "=&v"(a5), "=&v"(a6), "=&v"(a7)
      : "v"(b) : "memory");
  int m0 = imin2(imin2(vmin_red(a0), vmin_red(a1)),
                 imin2(vmin_red(a2), vmin_red(a3)));
  int m1 = imin2(imin2(vmin_red(a4), vmin_red(a5)),
                 imin2(vmin_red(a6), vmin_red(a7)));
  return imin2(m0, m1);
}

// ---------------- weight re-layout: gate-interleaved Wx/Wh/bl ----------------
__global__ __launch_bounds__(256) void prep_kernel(const float* __restrict__ Wx,
                                                   const float* __restrict__ Wh,
                                                   const float* __restrict__ bl,
                                                   float* __restrict__ ws) {
  float* WXI = ws + OFF_WXI;
  float* WHI = ws + OFF_WHI;
  float* BLI = ws + OFF_BLI;
  const int total = 409 * 2048 + 512 * 2048 + 2048;
  for (int idx = blockIdx.x * blockDim.x + threadIdx.x; idx < total;
       idx += gridDim.x * blockDim.x) {
    if (idx < 409 * 2048) {
      int k = idx >> 11, cc = idx & 2047;
      WXI[idx] = Wx[(size_t)k * 2048 + (cc & 3) * 512 + (cc >> 2)];
    } else if (idx < 409 * 2048 + 512 * 2048) {
      int j = idx - 409 * 2048;
      int k = j >> 11, cc = j & 2047;
      WHI[j] = Wh[(size_t)k * 2048 + (cc & 3) * 512 + (cc >> 2)];
    } else {
      int cc = idx - (409 * 2048 + 512 * 2048);
      BLI[cc] = bl[(cc & 3) * 512 + (cc >> 2)];
    }
  }
}

// ---------------- conv stack (validated) ----------------
__global__ __launch_bounds__(128) void conv_kernel(
    const float* __restrict__ img,
    const float* __restrict__ k1, const float* __restrict__ cb1, const float* __restrict__ g1,
    const float* __restrict__ be1, const float* __restrict__ mm1, const float* __restrict__ mv1,
    const float* __restrict__ k2, const float* __restrict__ cb2, const float* __restrict__ g2,
    const float* __restrict__ be2, const float* __restrict__ mm2, const float* __restrict__ mv2,
    const float* __restrict__ k3, const float* __restrict__ cb3, const float* __restrict__ g3,
    const float* __restrict__ be3, const float* __restrict__ mm3, const float* __restrict__ mv3,
    float* __restrict__ ws) {
  __shared__ float s_in[784];
  __shared__ float s_y1[13 * 13 * 8];
  __shared__ float s_y2[6 * 6 * 16];
  __shared__ float s_k1[72], s_k2[1152], s_k3[4608];
  __shared__ float s_s1[8], s_b1[8], s_s2[16], s_b2[16], s_s3[32], s_b3[32];
  float* FEATP = ws + OFF_FEATP;
  const int n = blockIdx.x, tid = threadIdx.x;
  const float* ip = img + (size_t)n * 784;
  for (int i = tid; i < 784; i += 128) s_in[i] = ip[i];
  for (int i = tid; i < 72; i += 128) s_k1[i] = k1[i];
  for (int i = tid; i < 1152; i += 128) s_k2[i] = k2[i];
  for (int i = tid; i < 4608; i += 128) s_k3[i] = k3[i];
  if (tid < 8) {
    float s = g1[tid] * rsqrtf(mv1[tid] + 1e-3f);
    s_s1[tid] = s; s_b1[tid] = (cb1[tid] - mm1[tid]) * s + be1[tid];
  } else if (tid >= 32 && tid < 48) {
    int c = tid - 32;
    float s = g2[c] * rsqrtf(mv2[c] + 1e-3f);
    s_s2[c] = s; s_b2[c] = (cb2[c] - mm2[c]) * s + be2[c];
  } else if (tid >= 64 && tid < 96) {
    int c = tid - 64;
    float s = g3[c] * rsqrtf(mv3[c] + 1e-3f);
    s_s3[c] = s; s_b3[c] = (cb3[c] - mm3[c]) * s + be3[c];
  }
  __syncthreads();
  for (int idx = tid; idx < 13 * 13 * 8; idx += 128) {
    int co = idx & 7, pos = idx >> 3;
    int j = pos % 13, i = pos / 13;
    float acc = 0.f;
    #pragma unroll
    for (int ky = 0; ky < 3; ++ky)
      #pragma unroll
      for (int kx = 0; kx < 3; ++kx)
        acc += s_in[(2 * i + ky) * 28 + (2 * j + kx)] * s_k1[(ky * 3 + kx) * 8 + co];
    float v = acc * s_s1[co] + s_b1[co];
    s_y1[idx] = v > 0.f ? v : 0.f;
  }
  __syncthreads();
  for (int idx = tid; idx < 6 * 6 * 16; idx += 128) {
    int co = idx & 15, pos = idx >> 4;
    int j = pos % 6, i = pos / 6;
    float acc = 0.f;
    for (int ky = 0; ky < 3; ++ky)
      for (int kx = 0; kx < 3; ++kx) {
        int base = ((2 * i + ky) * 13 + (2 * j + kx)) * 8;
        int kb = (ky * 3 + kx) * 128 + co;
        #pragma unroll
        for (int ci = 0; ci < 8; ++ci) acc += s_y1[base + ci] * s_k2[kb + ci * 16];
      }
    float v = acc * s_s2[co] + s_b2[co];
    s_y2[idx] = v > 0.f ? v : 0.f;
  }
  __syncthreads();
  for (int idx = tid; idx < 128; idx += 128) {
    int co = idx & 31, pos = idx >> 5;
    int j = pos & 1, i = pos >> 1;
    float acc = 0.f;
    for (int ky = 0; ky < 3; ++ky)
      for (int kx = 0; kx < 3; ++kx) {
        int base = ((2 * i + ky) * 6 + (2 * j + kx)) * 16;
        int kb = (ky * 3 + kx) * 512 + co;
        #pragma unroll
        for (int ci = 0; ci < 16; ++ci) acc += s_y2[base + ci] * s_k3[kb + ci * 32];
      }
    float v = acc * s_s3[co] + s_b3[co];
    FEATP[(size_t)n * 128 + idx] = v > 0.f ? v : 0.f;
  }
}

// ---------------- persistent LSTM scan: fine-grained per-producer tags ----------------
// RAW waits are per-slice (AZ: exactly 2 producer tags; AO: own 2 OH tags);
// WAR waits carry 1-2 steps of slack and are cached in registers.
__global__ __launch_bounds__(512) void lstm_kernel(
    const int* __restrict__ labels,
    const float* __restrict__ Wo, const float* __restrict__ bo,
    const float* __restrict__ Wp, const float* __restrict__ bp,
    const float* __restrict__ Wf, const float* __restrict__ bf,
    float* __restrict__ ws, float* __restrict__ out) {
  extern __shared__ float dyn[];
  const float* FEATP = ws + OFF_FEATP;
  const float* WXI   = ws + OFF_WXI;
  const float* WHI   = ws + OFF_WHI;
  const float* BLI   = ws + OFF_BLI;
  float* ZP0    = ws + OFF_ZP0;     // [2][32][2048]
  float* ZP1    = ws + OFF_ZP1;
  float* OH0    = ws + OFF_OH0;     // [2][32][512]
  float* OH1    = ws + OFF_OH1;
  float* HP0    = ws + OFF_HP0;
  float* HP1    = ws + OFF_HP1;
  float* OUTPRE = ws + OFF_OUTPRE;
  float* HT     = ws + OFF_HT;      // [2][512][32]
  float* RVT    = ws + OFF_RVT;     // [2][256][32]
  int*   TAGS   = (int*)(ws + OFF_BAR);

  const int bid = blockIdx.x;
  const int tid = threadIdx.x;

  auto tagAddr = [&](int grp, int i) -> int* {
    return TAGS + grp + ((i >> 2) << 4) + (i & 3);
  };
  // publish: drain this block's data stores, then single-writer tag store
  auto pub = [&](int grp, int i, int val) {
    asm volatile("s_waitcnt vmcnt(0)" ::: "memory");
    __syncthreads();
    if (tid == 0) st_tag(tagAddr(grp, i), val);
  };

  // stage 8192-float [256][32] coherent buffer into [256][36]-padded LDS tile
  auto stage_act = [&](float* dst, const float* src) {
    double v[8];
    ld8x2_sc((const double*)src + tid, v);
    #pragma unroll
    for (int j = 0; j < 8; ++j) {
      int i = (tid + j * 512) << 1;
      *(double*)&dst[(i >> 5) * 36 + (i & 31)] = v[j];
    }
  };

  // ---- E32: Y[32c][32b] (R6-validated). K mult of 16.
  auto E32 = [&](const float* Wm, const float* Am, int K, float* part, float2& r) {
    const int wv = tid >> 6, l = tid & 63;
    const int ksub = l & 1, cg = (l >> 1) & 3, bg = l >> 3;
    const int Kp = K >> 4;
    const int kb = wv * (K >> 3) + ksub * Kp;
    const float* wp = Wm + (size_t)kb * 32 + cg * 8;
    const float* ap = Am + (size_t)kb * 36 + bg * 4;
    float4 acc[8];
    #pragma unroll
    for (int i = 0; i < 8; ++i) acc[i] = {0.f, 0.f, 0.f, 0.f};
    #pragma unroll 4
    for (int kk = 0; kk < Kp; ++kk) {
      float4 w0 = *(const float4*)(wp + kk * 32);
      float4 w1 = *(const float4*)(wp + kk * 32 + 4);
      float4 a  = *(const float4*)(ap + kk * 36);
      float wl[8];
      *(float4*)&wl[0] = w0; *(float4*)&wl[4] = w1;
      #pragma unroll
      for (int i = 0; i < 8; ++i) {
        acc[i].x = fmaf(wl[i], a.x, acc[i].x);
        acc[i].y = fmaf(wl[i], a.y, acc[i].y);
        acc[i].z = fmaf(wl[i], a.z, acc[i].z);
        acc[i].w = fmaf(wl[i], a.w, acc[i].w);
      }
    }
    #pragma unroll
    for (int i = 0; i < 8; ++i) {
      acc[i].x += __shfl_xor(acc[i].x, 1, 64);
      acc[i].y += __shfl_xor(acc[i].y, 1, 64);
      acc[i].z += __shfl_xor(acc[i].z, 1, 64);
      acc[i].w += __shfl_xor(acc[i].w, 1, 64);
    }
    const int ob = (cg * 8) * 36 + bg * 4;
    if (ksub == 0 && wv < 4) {
      float* pb = part + wv * 1152 + ob;
      #pragma unroll
      for (int i = 0; i < 8; ++i) *(float4*)(pb + i * 36) = acc[i];
    }
    __syncthreads();
    if (ksub == 0 && wv >= 4) {
      float* pb = part + (wv - 4) * 1152 + ob;
      #pragma unroll
      for (int i = 0; i < 8; ++i) {
        float4 t = *(float4*)(pb + i * 36);
        t.x += acc[i].x; t.y += acc[i].y; t.z += acc[i].z; t.w += acc[i].w;
        *(float4*)(pb + i * 36) = t;
      }
    }
    __syncthreads();
    const int c = tid & 31, b2 = (tid >> 5) * 2;
    const int o = c * 36 + b2;
    float2 s0 = *(float2*)(part + o);
    float2 s1 = *(float2*)(part + 1152 + o);
    float2 s2 = *(float2*)(part + 2304 + o);
    float2 s3 = *(float2*)(part + 3456 + o);
    r.x = (s0.x + s1.x) + (s2.x + s3.x);
    r.y = (s0.y + s1.y) + (s2.y + s3.y);
  };

  // ---- E64: Y[64c][32b], K=256, rotated weight slab (R6-validated).
  auto E64 = [&](const float* Wm, const float* Am, float* part, float4& r) {
    const int wv = tid >> 6, l = tid & 63;
    const int ksub = l & 1, cg = (l >> 1) & 7, bg = l >> 4;
    const int kb = wv * 32 + ksub * 16;
    const float* wp0 = Wm + (size_t)kb * 64 + ((cg * 8 + ksub * 4) & 63);
    const float* wp1 = Wm + (size_t)kb * 64 + ((cg * 8 + 4 + ksub * 4) & 63);
    const float* ap = Am + (size_t)kb * 36 + bg * 8;
    float4 acc[8][2];
    #pragma unroll
    for (int i = 0; i < 8; ++i) { acc[i][0] = {0.f,0.f,0.f,0.f}; acc[i][1] = {0.f,0.f,0.f,0.f}; }
    #pragma unroll 2
    for (int kk = 0; kk < 16; ++kk) {
      float4 w0 = *(const float4*)(wp0 + kk * 64);
      float4 w1 = *(const float4*)(wp1 + kk * 64);
      float4 a0 = *(const float4*)(ap + kk * 36);
      float4 a1 = *(const float4*)(ap + kk * 36 + 4);
      float wl[8];
      *(float4*)&wl[0] = w0; *(float4*)&wl[4] = w1;
      #pragma unroll
      for (int i = 0; i < 8; ++i) {
        acc[i][0].x = fmaf(wl[i], a0.x, acc[i][0].x);
        acc[i][0].y = fmaf(wl[i], a0.y, acc[i][0].y);
        acc[i][0].z = fmaf(wl[i], a0.z, acc[i][0].z);
        acc[i][0].w = fmaf(wl[i], a0.w, acc[i][0].w);
        acc[i][1].x = fmaf(wl[i], a1.x, acc[i][1].x);
        acc[i][1].y = fmaf(wl[i], a1.y, acc[i][1].y);
        acc[i][1].z = fmaf(wl[i], a1.z, acc[i][1].z);
        acc[i][1].w = fmaf(wl[i], a1.w, acc[i][1].w);
      }
    }
    #pragma unroll
    for (int i = 0; i < 8; ++i) {
      #pragma unroll
      for (int j = 0; j < 2; ++j) {
        acc[i][j].x += __shfl_xor(acc[i][j].x, 1, 64);
        acc[i][j].y += __shfl_xor(acc[i][j].y, 1, 64);
        acc[i][j].z += __shfl_xor(acc[i][j].z, 1, 64);
        acc[i][j].w += __shfl_xor(acc[i][j].w, 1, 64);
      }
    }
    const int ob = (cg * 8) * 36 + bg * 8;
    if (ksub == 0 && wv < 4) {
      float* pb = part + wv * 2304 + ob;
      #pragma unroll
      for (int i = 0; i < 8; ++i) {
        *(float4*)(pb + i * 36) = acc[i][0];
        *(float4*)(pb + i * 36 + 4) = acc[i][1];
      }
    }
    __syncthreads();
    if (ksub == 0 && wv >= 4) {
      float* pb = part + (wv - 4) * 2304 + ob;
      #pragma unroll
      for (int i = 0; i < 8; ++i) {
        float4 t0 = *(float4*)(pb + i * 36);
        float4 t1 = *(float4*)(pb + i * 36 + 4);
        t0.x += acc[i][0].x; t0.y += acc[i][0].y; t0.z += acc[i][0].z; t0.w += acc[i][0].w;
        t1.x += acc[i][1].x; t1.y += acc[i][1].y; t1.z += acc[i][1].z; t1.w += acc[i][1].w;
        *(float4*)(pb + i * 36) = t0;
        *(float4*)(pb + i * 36 + 4) = t1;
      }
    }
    __syncthreads();
    const int c = tid & 63, b4 = (tid >> 6) * 4;
    const int o = c * 36 + b4;
    float4 s0 = *(float4*)(part + o);
    float4 s1 = *(float4*)(part + 2304 + o);
    float4 s2 = *(float4*)(part + 4608 + o);
    float4 s3 = *(float4*)(part + 6912 + o);
    r.x = (s0.x + s1.x) + (s2.x + s3.x);
    r.y = (s0.y + s1.y) + (s2.y + s3.y);
    r.z = (s0.z + s1.z) + (s2.z + s3.z);
    r.w = (s0.w + s1.w) + (s2.w + s3.w);
  };

  // ---------------- one-time init: weights -> LDS ----------------
  if (bid < 64) {            // AZ
    const int c0 = bid * 32;
    for (int i = tid; i < 8192; i += 512)
      dyn[i] = WXI[(size_t)(153 + (i >> 5)) * 2048 + c0 + (i & 31)];
    for (int i = tid; i < 4096; i += 512)
      dyn[8192 + i] = WXI[(size_t)(i >> 5) * 2048 + c0 + (i & 31)];
    if (tid < 256) dyn[12288 + tid] = 0.f;  // Cst
  } else if (bid < 80) {     // AO
    const int u0 = (bid - 64) * 32;
    for (int i = tid; i < 8192; i += 512)
      dyn[i] = Wo[(size_t)(512 + (i >> 5)) * 512 + u0 + (i & 31)];
    if (tid < 32) dyn[8192 + tid] = bo[u0 + tid];
  } else if (bid < 144) {    // BL
    const int c0 = (bid - 80) * 32;
    for (int i = tid; i < 8192; i += 512)
      dyn[i] = WHI[(size_t)(i >> 5) * 2048 + c0 + (i & 31)];
    if (tid < 32) dyn[8192 + tid] = BLI[c0 + tid];
  } else if (bid < 176) {    // BH (rotated)
    const int c0 = (bid - 144) * 64;
    for (int i = tid; i < 16384; i += 512) {
      int k = i >> 6, c = i & 63;
      int cr = (c + ((k >> 4) & 1) * 4) & 63;
      dyn[k * 64 + cr] = WHI[(size_t)(256 + k) * 2048 + c0 + c];
    }
  } else if (bid < 192) {    // OL
    const int u0 = (bid - 176) * 32;
    for (int i = tid; i < 8192; i += 512)
      dyn[i] = Wo[(size_t)(i >> 5) * 512 + u0 + (i & 31)];
  } else if (bid < 208) {    // OHI
    const int u0 = (bid - 192) * 32;
    for (int i = tid; i < 8192; i += 512)
      dyn[i] = Wo[(size_t)(256 + (i >> 5)) * 512 + u0 + (i & 31)];
  } else if (bid < 218) {    // PL
    const int j0 = (bid - 208) * 32;
    for (int i = tid; i < 8192; i += 512)
      dyn[i] = Wp[(size_t)(i >> 5) * 320 + j0 + (i & 31)];
  } else if (bid < 223) {    // PHI (rotated)
    const int j0 = (bid - 218) * 64;
    for (int i = tid; i < 16384; i += 512) {
      int k = i >> 6, c = i & 63;
      int cr = (c + ((k >> 4) & 1) * 4) & 63;
      dyn[k * 64 + cr] = Wp[(size_t)(256 + k) * 320 + j0 + c];
    }
  } else if (bid < 255) {    // CA
    for (int i = tid; i < 17000; i += 512) dyn[i] = 0.f;       // ring[250][68]
    for (int i = tid; i < 12800; i += 512) dyn[17000 + i] = Wf[i];
    for (int i = tid; i < 320; i += 512) dyn[29800 + i] = bp[i];
    if (tid < 25) dyn[30120 + tid] = bf[tid];
  }
  __syncthreads();

  // ---------------- role bodies (parity-parameterized) ----------------
  // AZ dyn: Wz[0,8192) Wxx[8192,12288) Cst[12288,12544) rvT[12544,21760)
  //         xT[21760,26368) zx[26368,27392) zf[27392,28416) part[28416,33024)
  // zp partial load + zf staging (done while waiting for rv; own slice only)
  auto azPre = [&](int t) {
    const int c0 = bid * 32;
    const float* zp0S = ZP0 + (t & 1) * 65536;
    const float* zp1S = ZP1 + (t & 1) * 65536;
    float* zf = dyn + 27392;
    const int b = tid >> 4, c2 = tid & 15;
    double x, y;
    ldpair64_sc((const double*)(zp0S + (size_t)b * 2048 + c0) + c2,
                (const double*)(zp1S + (size_t)b * 2048 + c0) + c2, x, y);
    float2 f0 = *(float2*)&x, f1 = *(float2*)&y;
    float2 s = {f0.x + f1.x, f0.y + f1.y};
    *(double*)&zf[b * 32 + c2 * 2] = *(double*)&s;
  };
  auto azGatesMain = [&](int t) {
    const float* rvS = RVT + ((t + 1) & 1) * 8192;   // RVT_{t-1}
    float* htD = HT + (t & 1) * 16384;               // HT_t
    float* Wz = dyn; float* Cst = dyn + 12288; float* rvT = dyn + 12544;
    float* zx = dyn + 26368; float* zf = dyn + 27392; float* part = dyn + 28416;
    {
      double v[8];
      ld8x2_sc((const double*)rvS + tid, v);
      #pragma unroll
      for (int j = 0; j < 8; ++j) {
        int i = (tid + j * 512) << 1;
        *(double*)&rvT[(i >> 5) * 36 + (i & 31)] = v[j];
      }
    }
    __syncthreads();
    float2 r;
    E32(Wz, rvT, 256, part, r);
    const int c = tid & 31, b2 = (tid >> 5) * 2;
    zf[b2 * 32 + c] += r.x + zx[b2 * 32 + c];
    zf[(b2 + 1) * 32 + c] += r.y + zx[(b2 + 1) * 32 + c];
    __syncthreads();
    if (tid < 256) {
      int u = tid & 7, b = tid >> 3;
      float4 z = *(float4*)(zf + b * 32 + u * 4);
      float ig = sigm(z.x), fg = sigm(z.y), gg = tanhf(z.z), og = sigm(z.w);
      float cc = fg * Cst[b * 8 + u] + ig * gg;
      Cst[b * 8 + u] = cc;
      st_sc(&htD[(size_t)(bid * 8 + u) * 32 + b], og * tanhf(cc));
    }
  };
  auto azX = [&](int tt) {    // zx = x_{tt}@Wx, local
    float* Wxx = dyn + 8192; float* xT = dyn + 21760;
    float* zx = dyn + 26368; float* part = dyn + 28416;
    for (int i = tid; i < 4096; i += 512) {
      int b = i >> 7, k = i & 127;
      xT[k * 36 + b] = FEATP[((size_t)b * 250 + tt) * 128 + k];
    }
    __syncthreads();
    float2 r;
    E32(Wxx, xT, 128, part, r);
    const int c = tid & 31, b2 = (tid >> 5) * 2;
    zx[b2 * 32 + c] = r.x;
    zx[(b2 + 1) * 32 + c] = r.y;
  };
  // AO dyn: W[0,8192) bo[8192,8224) rvT[8224,17440) of[17440,18464) part[18464,23072)
  auto aoOut = [&](int t) {   // outpre_{t-1}: RVT_{t-1}, OH_{t-1}
    const int u0 = (bid - 64) * 32;
    const float* rvS  = RVT + ((t + 1) & 1) * 8192;
    const float* oh0S = OH0 + ((t + 1) & 1) * 16384;
    const float* oh1S = OH1 + ((t + 1) & 1) * 16384;
    float* W = dyn; float* bo_l = dyn + 8192; float* rvT = dyn + 8224;
    float* of = dyn + 17440; float* part = dyn + 18464;
    {
      const int b = tid >> 4, c2 = tid & 15;
      double v[10];
      ld10x2_sc((const double*)rvS + tid,
                (const double*)(oh0S + b * 512 + u0) + c2,
                (const double*)(oh1S + b * 512 + u0) + c2, v);
      #pragma unroll
      for (int j = 0; j < 8; ++j) {
        int i = (tid + j * 512) << 1;
        *(double*)&rvT[(i >> 5) * 36 + (i & 31)] = v[j];
      }
      float2 f0 = *(float2*)&v[8], f1 = *(float2*)&v[9];
      float2 s = {f0.x + f1.x, f0.y + f1.y};
      *(double*)&of[b * 32 + c2 * 2] = *(double*)&s;
    }
    __syncthreads();
    float2 r;
    E32(W, rvT, 256, part, r);
    const int c = tid & 31, b2 = (tid >> 5) * 2;
    float bv = bo_l[c];
    st_sc(&OUTPRE[b2 * 512 + u0 + c], r.x + of[b2 * 32 + c] + bv);
    st_sc(&OUTPRE[(b2 + 1) * 512 + u0 + c], r.y + of[(b2 + 1) * 32 + c] + bv);
  };
  // BL dyn: W[0,8192) blc[8192,8224) slab[8224,8256) A[8256,17472) part[17472,22080)
  auto blLoadLab = [&](int tt1) {
    __syncthreads();
    int* slab = (int*)(dyn + 8224);
    if (tid < 32) slab[tid] = labels[tid * 250 + tt1];
  };
  auto blGemm = [&](int s) {  // produce ZP_s from HT_{s-1}
    const int c0 = (bid - 80) * 32;
    const float* htS = HT + ((s + 1) & 1) * 16384;
    float* zpD = ZP0 + (s & 1) * 65536;
    float* W = dyn; float* blc = dyn + 8192; int* slab = (int*)(dyn + 8224);
    float* A = dyn + 8256; float* part = dyn + 17472;
    stage_act(A, htS);
    __syncthreads();
    float2 r;
    E32(W, A, 256, part, r);
    const int c = tid & 31, b2 = (tid >> 5) * 2;
    float base = blc[c];
    int l0 = slab[b2], l1 = slab[b2 + 1];
    st_sc(&zpD[(size_t)b2 * 2048 + c0 + c],
          r.x + base + WXI[(size_t)(128 + l0) * 2048 + c0 + c]);
    st_sc(&zpD[(size_t)(b2 + 1) * 2048 + c0 + c],
          r.y + base + WXI[(size_t)(128 + l1) * 2048 + c0 + c]);
  };
  // BH dyn: W[0,16384) A[16384,25600) part[25600,34816)
  auto bhGemm = [&](int s) {
    const int c0 = (bid - 144) * 64;
    const float* htS = HT + ((s + 1) & 1) * 16384 + 8192;
    float* zpD = ZP1 + (s & 1) * 65536;
    float* W = dyn; float* A = dyn + 16384; float* part = dyn + 25600;
    stage_act(A, htS);
    __syncthreads();
    float4 r;
    E64(W, A, part, r);
    const int c = tid & 63, b4 = (tid >> 6) * 4;
    st_sc(&zpD[(size_t)(b4 + 0) * 2048 + c0 + c], r.x);
    st_sc(&zpD[(size_t)(b4 + 1) * 2048 + c0 + c], r.y);
    st_sc(&zpD[(size_t)(b4 + 2) * 2048 + c0 + c], r.z);
    st_sc(&zpD[(size_t)(b4 + 3) * 2048 + c0 + c], r.w);
  };
  // OL/OHI/PL: E32; PHI: E64 (producers of OH_t / HP_t)
  auto p2Gemm = [&](int t) {
    const float* htBase = HT + (t & 1) * 16384;
    if (bid < 218) {
      float* W = dyn; float* A = dyn + 8192; float* part = dyn + 17408;
      const bool isOLr = bid < 192, isOHIr = (bid >= 192 && bid < 208);
      stage_act(A, isOHIr ? (htBase + 8192) : htBase);
      __syncthreads();
      float2 r;
      E32(W, A, 256, part, r);
      const int c = tid & 31, b2 = (tid >> 5) * 2;
      if (isOLr) {
        const int u0 = (bid - 176) * 32;
        float* d = OH0 + (t & 1) * 16384;
        st_sc(&d[b2 * 512 + u0 + c], r.x);
        st_sc(&d[(b2 + 1) * 512 + u0 + c], r.y);
      } else if (isOHIr) {
        const int u0 = (bid - 192) * 32;
        float* d = OH1 + (t & 1) * 16384;
        st_sc(&d[b2 * 512 + u0 + c], r.x);
        st_sc(&d[(b2 + 1) * 512 + u0 + c], r.y);
      } else {
        const int j0 = (bid - 208) * 32;
        st_sc(&HP0[b2 * 320 + j0 + c], r.x);
        st_sc(&HP0[(b2 + 1) * 320 + j0 + c], r.y);
      }
    } else {
      const int j0 = (bid - 218) * 64;
      float* W = dyn; float* A = dyn + 16384; float* part = dyn + 25600;
      stage_act(A, htBase + 8192);
      __syncthreads();
      float4 r;
      E64(W, A, part, r);
      const int c = tid & 63, b4 = (tid >> 6) * 4;
      st_sc(&HP1[(b4 + 0) * 320 + j0 + c], r.x);
      st_sc(&HP1[(b4 + 1) * 320 + j0 + c], r.y);
      st_sc(&HP1[(b4 + 2) * 320 + j0 + c], r.z);
      st_sc(&HP1[(b4 + 3) * 320 + j0 + c], r.w);
    }
  };
  // CA dyn: ring[0,17000) Wf[17000,29800) bp[29800,30120) bf[30120,30152)
  //         hid[30152,30472) kn[30472,30728) att4[30728,31752) red[31752,31784)
  //         msum[31784,31800) rvp[31800,33848)  (to/lp/lg alias rvp)
  auto caOut = [&](int t) {
    float* WfL = dyn + 17000; float* bfL = dyn + 30120;
    float* to  = dyn + 31800; float* lp = dyn + 32312; float* lg = dyn + 32712;
    const int b = bid - 223;
    to[tid] = tanhf(ld_sc(&OUTPRE[b * 512 + tid]));
    __syncthreads();
    if (tid < 400) {
      int l = tid % 25, p = tid / 25;
      float s = 0.f;
      #pragma unroll
      for (int q = 0; q < 32; ++q) { int k = p * 32 + q; s += to[k] * WfL[k * 25 + l]; }
      lp[p * 25 + l] = s;
    }
    __syncthreads();
    if (tid < 25) {
      float s = bfL[tid];
      #pragma unroll
      for (int p = 0; p < 16; ++p) s += lp[p * 25 + tid];
      lg[tid] = s;
    }
    __syncthreads();
    if (tid == 0) {
      float mx = lg[0];
      for (int l = 1; l < 25; ++l) mx = fmaxf(mx, lg[l]);
      float ss = 0.f;
      for (int l = 0; l < 25; ++l) ss += __expf(lg[l] - mx);
      lg[25] = mx; lg[26] = 1.f / ss;
    }
    __syncthreads();
    if (tid < 25)
      out[((size_t)b * 250 + (t - 1)) * 25 + tid] = __expf(lg[tid] - lg[25]) * lg[26];
  };
  auto caAtt = [&](int t) {
    float* ring = dyn;
    float* bpL  = dyn + 29800;
    float* hid  = dyn + 30152;
    float* kn   = dyn + 30472;
    float* att4 = dyn + 30728;
    float* red  = dyn + 31752;
    float* msum = dyn + 31784;
    float* rvp  = dyn + 31800;
    const int b = bid - 223;
    float* rvD = RVT + (t & 1) * 8192;
    if (tid < 320) {
      float x, y;
      ldpair_sc(&HP0[b * 320 + tid], &HP1[b * 320 + tid], x, y);
      hid[tid] = tanhf(x + y + bpL[tid]);
    }
    __syncthreads();
    if (tid < 256) {
      float v = hid[64 + tid]; float pq = v * v;
      for (int off = 32; off; off >>= 1) pq += __shfl_down(pq, off, 64);
      if ((tid & 63) == 0) red[tid >> 6] = rsqrtf(fmaxf(pq, 1e-12f));
    }
    __syncthreads();
    if (tid < 256) kn[tid] = hid[64 + tid] * red[tid >> 6];
    __syncthreads();
    const int start = (250 - t) % 250;
    if (tid < 500) {
      int m = tid >> 1, dh = tid & 1;
      int p = start + m; if (p >= 250) p -= 250;
      const float* cell = ring + p * 68;
      const float* k0 = kn + dh * 128;
      float n2 = 0.f, d0 = 0.f, d1 = 0.f;
      #pragma unroll
      for (int s = 0; s < 64; s += 4) {
        float4 q = *(const float4*)(cell + s);
        n2 += q.x * q.x + q.y * q.y + q.z * q.z + q.w * q.w;
        d0 += k0[s] * q.x + k0[s + 1] * q.y + k0[s + 2] * q.z + k0[s + 3] * q.w;
        d1 += k0[64 + s] * q.x + k0[64 + s + 1] * q.y + k0[64 + s + 2] * q.z + k0[64 + s + 3] * q.w;
      }
      float rs = rsqrtf(fmaxf(n2, 1e-12f));
      att4[(2 * dh) * 256 + m] = d0 * rs;
      att4[(2 * dh + 1) * 256 + m] = d1 * rs;
    }
    __syncthreads();
    {
      int h4 = tid >> 7, mm = tid & 127;
      float v0 = att4[h4 * 256 + mm];
      bool has2 = (mm + 128) < 250;
      float v1 = has2 ? att4[h4 * 256 + mm + 128] : -3.0e38f;
      float mx = fmaxf(v0, v1);
      for (int off = 32; off; off >>= 1) mx = fmaxf(mx, __shfl_down(mx, off, 64));
      if ((tid & 63) == 0) red[tid >> 6] = mx;
      __syncthreads();
      float MX = fmaxf(red[h4 * 2], red[h4 * 2 + 1]);
      float e0 = __expf(v0 - MX);
      float e1 = has2 ? __expf(v1 - MX) : 0.f;
      att4[h4 * 256 + mm] = e0;
      if (has2) att4[h4 * 256 + mm + 128] = e1;
      float sm_ = e0 + e1;
      for (int off = 32; off; off >>= 1) sm_ += __shfl_down(sm_, off, 64);
      if ((tid & 63) == 0) red[8 + (tid >> 6)] = sm_;
      __syncthreads();
      if (tid < 4) msum[tid] = red[8 + tid * 2] + red[8 + tid * 2 + 1];
      __syncthreads();
    }
    {
      int h4 = tid >> 7, mh = (tid >> 4) & 7, s4 = tid & 15;
      float4 a = {0.f, 0.f, 0.f, 0.f};
      for (int m = mh; m < 250; m += 8) {
        int p = start + m; if (p >= 250) p -= 250;
        float w = att4[h4 * 256 + m];
        float4 q = *(const float4*)(ring + p * 68 + s4 * 4);
        a.x = fmaf(w, q.x, a.x); a.y = fmaf(w, q.y, a.y);
        a.z = fmaf(w, q.z, a.z); a.w = fmaf(w, q.w, a.w);
      }
      *(float4*)(rvp + tid * 4) = a;
    }
    __syncthreads();
    if (tid < 256) {
      int h = tid >> 6, s = tid & 63;
      float sum = 0.f;
      #pragma unroll
      for (int j = 0; j < 8; ++j)
        sum += rvp[(h * 128 + j * 16 + (s >> 2)) * 4 + (s & 3)];
      st_sc(&rvD[(h * 64 + s) * 32 + b], sum / msum[h]);
    }
    __syncthreads();
    if (tid < 64) {
      int ip = start + 249; if (ip >= 250) ip -= 250;
      ring[ip * 68 + tid] = hid[tid];
    }
  };

  // ---------------- dataflow role loops (tag protocol) ----------------
  if (bid < 64) {                       // AZ
    int* tz0 = tagAddr(TG_Z0, bid);
    int* tz1 = tagAddr(TG_Z1, bid >> 1);
    const bool lohalf = bid < 32;
    int warZ = 0, warOH = 0, warHP = 0;   // cached slack (WAR) mins
    azX(0);
    for (int t = 0; t < 250; ++t) {
      // RAW: own ZP_t slices (exactly 2 producers)
      if (tid == 0) {
        int x, y;
        do { ldpair_int_sc(tz0, tz1, x, y); } while (x < t + 1 || y < t + 1);
      }
      __syncthreads();
      azPre(t);                         // zp load + zf staging overlaps rv wait
      if (tid == 0) {
        // WAR on HT_t over HT_{t-2}: all readers of this half done (>=1 step slack)
        if (t >= 1 && warZ < t) {
          do {
            warZ = lohalf ? imin2(min32_tags(TAGS + TG_Z0),
                                  min32_tags(TAGS + TG_Z0 + 128))
                          : min32_tags(TAGS + TG_Z1);
          } while (warZ < t);
        }
        if (t >= 2) {
          if (warOH < t - 1) { do { warOH = min32_tags(TAGS + TG_OH); } while (warOH < t - 1); }
          if (warHP < t - 1) { do { warHP = min16_tags(TAGS + TG_HP); } while (warHP < t - 1); }
        }
        // RAW: RVT_{t-1} from all 32 CA blocks (inherent full gather)
        if (t >= 1) { while (min32_tags(TAGS + TG_RV) < t) {} }
      }
      __syncthreads();
      azGatesMain(t);
      pub(TG_HT, bid, t + 1);
      if (t < 249) azX(t + 1);
    }
  } else if (bid < 80) {                // AO
    const int k = bid - 64;
    int* toh0 = tagAddr(TG_OH, k);
    int* toh1 = tagAddr(TG_OH, 16 + k);
    int warCO = 0;
    for (int t = 1; t <= 250; ++t) {
      if (tid == 0) {
        while (min32_tags(TAGS + TG_RV) < t) {}       // RVT_{t-1} (full gather)
        { int x, y;
          do { ldpair_int_sc(toh0, toh1, x, y); } while (x < t || y < t); } // own OH_{t-1}
        if (t >= 2 && warCO < t - 1) {                // OUTPRE WAR: caOut(t-1) done
          do { warCO = min32_tags(TAGS + TG_CO); } while (warCO < t - 1);
        }
      }
      __syncthreads();
      aoOut(t);
      pub(TG_OP, k, t);
    }
  } else if (bid < 144) {               // BL: produce ZP0_s, s=0..249
    const int j = bid - 80;
    int* thtj = tagAddr(TG_HT, j);
    for (int s = 0; s < 250; ++s) {
      blLoadLab(s);
      if (tid == 0) {
        if (s >= 1) { while (min32_tags(TAGS + TG_HT) < s) {} }      // HT_{s-1} lo
        if (s >= 2 && j >= 32) { while (ld_tag(thtj) < s - 1) {} }   // ZP slice WAR (AZ j)
      }
      __syncthreads();
      blGemm(s);
      pub(TG_Z0, j, s + 1);
    }
  } else if (bid < 176) {               // BH: produce ZP1_s
    const int j = bid - 144;
    int* th0 = tagAddr(TG_HT, 2 * j);
    int* th1 = tagAddr(TG_HT, 2 * j + 1);
    for (int s = 0; s < 250; ++s) {
      if (tid == 0) {
        if (s >= 1) { while (min32_tags(TAGS + TG_HT + 128) < s) {} } // HT_{s-1} hi
        if (s >= 2 && j < 16) {
          int x, y;
          do { ldpair_int_sc(th0, th1, x, y); } while (x < s - 1 || y < s - 1);
        }
      }
      __syncthreads();
      bhGemm(s);
      pub(TG_Z1, j, s + 1);
    }
  } else if (bid < 223) {               // OL/OHI (OH_t) and PL/PHI (HP_t)
    if (bid < 208) {                    // OL (176..191) / OHI (192..207)
      const bool isOL = bid < 192;
      const int k = isOL ? (bid - 176) : (bid - 192);
      int* topk = tagAddr(TG_OP, k);
      const int* htBaseTag = TAGS + TG_HT + (isOL ? 0 : 128);
      for (int t = 0; t < 250; ++t) {
        if (tid == 0) {
          while (min32_tags(htBaseTag) < t + 1) {}               // HT_t half
          if (t >= 2) { while (ld_tag(topk) < t - 1) {} }        // OH WAR: AO(t-1) done
        }
        __syncthreads();
        p2Gemm(t);
        pub(TG_OH, isOL ? k : 16 + k, t + 1);
      }
    } else {                            // PL (208..217) / PHI (218..222)
      const bool isPL = bid < 218;
      const int hp = isPL ? (bid - 208) : (10 + (bid - 218));
      const int* htBaseTag = TAGS + TG_HT + (isPL ? 0 : 128);
      for (int t = 0; t < 250; ++t) {
        if (tid == 0) {
          while (min32_tags(htBaseTag) < t + 1) {}               // HT_t half
          if (t >= 1) { while (min32_tags(TAGS + TG_RV) < t) {} }// HP WAR: caAtt(t-1)
        }
        __syncthreads();
        p2Gemm(t);
        pub(TG_HP, hp, t + 1);
      }
    }
  } else if (bid < 255) {               // CA
    const int b = bid - 223;
    if (b == 0 && tid == 0) st_tag(tagAddr(TG_HP, 15), 0x7fffffff);  // pad slot
    int warOP = 0;
    for (int t = 0; t < 250; ++t) {
      if (tid == 0) {
        while (min16_tags(TAGS + TG_HP) < t + 1) {}              // HP_t (15 producers)
        if (t >= 2 && warOP < t - 1) {                           // RVT WAR: aoOut(t-1) done
          do { warOP = min16_tags(TAGS + TG_OP); } while (warOP < t - 1);
        }
      }
      __syncthreads();
      caAtt(t);                    // publish rv FIRST, then do the output head
      pub(TG_RV, b, t + 1);
      if (t >= 1) {
        if (tid == 0) { while (min16_tags(TAGS + TG_OP) < t) {} }
        __syncthreads();
        caOut(t);
        if (tid == 0) st_tag(tagAddr(TG_CO, b), t);   // OUTPRE reads done
      }
    }
    if (tid == 0) { while (min16_tags(TAGS + TG_OP) < 250) {} }
    __syncthreads();
    caOut(250);
  }
}

extern "C" void kernel_launch(void* const* d_in, const int* in_sizes, int n_in,
                              void* d_out, int out_size, void* d_ws, size_t ws_size,
                              hipStream_t stream) {
  const float* images = (const float*)d_in[0];
  const int* labels = (const int*)d_in[1];
  const float* k1  = (const float*)d_in[2];
  const float* cb1 = (const float*)d_in[3];
  const float* g1  = (const float*)d_in[4];
  const float* be1 = (const float*)d_in[5];
  const float* mm1 = (const float*)d_in[6];
  const float* mv1 = (const float*)d_in[7];
  const float* k2  = (const float*)d_in[8];
  const float* cb2 = (const float*)d_in[9];
  const float* g2  = (const float*)d_in[10];
  const float* be2 = (const float*)d_in[11];
  const float* mm2 = (const float*)d_in[12];
  const float* mv2 = (const float*)d_in[13];
  const float* k3  = (const float*)d_in[14];
  const float* cb3 = (const float*)d_in[15];
  const float* g3  = (const float*)d_in[16];
  const float* be3 = (const float*)d_in[17];
  const float* mm3 = (const float*)d_in[18];
  const float* mv3 = (const float*)d_in[19];
  const float* Wx  = (const float*)d_in[20];
  const float* Wh  = (const float*)d_in[21];
  const float* bl  = (const float*)d_in[22];
  const float* Wp  = (const float*)d_in[23];
  const float* bp  = (const float*)d_in[24];
  const float* Wo  = (const float*)d_in[25];
  const float* bo  = (const float*)d_in[26];
  const float* Wf  = (const float*)d_in[27];
  const float* bf  = (const float*)d_in[28];
  float* ws = (float*)d_ws;

  hipFuncSetAttribute((const void*)lstm_kernel,
                      hipFuncAttributeMaxDynamicSharedMemorySize, DYN_BYTES);

  // zero activation/state/tag region (ws poisoned 0xAA before each call)
  hipMemsetAsync((char*)d_ws + OFF_ZP0 * sizeof(float), 0,
                 (WS_FLOATS - OFF_ZP0) * sizeof(float), stream);
  prep_kernel<<<1024, 256, 0, stream>>>(Wx, Wh, bl, ws);
  conv_kernel<<<8000, 128, 0, stream>>>(images,
      k1, cb1, g1, be1, mm1, mv1,
      k2, cb2, g2, be2, mm2, mv2,
      k3, cb3, g3, be3, mm3, mv3, ws);
  lstm_kernel<<<256, 512, DYN_BYTES, stream>>>(labels, Wo, bo, Wp, bp, Wf, bf, ws,
                                               (float*)d_out);
}

// Round 2
// 4683.876 us; speedup vs baseline: 1.2756x; 1.2756x over previous
//
#include <hip/hip_runtime.h>

// ---------------- problem constants ----------------
// B=32, T=250, FEAT=128, CLASSES=25, UNITS=512, CELL=64, HEADS=4, IN_LSTM=409

// ---------------- scratch layout (floats) ----------------
constexpr size_t OFF_FEATP  = 0;                              // [8000][128]
constexpr size_t OFF_WXI    = OFF_FEATP + (size_t)8000 * 128; // [409][2048] gate-interleaved
constexpr size_t OFF_WHI    = OFF_WXI + (size_t)409 * 2048;   // [512][2048]
constexpr size_t OFF_BLI    = OFF_WHI + (size_t)512 * 2048;   // [2048]
constexpr size_t OFF_ZP0    = OFF_BLI + 2048;                 // [2][32][2048] parity
constexpr size_t OFF_ZP1    = OFF_ZP0 + 131072;               // reused: HTT + WVP
constexpr size_t OFF_OH0    = OFF_ZP1 + 131072;               // [2][32][512]
constexpr size_t OFF_OH1    = OFF_OH0 + 32768;                // [2][32][512]
constexpr size_t OFF_HP0    = OFF_OH1 + 32768;                // (unused)
constexpr size_t OFF_HP1    = OFF_HP0 + 10240;                // (unused)
constexpr size_t OFF_OUTPRE = OFF_HP1 + 10240;                // [32][512]
constexpr size_t OFF_HT     = OFF_OUTPRE + 16384;             // [2][512][32] parity
constexpr size_t OFF_RVT    = OFF_HT + 32768;                 // [2][256][32] parity
constexpr size_t OFF_BAR    = OFF_RVT + 16384;                // counters (4096 ints)
constexpr size_t OFF_WPT    = OFF_BAR + 4096;                 // [128][320][4] k-major Wp
constexpr size_t WS_FLOATS  = OFF_WPT + (size_t)163840;

// carved from old ZP1 region:
constexpr size_t OFF_HTT = OFF_ZP1;           // [2][32][512] h transposed
constexpr size_t OFF_WVP = OFF_ZP1 + 32768;   // [2][2][32][64] wv partials

constexpr int DYN_FLOATS = 34816;                 // 136 KB dynamic LDS
constexpr int DYN_BYTES  = DYN_FLOATS * 4;

// counter bases (ints; 8 lines x 64-int stride each)
constexpr int CZP = 0, CHT = 512, COH = 1024, CWV = 1536, CRV = 2048,
              COP = 2560, CCO = 3072, CRING = 3584;

__device__ __forceinline__ float sigm(float x) { return 1.f / (1.f + __expf(-x)); }

// ---- LLC-coherent accesses (bypass L1+L2). Loads batched in asm with the
// waitcnt inside so they cannot be serialized into dependent round-trips.
__device__ __forceinline__ void st_sc(float* p, float v) {
  __hip_atomic_store(p, v, __ATOMIC_RELAXED, __HIP_MEMORY_SCOPE_AGENT);
}
__device__ __forceinline__ float ld_sc(const float* p) {
  return __hip_atomic_load(p, __ATOMIC_RELAXED, __HIP_MEMORY_SCOPE_AGENT);
}
__device__ __forceinline__ void ld8x2_sc(const double* b0, double* v) {
  const double *p0 = b0, *p1 = b0 + 512, *p2 = b0 + 1024, *p3 = b0 + 1536,
               *p4 = b0 + 2048, *p5 = b0 + 2560, *p6 = b0 + 3072, *p7 = b0 + 3584;
  asm volatile(
      "global_load_dwordx2 %0, %8, off sc0 sc1\n\t"
      "global_load_dwordx2 %1, %9, off sc0 sc1\n\t"
      "global_load_dwordx2 %2, %10, off sc0 sc1\n\t"
      "global_load_dwordx2 %3, %11, off sc0 sc1\n\t"
      "global_load_dwordx2 %4, %12, off sc0 sc1\n\t"
      "global_load_dwordx2 %5, %13, off sc0 sc1\n\t"
      "global_load_dwordx2 %6, %14, off sc0 sc1\n\t"
      "global_load_dwordx2 %7, %15, off sc0 sc1\n\t"
      "s_waitcnt vmcnt(0)"
      : "=&v"(v[0]), "=&v"(v[1]), "=&v"(v[2]), "=&v"(v[3]),
        "=&v"(v[4]), "=&v"(v[5]), "=&v"(v[6]), "=&v"(v[7])
      : "v"(p0), "v"(p1), "v"(p2), "v"(p3), "v"(p4), "v"(p5), "v"(p6), "v"(p7)
      : "memory");
}
// 8 rv loads + 2 partial loads, one waitcnt (AO staging)
__device__ __forceinline__ void ld10x2_sc(const double* b0, const double* z0,
                                          const double* z1, double* v) {
  const double *p0 = b0, *p1 = b0 + 512, *p2 = b0 + 1024, *p3 = b0 + 1536,
               *p4 = b0 + 2048, *p5 = b0 + 2560, *p6 = b0 + 3072, *p7 = b0 + 3584;
  asm volatile(
      "global_load_dwordx2 %0, %10, off sc0 sc1\n\t"
      "global_load_dwordx2 %1, %11, off sc0 sc1\n\t"
      "global_load_dwordx2 %2, %12, off sc0 sc1\n\t"
      "global_load_dwordx2 %3, %13, off sc0 sc1\n\t"
      "global_load_dwordx2 %4, %14, off sc0 sc1\n\t"
      "global_load_dwordx2 %5, %15, off sc0 sc1\n\t"
      "global_load_dwordx2 %6, %16, off sc0 sc1\n\t"
      "global_load_dwordx2 %7, %17, off sc0 sc1\n\t"
      "global_load_dwordx2 %8, %18, off sc0 sc1\n\t"
      "global_load_dwordx2 %9, %19, off sc0 sc1\n\t"
      "s_waitcnt vmcnt(0)"
      : "=&v"(v[0]), "=&v"(v[1]), "=&v"(v[2]), "=&v"(v[3]), "=&v"(v[4]),
        "=&v"(v[5]), "=&v"(v[6]), "=&v"(v[7]), "=&v"(v[8]), "=&v"(v[9])
      : "v"(p0), "v"(p1), "v"(p2), "v"(p3), "v"(p4), "v"(p5), "v"(p6), "v"(p7),
        "v"(z0), "v"(z1)
      : "memory");
}
__device__ __forceinline__ void ldpair_sc(const float* a, const float* b,
                                          float& x, float& y) {
  asm volatile(
      "global_load_dword %0, %2, off sc0 sc1\n\t"
      "global_load_dword %1, %3, off sc0 sc1\n\t"
      "s_waitcnt vmcnt(0)"
      : "=&v"(x), "=&v"(y) : "v"(a), "v"(b) : "memory");
}
__device__ __forceinline__ double ld1x2_sc(const double* a) {
  double x;
  asm volatile(
      "global_load_dwordx2 %0, %1, off sc0 sc1\n\t"
      "s_waitcnt vmcnt(0)"
      : "=&v"(x) : "v"(a) : "memory");
  return x;
}
// counter poll: sum of 8 lines, single batched round trip
__device__ __forceinline__ int sum8_bar(const int* b) {
  int v0, v1, v2, v3, v4, v5, v6, v7;
  asm volatile(
      "global_load_dword %0, %8, off sc0 sc1\n\t"
      "global_load_dword %1, %9, off sc0 sc1\n\t"
      "global_load_dword %2, %10, off sc0 sc1\n\t"
      "global_load_dword %3, %11, off sc0 sc1\n\t"
      "global_load_dword %4, %12, off sc0 sc1\n\t"
      "global_load_dword %5, %13, off sc0 sc1\n\t"
      "global_load_dword %6, %14, off sc0 sc1\n\t"
      "global_load_dword %7, %15, off sc0 sc1\n\t"
      "s_waitcnt vmcnt(0)"
      : "=&v"(v0), "=&v"(v1), "=&v"(v2), "=&v"(v3),
        "=&v"(v4), "=&v"(v5), "=&v"(v6), "=&v"(v7)
      : "v"(b), "v"(b + 64), "v"(b + 128), "v"(b + 192),
        "v"(b + 256), "v"(b + 320), "v"(b + 384), "v"(b + 448)
      : "memory");
  return ((v0 + v1) + (v2 + v3)) + ((v4 + v5) + (v6 + v7));
}

// ---------------- weight re-layout: gate-interleaved Wx/Wh/bl + k-major Wp ----------------
__global__ __launch_bounds__(256) void prep_kernel(const float* __restrict__ Wx,
                                                   const float* __restrict__ Wh,
                                                   const float* __restrict__ bl,
                                                   const float* __restrict__ Wp,
                                                   float* __restrict__ ws) {
  float* WXI = ws + OFF_WXI;
  float* WHI = ws + OFF_WHI;
  float* BLI = ws + OFF_BLI;
  float* WPT = ws + OFF_WPT;
  const int t0 = 409 * 2048;
  const int t1 = t0 + 512 * 2048;
  const int t2 = t1 + 2048;
  const int total = t2 + 163840;
  for (int idx = blockIdx.x * blockDim.x + threadIdx.x; idx < total;
       idx += gridDim.x * blockDim.x) {
    if (idx < t0) {
      int k = idx >> 11, cc = idx & 2047;
      WXI[idx] = Wx[(size_t)k * 2048 + (cc & 3) * 512 + (cc >> 2)];
    } else if (idx < t1) {
      int j = idx - t0;
      int k = j >> 11, cc = j & 2047;
      WHI[j] = Wh[(size_t)k * 2048 + (cc & 3) * 512 + (cc >> 2)];
    } else if (idx < t2) {
      int cc = idx - t1;
      BLI[cc] = bl[(cc & 3) * 512 + (cc >> 2)];
    } else {
      // WPT[k4][j][ks] = Wp[k4*4+ks][j]  (k-major float4 tiles for coalesced key GEMM)
      int e = idx - t2;
      int k4 = e / 1280, r = e - k4 * 1280;
      int j = r >> 2, ks = r & 3;
      WPT[e] = Wp[(size_t)(k4 * 4 + ks) * 320 + j];
    }
  }
}

// ---------------- conv stack (validated) ----------------
__global__ __launch_bounds__(128) void conv_kernel(
    const float* __restrict__ img,
    const float* __restrict__ k1, const float* __restrict__ cb1, const float* __restrict__ g1,
    const float* __restrict__ be1, const float* __restrict__ mm1, const float* __restrict__ mv1,
    const float* __restrict__ k2, const float* __restrict__ cb2, const float* __restrict__ g2,
    const float* __restrict__ be2, const float* __restrict__ mm2, const float* __restrict__ mv2,
    const float* __restrict__ k3, const float* __restrict__ cb3, const float* __restrict__ g3,
    const float* __restrict__ be3, const float* __restrict__ mm3, const float* __restrict__ mv3,
    float* __restrict__ ws) {
  __shared__ float s_in[784];
  __shared__ float s_y1[13 * 13 * 8];
  __shared__ float s_y2[6 * 6 * 16];
  __shared__ float s_k1[72], s_k2[1152], s_k3[4608];
  __shared__ float s_s1[8], s_b1[8], s_s2[16], s_b2[16], s_s3[32], s_b3[32];
  float* FEATP = ws + OFF_FEATP;
  const int n = blockIdx.x, tid = threadIdx.x;
  const float* ip = img + (size_t)n * 784;
  for (int i = tid; i < 784; i += 128) s_in[i] = ip[i];
  for (int i = tid; i < 72; i += 128) s_k1[i] = k1[i];
  for (int i = tid; i < 1152; i += 128) s_k2[i] = k2[i];
  for (int i = tid; i < 4608; i += 128) s_k3[i] = k3[i];
  if (tid < 8) {
    float s = g1[tid] * rsqrtf(mv1[tid] + 1e-3f);
    s_s1[tid] = s; s_b1[tid] = (cb1[tid] - mm1[tid]) * s + be1[tid];
  } else if (tid >= 32 && tid < 48) {
    int c = tid - 32;
    float s = g2[c] * rsqrtf(mv2[c] + 1e-3f);
    s_s2[c] = s; s_b2[c] = (cb2[c] - mm2[c]) * s + be2[c];
  } else if (tid >= 64 && tid < 96) {
    int c = tid - 64;
    float s = g3[c] * rsqrtf(mv3[c] + 1e-3f);
    s_s3[c] = s; s_b3[c] = (cb3[c] - mm3[c]) * s + be3[c];
  }
  __syncthreads();
  for (int idx = tid; idx < 13 * 13 * 8; idx += 128) {
    int co = idx & 7, pos = idx >> 3;
    int j = pos % 13, i = pos / 13;
    float acc = 0.f;
    #pragma unroll
    for (int ky = 0; ky < 3; ++ky)
      #pragma unroll
      for (int kx = 0; kx < 3; ++kx)
        acc += s_in[(2 * i + ky) * 28 + (2 * j + kx)] * s_k1[(ky * 3 + kx) * 8 + co];
    float v = acc * s_s1[co] + s_b1[co];
    s_y1[idx] = v > 0.f ? v : 0.f;
  }
  __syncthreads();
  for (int idx = tid; idx < 6 * 6 * 16; idx += 128) {
    int co = idx & 15, pos = idx >> 4;
    int j = pos % 6, i = pos / 6;
    float acc = 0.f;
    for (int ky = 0; ky < 3; ++ky)
      for (int kx = 0; kx < 3; ++kx) {
        int base = ((2 * i + ky) * 13 + (2 * j + kx)) * 8;
        int kb = (ky * 3 + kx) * 128 + co;
        #pragma unroll
        for (int ci = 0; ci < 8; ++ci) acc += s_y1[base + ci] * s_k2[kb + ci * 16];
      }
    float v = acc * s_s2[co] + s_b2[co];
    s_y2[idx] = v > 0.f ? v : 0.f;
  }
  __syncthreads();
  for (int idx = tid; idx < 128; idx += 128) {
    int co = idx & 31, pos = idx >> 5;
    int j = pos & 1, i = pos >> 1;
    float acc = 0.f;
    for (int ky = 0; ky < 3; ++ky)
      for (int kx = 0; kx < 3; ++kx) {
        int base = ((2 * i + ky) * 6 + (2 * j + kx)) * 16;
        int kb = (ky * 3 + kx) * 512 + co;
        #pragma unroll
        for (int ci = 0; ci < 16; ++ci) acc += s_y2[base + ci] * s_k3[kb + ci * 32];
      }
    float v = acc * s_s3[co] + s_b3[co];
    FEATP[(size_t)n * 128 + idx] = v > 0.f ? v : 0.f;
  }
}

// ---------------- persistent LSTM scan: 2-hop critical chain ----------------
// Roles: AZ 0-63 (gates, 32 z-cols each) | AO 64-79 (outpre) | ZH 80-143 (h@Wh,
// 32 cols, K=512) | OL 144-159 / OHI 160-175 (h@Wo halves) | ATT 176-239
// (per (batch, head-pair): keys via streamed Wp + attention + rv) | WV 240-243
// (wv partials) | COUT 244-251 (final logits+softmax) | 252-255 idle.
// Critical cycle: AZ --HT/HTT--> ATT --RVT--> AZ  (2 LLC hops).
__global__ __launch_bounds__(512) void lstm_kernel(
    const int* __restrict__ labels,
    const float* __restrict__ Wo, const float* __restrict__ bo,
    const float* __restrict__ Wp, const float* __restrict__ bp,
    const float* __restrict__ Wf, const float* __restrict__ bf,
    float* __restrict__ ws, float* __restrict__ out) {
  extern __shared__ float dyn[];
  const float* FEATP = ws + OFF_FEATP;
  const float* WXI   = ws + OFF_WXI;
  const float* WHI   = ws + OFF_WHI;
  const float* BLI   = ws + OFF_BLI;
  float* ZP0    = ws + OFF_ZP0;     // [2][32][2048]
  float* OH0    = ws + OFF_OH0;     // [2][32][512]
  float* OH1    = ws + OFF_OH1;
  float* OUTPRE = ws + OFF_OUTPRE;  // [32][512]
  float* HT     = ws + OFF_HT;      // [2][512][32]
  float* HTT    = ws + OFF_HTT;     // [2][32][512]
  float* RVT    = ws + OFF_RVT;     // [2][256][32]
  float* WVPp   = ws + OFF_WVP;     // [2][2][32][64]
  const float* WPT = ws + OFF_WPT;  // [128][320][4]
  int*   BARp   = (int*)(ws + OFF_BAR);

  const int bid = blockIdx.x;
  const int tid = threadIdx.x;

  auto waitC = [&](int base, int target) {
    if (tid == 0) {
      while (sum8_bar(BARp + base) < target) {}
    }
    __syncthreads();
  };
  auto bumpC = [&](int base) {
    asm volatile("s_waitcnt vmcnt(0)" ::: "memory");
    __syncthreads();
    if (tid == 0) atomicAdd(&BARp[base + ((bid & 7) << 6)], 1);
  };

  // stage 8192-float [256][32] coherent buffer into [256][36]-padded LDS tile
  auto stage_act = [&](float* dst, const float* src) {
    double v[8];
    ld8x2_sc((const double*)src + tid, v);
    #pragma unroll
    for (int j = 0; j < 8; ++j) {
      int i = (tid + j * 512) << 1;
      *(double*)&dst[(i >> 5) * 36 + (i & 31)] = v[j];
    }
  };

  // ---- E32: Y[32c][32b] (R6-validated). K mult of 16.
  auto E32 = [&](const float* Wm, const float* Am, int K, float* part, float2& r) {
    const int wv = tid >> 6, l = tid & 63;
    const int ksub = l & 1, cg = (l >> 1) & 3, bg = l >> 3;
    const int Kp = K >> 4;
    const int kb = wv * (K >> 3) + ksub * Kp;
    const float* wp = Wm + (size_t)kb * 32 + cg * 8;
    const float* ap = Am + (size_t)kb * 36 + bg * 4;
    float4 acc[8];
    #pragma unroll
    for (int i = 0; i < 8; ++i) acc[i] = {0.f, 0.f, 0.f, 0.f};
    #pragma unroll 4
    for (int kk = 0; kk < Kp; ++kk) {
      float4 w0 = *(const float4*)(wp + kk * 32);
      float4 w1 = *(const float4*)(wp + kk * 32 + 4);
      float4 a  = *(const float4*)(ap + kk * 36);
      float wl[8];
      *(float4*)&wl[0] = w0; *(float4*)&wl[4] = w1;
      #pragma unroll
      for (int i = 0; i < 8; ++i) {
        acc[i].x = fmaf(wl[i], a.x, acc[i].x);
        acc[i].y = fmaf(wl[i], a.y, acc[i].y);
        acc[i].z = fmaf(wl[i], a.z, acc[i].z);
        acc[i].w = fmaf(wl[i], a.w, acc[i].w);
      }
    }
    #pragma unroll
    for (int i = 0; i < 8; ++i) {
      acc[i].x += __shfl_xor(acc[i].x, 1, 64);
      acc[i].y += __shfl_xor(acc[i].y, 1, 64);
      acc[i].z += __shfl_xor(acc[i].z, 1, 64);
      acc[i].w += __shfl_xor(acc[i].w, 1, 64);
    }
    const int ob = (cg * 8) * 36 + bg * 4;
    if (ksub == 0 && wv < 4) {
      float* pb = part + wv * 1152 + ob;
      #pragma unroll
      for (int i = 0; i < 8; ++i) *(float4*)(pb + i * 36) = acc[i];
    }
    __syncthreads();
    if (ksub == 0 && wv >= 4) {
      float* pb = part + (wv - 4) * 1152 + ob;
      #pragma unroll
      for (int i = 0; i < 8; ++i) {
        float4 t = *(float4*)(pb + i * 36);
        t.x += acc[i].x; t.y += acc[i].y; t.z += acc[i].z; t.w += acc[i].w;
        *(float4*)(pb + i * 36) = t;
      }
    }
    __syncthreads();
    const int c = tid & 31, b2 = (tid >> 5) * 2;
    const int o = c * 36 + b2;
    float2 s0 = *(float2*)(part + o);
    float2 s1 = *(float2*)(part + 1152 + o);
    float2 s2 = *(float2*)(part + 2304 + o);
    float2 s3 = *(float2*)(part + 3456 + o);
    r.x = (s0.x + s1.x) + (s2.x + s3.x);
    r.y = (s0.y + s1.y) + (s2.y + s3.y);
  };

  // ---------------- one-time init: weights -> LDS ----------------
  if (bid < 64) {            // AZ: Wz (rv part of Wx) + Wxx (x part)
    const int c0 = bid * 32;
    for (int i = tid; i < 8192; i += 512)
      dyn[i] = WXI[(size_t)(153 + (i >> 5)) * 2048 + c0 + (i & 31)];
    for (int i = tid; i < 4096; i += 512)
      dyn[8192 + i] = WXI[(size_t)(i >> 5) * 2048 + c0 + (i & 31)];
    if (tid < 256) dyn[12288 + tid] = 0.f;  // Cst
  } else if (bid < 80) {     // AO: Wo rows 512..768
    const int u0 = (bid - 64) * 32;
    for (int i = tid; i < 8192; i += 512)
      dyn[i] = Wo[(size_t)(512 + (i >> 5)) * 512 + u0 + (i & 31)];
    if (tid < 32) dyn[8192 + tid] = bo[u0 + tid];
  } else if (bid < 144) {    // ZH: full Wh column slab [512][32]
    const int c0 = (bid - 80) * 32;
    for (int i = tid; i < 16384; i += 512)
      dyn[i] = WHI[(size_t)(i >> 5) * 2048 + c0 + (i & 31)];
    if (tid < 32) dyn[16384 + tid] = BLI[c0 + tid];
  } else if (bid < 160) {    // OL: Wo rows 0..256
    const int u0 = (bid - 144) * 32;
    for (int i = tid; i < 8192; i += 512)
      dyn[i] = Wo[(size_t)(i >> 5) * 512 + u0 + (i & 31)];
  } else if (bid < 176) {    // OHI: Wo rows 256..512
    const int u0 = (bid - 160) * 32;
    for (int i = tid; i < 8192; i += 512)
      dyn[i] = Wo[(size_t)(256 + (i >> 5)) * 512 + u0 + (i & 31)];
  } else if (bid < 240) {    // ATT: ring + cached norms + bias slices
    const int hp = (bid - 176) & 1;
    for (int i = tid; i < 17000; i += 512) dyn[i] = 0.f;            // ring[250][68]
    if (tid < 256) dyn[17000 + tid] = rsqrtf(1e-12f);               // rn
    if (tid < 128) dyn[21264 + tid] = bp[64 + hp * 128 + tid];      // bpk
    if (tid < 64)  dyn[21392 + tid] = bp[tid];                      // bpw
  } else if (bid < 244) {    // WV: Wp[kh*256..+256][cp*32..+32]
    const int kh = (bid - 240) >> 1, cp = (bid - 240) & 1;
    for (int i = tid; i < 8192; i += 512) {
      int k = i >> 5, c = i & 31;
      dyn[i] = Wp[(size_t)(kh * 256 + k) * 320 + cp * 32 + c];
    }
  } else if (bid < 252) {    // COUT: Wf + bf
    for (int i = tid; i < 12800; i += 512) dyn[i] = Wf[i];
    if (tid < 25) dyn[12800 + tid] = bf[tid];
  }
  __syncthreads();

  // ================= role bodies =================
  // AZ dyn: Wz[0,8192) Wxx[8192,12288) Cst[12288,12544) rvT[12544,21760)
  //         xT[21760,26368) zx[26368,27392) zf[27392,28416) part[28416,33024)
  auto azPre = [&](int t) {           // ZP_t -> zf (overlaps the rv wait)
    const int c0 = bid * 32;
    const float* zpS = ZP0 + (t & 1) * 65536;
    float* zf = dyn + 27392;
    const int bb = tid >> 4, c2 = tid & 15;
    double x = ld1x2_sc((const double*)(zpS + (size_t)bb * 2048 + c0) + c2);
    *(double*)&zf[bb * 32 + c2 * 2] = x;
  };
  auto azGatesMain = [&](int t) {
    const float* rvS = RVT + ((t + 1) & 1) * 8192;   // RVT_{t-1}
    float* htD  = HT + (t & 1) * 16384;              // HT_t
    float* htD2 = HTT + (t & 1) * 16384;             // HTT_t
    float* Wz = dyn; float* Cst = dyn + 12288; float* rvT = dyn + 12544;
    float* zx = dyn + 26368; float* zf = dyn + 27392; float* part = dyn + 28416;
    {
      double v[8];
      ld8x2_sc((const double*)rvS + tid, v);
      #pragma unroll
      for (int j = 0; j < 8; ++j) {
        int i = (tid + j * 512) << 1;
        *(double*)&rvT[(i >> 5) * 36 + (i & 31)] = v[j];
      }
    }
    __syncthreads();
    float2 r;
    E32(Wz, rvT, 256, part, r);
    const int c = tid & 31, b2 = (tid >> 5) * 2;
    zf[b2 * 32 + c] += r.x + zx[b2 * 32 + c];
    zf[(b2 + 1) * 32 + c] += r.y + zx[(b2 + 1) * 32 + c];
    __syncthreads();
    if (tid < 256) {
      int u = tid & 7, b = tid >> 3;
      float4 z = *(float4*)(zf + b * 32 + u * 4);
      float ig = sigm(z.x), fg = sigm(z.y), gg = tanhf(z.z), og = sigm(z.w);
      float cc = fg * Cst[b * 8 + u] + ig * gg;
      Cst[b * 8 + u] = cc;
      float hv = og * tanhf(cc);
      st_sc(&htD[(size_t)(bid * 8 + u) * 32 + b], hv);
      st_sc(&htD2[(size_t)b * 512 + bid * 8 + u], hv);
    }
  };
  auto azX = [&](int tt) {    // zx = x_{tt}@Wx, local
    float* Wxx = dyn + 8192; float* xT = dyn + 21760;
    float* zx = dyn + 26368; float* part = dyn + 28416;
    for (int i = tid; i < 4096; i += 512) {
      int b = i >> 7, k = i & 127;
      xT[k * 36 + b] = FEATP[((size_t)b * 250 + tt) * 128 + k];
    }
    __syncthreads();
    float2 r;
    E32(Wxx, xT, 128, part, r);
    const int c = tid & 31, b2 = (tid >> 5) * 2;
    zx[b2 * 32 + c] = r.x;
    zx[(b2 + 1) * 32 + c] = r.y;
  };
  // AO dyn: W[0,8192) bo[8192,8224) rvT[8224,17440) of[17440,18464) part[18464,23072)
  auto aoOut = [&](int t) {   // outpre_{t-1}: RVT_{t-1}, OH_{t-1}
    const int u0 = (bid - 64) * 32;
    const float* rvS  = RVT + ((t + 1) & 1) * 8192;
    const float* oh0S = OH0 + ((t + 1) & 1) * 16384;
    const float* oh1S = OH1 + ((t + 1) & 1) * 16384;
    float* W = dyn; float* bo_l = dyn + 8192; float* rvT = dyn + 8224;
    float* of = dyn + 17440; float* part = dyn + 18464;
    {
      const int b = tid >> 4, c2 = tid & 15;
      double v[10];
      ld10x2_sc((const double*)rvS + tid,
                (const double*)(oh0S + b * 512 + u0) + c2,
                (const double*)(oh1S + b * 512 + u0) + c2, v);
      #pragma unroll
      for (int j = 0; j < 8; ++j) {
        int i = (tid + j * 512) << 1;
        *(double*)&rvT[(i >> 5) * 36 + (i & 31)] = v[j];
      }
      float2 f0 = *(float2*)&v[8], f1 = *(float2*)&v[9];
      float2 s = {f0.x + f1.x, f0.y + f1.y};
      *(double*)&of[b * 32 + c2 * 2] = *(double*)&s;
    }
    __syncthreads();
    float2 r;
    E32(W, rvT, 256, part, r);
    const int c = tid & 31, b2 = (tid >> 5) * 2;
    float bv = bo_l[c];
    st_sc(&OUTPRE[b2 * 512 + u0 + c], r.x + of[b2 * 32 + c] + bv);
    st_sc(&OUTPRE[(b2 + 1) * 512 + u0 + c], r.y + of[(b2 + 1) * 32 + c] + bv);
  };
  // ZH dyn: W[0,16384) blc[16384,16416) slab[16416,16448) A[16448,25664) part[25664,30272)
  auto zhLab = [&](int s) {
    __syncthreads();
    int* slab = (int*)(dyn + 16416);
    if (tid < 32) slab[tid] = labels[tid * 250 + s];
  };
  auto zhGemm = [&](int s) {  // ZP_s = h_{s-1}@Wh + bl + Wx[onehot label_s]
    const int c0 = (bid - 80) * 32;
    const float* htS = HT + ((s + 1) & 1) * 16384;
    float* zpD = ZP0 + (s & 1) * 65536;
    float* W = dyn; float* blc = dyn + 16384; int* slab = (int*)(dyn + 16416);
    float* A = dyn + 16448; float* part = dyn + 25664;
    stage_act(A, htS);
    __syncthreads();
    float2 r1;
    E32(W, A, 256, part, r1);
    __syncthreads();           // part WAR before second pass
    stage_act(A, htS + 8192);
    __syncthreads();
    float2 r2;
    E32(W + 8192, A, 256, part, r2);
    const int c = tid & 31, b2 = (tid >> 5) * 2;
    float base = blc[c];
    int l0 = slab[b2], l1 = slab[b2 + 1];
    st_sc(&zpD[(size_t)b2 * 2048 + c0 + c],
          r1.x + r2.x + base + WXI[(size_t)(128 + l0) * 2048 + c0 + c]);
    st_sc(&zpD[(size_t)(b2 + 1) * 2048 + c0 + c],
          r1.y + r2.y + base + WXI[(size_t)(128 + l1) * 2048 + c0 + c]);
  };
  // OL/OHI dyn: W[0,8192) A[8192,17408) part[17408,22016)
  auto p2Gemm = [&](int t) {
    const float* htBase = HT + (t & 1) * 16384;
    float* W = dyn; float* A = dyn + 8192; float* part = dyn + 17408;
    const bool isOLr = bid < 160;
    stage_act(A, isOLr ? htBase : (htBase + 8192));
    __syncthreads();
    float2 r;
    E32(W, A, 256, part, r);
    const int c = tid & 31, b2 = (tid >> 5) * 2;
    const int u0 = (isOLr ? (bid - 144) : (bid - 160)) * 32;
    float* d = (isOLr ? OH0 : OH1) + (t & 1) * 16384;
    st_sc(&d[b2 * 512 + u0 + c], r.x);
    st_sc(&d[(b2 + 1) * 512 + u0 + c], r.y);
  };
  // COUT dyn: Wf[0,12800) bf[12800,12825) to[12832,13344) lp[13344,13744) lg[13744,13771)
  auto caOutB = [&](int b, int t) {
    float* WfL = dyn; float* bfL = dyn + 12800;
    float* to = dyn + 12832; float* lp = dyn + 13344; float* lg = dyn + 13744;
    to[tid] = tanhf(ld_sc(&OUTPRE[b * 512 + tid]));
    __syncthreads();
    if (tid < 400) {
      int l = tid % 25, p = tid / 25;
      float s = 0.f;
      #pragma unroll
      for (int q = 0; q < 32; ++q) { int k = p * 32 + q; s += to[k] * WfL[k * 25 + l]; }
      lp[p * 25 + l] = s;
    }
    __syncthreads();
    if (tid < 25) {
      float s = bfL[tid];
      #pragma unroll
      for (int p = 0; p < 16; ++p) s += lp[p * 25 + tid];
      lg[tid] = s;
    }
    __syncthreads();
    if (tid == 0) {
      float mx = lg[0];
      for (int l = 1; l < 25; ++l) mx = fmaxf(mx, lg[l]);
      float ss = 0.f;
      for (int l = 0; l < 25; ++l) ss += __expf(lg[l] - mx);
      lg[25] = mx; lg[26] = 1.f / ss;
    }
    __syncthreads();
    if (tid < 25)
      out[((size_t)b * 250 + (t - 1)) * 25 + tid] = __expf(lg[tid] - lg[25]) * lg[26];
    __syncthreads();
  };

  // ---------------- dataflow role loops ----------------
  if (bid < 64) {                       // AZ
    azX(0);
    for (int t = 0; t < 250; ++t) {
      waitC(CZP, 64 * (t + 1));                  // RAW ZP_t
      azPre(t);
      if (t >= 2) {                              // HT/HTT WAR (1-step slack)
        waitC(COH, 32 * (t - 1));
        waitC(CWV, 4 * (t - 1));
      }
      if (t >= 1) waitC(CRV, 64 * t);            // RAW RVT_{t-1}
      azGatesMain(t);
      bumpC(CHT);
      if (t < 249) azX(t + 1);
    }
  } else if (bid < 80) {                // AO
    for (int t = 1; t <= 250; ++t) {
      waitC(CRV, 64 * t);                        // RAW RVT_{t-1}
      waitC(COH, 32 * t);                        // RAW OH_{t-1}
      if (t >= 2) waitC(CCO, 8 * (t - 1));       // OUTPRE WAR (COUT read done)
      aoOut(t);
      bumpC(COP);
    }
  } else if (bid < 144) {               // ZH
    for (int s = 0; s < 250; ++s) {
      zhLab(s);
      if (s >= 1) waitC(CHT, 64 * s);            // RAW HT_{s-1} (WARs implied)
      zhGemm(s);
      bumpC(CZP);
    }
  } else if (bid < 176) {               // OL / OHI
    for (int t = 0; t < 250; ++t) {
      waitC(CHT, 64 * (t + 1));                  // RAW HT_t
      if (t >= 2) waitC(COP, 16 * (t - 1));      // OH WAR (AO_{t-1} read done)
      p2Gemm(t);
      bumpC(COH);
    }
  } else if (bid < 240) {               // ATT: keys + attention + rv
    // LDS: ring@0 rn@17000 h_s@17256 kpart@17768 kv@18280 kn@18408 att@18536
    //      redK@19048 redM@19052 redS@19068 pslab@19088(2x16x68) bpk@21264 bpw@21392
    float* ring = dyn;
    float* rn   = dyn + 17000;
    float* h_s  = dyn + 17256;
    float* kpart= dyn + 17768;
    float* kv   = dyn + 18280;
    float* kn   = dyn + 18408;
    float* att  = dyn + 18536;
    float* redK = dyn + 19048;
    float* redM = dyn + 19052;
    float* redS = dyn + 19068;
    float* pslab= dyn + 19088;
    float* bpk  = dyn + 21264;
    float* bpw  = dyn + 21392;
    const int b = (bid - 176) >> 1, hp = (bid - 176) & 1;
    const int j = tid & 127, q = tid >> 7;
    const int J = 64 + hp * 128 + j;
    const float4* wbase = (const float4*)WPT + q * 32 * 320 + J;
    for (int t = 0; t < 250; ++t) {
      // prefetch first half of this thread's Wp chunk while waiting for h_t
      float4 pf[16];
      #pragma unroll
      for (int i = 0; i < 16; ++i) pf[i] = wbase[i * 320];
      waitC(CHT, 64 * (t + 1));                  // RAW h_t
      if (t >= 2) waitC(COP, 16 * (t - 1));      // RVT WAR (AO_{t-1} read done)
      h_s[tid] = ld_sc(&HTT[(t & 1) * 16384 + b * 512 + tid]);
      __syncthreads();
      {  // key GEMM: kpart[q][j] = sum_k h[k]*Wp[k][J] over k in [q*128, q*128+128)
        float a = 0.f;
        #pragma unroll
        for (int i = 0; i < 16; ++i) {
          float4 h4 = *(const float4*)&h_s[q * 128 + i * 4];
          a += pf[i].x * h4.x + pf[i].y * h4.y + pf[i].z * h4.z + pf[i].w * h4.w;
        }
        #pragma unroll 4
        for (int i = 16; i < 32; ++i) {
          float4 w = wbase[i * 320];
          float4 h4 = *(const float4*)&h_s[q * 128 + i * 4];
          a += w.x * h4.x + w.y * h4.y + w.z * h4.z + w.w * h4.w;
        }
        kpart[q * 128 + j] = a;
      }
      __syncthreads();
      if (tid < 128) {
        float kr = kpart[tid] + kpart[128 + tid] + kpart[256 + tid] +
                   kpart[384 + tid] + bpk[tid];
        float v = tanhf(kr);
        kv[tid] = v;
        float pq = v * v;
        #pragma unroll
        for (int off = 32; off; off >>= 1) pq += __shfl_xor(pq, off, 64);
        if ((tid & 63) == 0) redK[tid >> 6] = rsqrtf(fmaxf(pq, 1e-12f));
      }
      __syncthreads();
      if (tid < 128) kn[tid] = kv[tid] * redK[tid >> 6];
      __syncthreads();
      const int start = (250 - t) % 250;
      const int m = tid >> 1, hh = tid & 1;
      {  // dots + softmax (cell norms cached in rn)
        float v;
        if (m < 250) {
          int p = start + m; if (p >= 250) p -= 250;
          const float4* c4 = (const float4*)ring + p * 17;
          const float4* k4 = (const float4*)kn + hh * 16;
          float d = 0.f;
          #pragma unroll
          for (int s4 = 0; s4 < 16; ++s4) {
            float4 cc = c4[s4], kk = k4[s4];
            d += cc.x * kk.x + cc.y * kk.y + cc.z * kk.z + cc.w * kk.w;
          }
          v = d * rn[p];
        } else v = -3.0e38f;
        float mx = v;
        #pragma unroll
        for (int off = 2; off <= 32; off <<= 1) mx = fmaxf(mx, __shfl_xor(mx, off, 64));
        if ((tid & 63) < 2) redM[(tid >> 6) * 2 + (tid & 1)] = mx;
        __syncthreads();
        float MX = redM[hh];
        #pragma unroll
        for (int w = 1; w < 8; ++w) MX = fmaxf(MX, redM[w * 2 + hh]);
        float e = (m < 250) ? __expf(v - MX) : 0.f;
        if (m < 250) att[hh * 256 + m] = e;
        float sm = e;
        #pragma unroll
        for (int off = 2; off <= 32; off <<= 1) sm += __shfl_xor(sm, off, 64);
        if ((tid & 63) < 2) redS[(tid >> 6) * 2 + (tid & 1)] = sm;
      }
      __syncthreads();
      {  // weighted sum into padded partial slabs
        int hh2 = tid >> 8, s4 = (tid >> 4) & 15, g = tid & 15;
        float4 a4 = {0.f, 0.f, 0.f, 0.f};
        for (int mm = g; mm < 250; mm += 16) {
          int p = start + mm; if (p >= 250) p -= 250;
          float w = att[hh2 * 256 + mm];
          float4 cc = ((const float4*)ring)[p * 17 + s4];
          a4.x = fmaf(w, cc.x, a4.x); a4.y = fmaf(w, cc.y, a4.y);
          a4.z = fmaf(w, cc.z, a4.z); a4.w = fmaf(w, cc.w, a4.w);
        }
        *(float4*)&pslab[(hh2 * 16 + s4) * 68 + g * 4] = a4;
      }
      __syncthreads();
      if (tid < 128) {
        int hh3 = tid >> 6, s = tid & 63;
        float denom = redS[hh3];
        #pragma unroll
        for (int w = 1; w < 8; ++w) denom += redS[w * 2 + hh3];
        float sum = 0.f;
        #pragma unroll
        for (int g = 0; g < 16; ++g)
          sum += pslab[(hh3 * 16 + (s >> 2)) * 68 + g * 4 + (s & 3)];
        float* rvD = RVT + (t & 1) * 8192;
        st_sc(&rvD[((2 * hp + hh3) * 64 + s) * 32 + b], sum / denom);
      }
      bumpC(CRV);
      // ring update with wv_t (off critical path)
      waitC(CWV, 4 * (t + 1));
      {
        int ip = start + 249; if (ip >= 250) ip -= 250;
        if (tid < 64) {
          float p0, p1;
          ldpair_sc(&WVPp[(t & 1) * 4096 + b * 64 + tid],
                    &WVPp[(t & 1) * 4096 + 2048 + b * 64 + tid], p0, p1);
          float nv = tanhf(p0 + p1 + bpw[tid]);
          ring[ip * 68 + tid] = nv;
          float n2 = nv * nv;
          #pragma unroll
          for (int off = 32; off; off >>= 1) n2 += __shfl_xor(n2, off, 64);
          if (tid == 0) rn[ip] = rsqrtf(fmaxf(n2, 1e-12f));
        }
      }
      bumpC(CRING);
    }
  } else if (bid < 244) {               // WV: wv partials
    // dyn: W[0,8192) A[8192,17408) part[17408,22016)
    const int kh = (bid - 240) >> 1, cp = (bid - 240) & 1;
    float* W = dyn; float* A = dyn + 8192; float* part = dyn + 17408;
    for (int t = 0; t < 250; ++t) {
      waitC(CHT, 64 * (t + 1));                  // RAW h_t
      if (t >= 2) waitC(CRING, 64 * (t - 1));    // WVP WAR (ATT ring-update done)
      stage_act(A, HT + (t & 1) * 16384 + kh * 8192);
      __syncthreads();
      float2 r;
      E32(W, A, 256, part, r);
      const int c = tid & 31, b2 = (tid >> 5) * 2;
      float* d = WVPp + (t & 1) * 4096 + kh * 2048;
      st_sc(&d[b2 * 64 + cp * 32 + c], r.x);
      st_sc(&d[(b2 + 1) * 64 + cp * 32 + c], r.y);
      bumpC(CWV);
    }
  } else if (bid < 252) {               // COUT
    const int b0 = (bid - 244) * 4;
    for (int t = 1; t <= 250; ++t) {
      waitC(COP, 16 * t);                        // RAW outpre_{t-1}
      caOutB(b0 + 0, t);
      caOutB(b0 + 1, t);
      caOutB(b0 + 2, t);
      caOutB(b0 + 3, t);
      bumpC(CCO);
    }
  }
}

extern "C" void kernel_launch(void* const* d_in, const int* in_sizes, int n_in,
                              void* d_out, int out_size, void* d_ws, size_t ws_size,
                              hipStream_t stream) {
  const float* images = (const float*)d_in[0];
  const int* labels = (const int*)d_in[1];
  const float* k1  = (const float*)d_in[2];
  const float* cb1 = (const float*)d_in[3];
  const float* g1  = (const float*)d_in[4];
  const float* be1 = (const float*)d_in[5];
  const float* mm1 = (const float*)d_in[6];
  const float* mv1 = (const float*)d_in[7];
  const float* k2  = (const float*)d_in[8];
  const float* cb2 = (const float*)d_in[9];
  const float* g2  = (const float*)d_in[10];
  const float* be2 = (const float*)d_in[11];
  const float* mm2 = (const float*)d_in[12];
  const float* mv2 = (const float*)d_in[13];
  const float* k3  = (const float*)d_in[14];
  const float* cb3 = (const float*)d_in[15];
  const float* g3  = (const float*)d_in[16];
  const float* be3 = (const float*)d_in[17];
  const float* mm3 = (const float*)d_in[18];
  const float* mv3 = (const float*)d_in[19];
  const float* Wx  = (const float*)d_in[20];
  const float* Wh  = (const float*)d_in[21];
  const float* bl  = (const float*)d_in[22];
  const float* Wp  = (const float*)d_in[23];
  const float* bp  = (const float*)d_in[24];
  const float* Wo  = (const float*)d_in[25];
  const float* bo  = (const float*)d_in[26];
  const float* Wf  = (const float*)d_in[27];
  const float* bf  = (const float*)d_in[28];
  float* ws = (float*)d_ws;

  hipFuncSetAttribute((const void*)lstm_kernel,
                      hipFuncAttributeMaxDynamicSharedMemorySize, DYN_BYTES);

  // zero activation/state/counter region (ws poisoned 0xAA before each call)
  hipMemsetAsync((char*)d_ws + OFF_ZP0 * sizeof(float), 0,
                 (WS_FLOATS - OFF_ZP0) * sizeof(float), stream);
  prep_kernel<<<1024, 256, 0, stream>>>(Wx, Wh, bl, Wp, ws);
  conv_kernel<<<8000, 128, 0, stream>>>(images,
      k1, cb1, g1, be1, mm1, mv1,
      k2, cb2, g2, be2, mm2, mv2,
      k3, cb3, g3, be3, mm3, mv3, ws);
  lstm_kernel<<<256, 512, DYN_BYTES, stream>>>(labels, Wo, bo, Wp, bp, Wf, bf, ws,
                                               (float*)d_out);
}

// Round 3
// 3935.167 us; speedup vs baseline: 1.5183x; 1.1903x over previous
//
#include <hip/hip_runtime.h>

// ---------------- problem constants ----------------
// B=32, T=250, FEAT=128, CLASSES=25, UNITS=512, CELL=64, HEADS=4, IN_LSTM=409

// ---------------- scratch layout (floats) ----------------
// All inter-block activations are (value,epoch) PAIRS (2 floats / 8 B, stored
// atomically): no producer drain, no separate flag, consumer spin = 1 LLC RTT.
constexpr size_t OFF_FEATP  = 0;                              // [8000][128]
constexpr size_t OFF_WXI    = OFF_FEATP + (size_t)8000 * 128; // [409][2048] gate-interleaved
constexpr size_t OFF_WHI    = OFF_WXI + (size_t)409 * 2048;   // [512][2048]
constexpr size_t OFF_BLI    = OFF_WHI + (size_t)512 * 2048;   // [2048]
constexpr size_t OFF_ZP2    = OFF_BLI + 2048;                 // [2][32][2048]p
constexpr size_t OFF_OH2A   = OFF_ZP2 + 262144;               // [2][32][512]p
constexpr size_t OFF_OH2B   = OFF_OH2A + 65536;               // [2][32][512]p
constexpr size_t OFF_OUTPRE2= OFF_OH2B + 65536;               // [32][512]p
constexpr size_t OFF_HT2    = OFF_OUTPRE2 + 32768;            // [2][512][32]p
constexpr size_t OFF_HTT2   = OFF_HT2 + 65536;                // [2][32][512]p
constexpr size_t OFF_RVT2   = OFF_HTT2 + 65536;               // [2][256][32]p
constexpr size_t OFF_WVP2   = OFF_RVT2 + 32768;               // [2][2][32][64]p
constexpr size_t OFF_BAR    = OFF_WVP2 + 16384;               // counters (4096 ints)
constexpr size_t OFF_WPT    = OFF_BAR + 4096;                 // [128][320][4] k-major Wp
constexpr size_t WS_FLOATS  = OFF_WPT + (size_t)163840;

constexpr int DYN_FLOATS = 34816;                 // 136 KB dynamic LDS
constexpr int DYN_BYTES  = DYN_FLOATS * 4;

// WAR-slack counters only (8 lines x 64-int stride each). RAW sync is via tags.
constexpr int COH = 0, COP = 512, CCO = 1024, CRING = 1536;

__device__ __forceinline__ float sigm(float x) { return 1.f / (1.f + __expf(-x)); }

typedef int iv2 __attribute__((ext_vector_type(2)));
typedef int iv4 __attribute__((ext_vector_type(4)));

// ---- LLC-coherent accesses (bypass L1+L2). Batched loads with the waitcnt
// inside the asm so they are one round trip.
__device__ __forceinline__ void st_pair(float* base, size_t pidx, float v, int tag) {
  unsigned long long u = (unsigned long long)__float_as_uint(v) |
                         ((unsigned long long)(unsigned)tag << 32);
  __hip_atomic_store((unsigned long long*)(base + 2 * pidx), u,
                     __ATOMIC_RELAXED, __HIP_MEMORY_SCOPE_AGENT);
}
__device__ __forceinline__ float spin_pair(const float* base, size_t pidx, int tag) {
  const iv2* p = (const iv2*)(base + 2 * pidx);
  iv2 v;
  for (;;) {
    asm volatile("global_load_dwordx2 %0, %1, off sc0 sc1\n\ts_waitcnt vmcnt(0)"
                 : "=&v"(v) : "v"(p) : "memory");
    if (v[1] == tag) break;
    __builtin_amdgcn_s_sleep(1);
  }
  return __int_as_float(v[0]);
}
// two consecutive pairs (one dwordx4)
__device__ __forceinline__ float2 spin_pair2(const float* base, size_t pidx, int tag) {
  const iv4* p = (const iv4*)(base + 2 * pidx);
  iv4 v;
  for (;;) {
    asm volatile("global_load_dwordx4 %0, %1, off sc0 sc1\n\ts_waitcnt vmcnt(0)"
                 : "=&v"(v) : "v"(p) : "memory");
    if (v[1] == tag && v[3] == tag) break;
    __builtin_amdgcn_s_sleep(1);
  }
  return {__int_as_float(v[0]), __int_as_float(v[2])};
}
// two pairs at separate addresses
__device__ __forceinline__ float2 spin_pair_2addr(const float* a, const float* b, int tag) {
  const iv2* pa = (const iv2*)a;
  const iv2* pb = (const iv2*)b;
  iv2 x, y;
  for (;;) {
    asm volatile(
        "global_load_dwordx2 %0, %2, off sc0 sc1\n\t"
        "global_load_dwordx2 %1, %3, off sc0 sc1\n\t"
        "s_waitcnt vmcnt(0)"
        : "=&v"(x), "=&v"(y) : "v"(pa), "v"(pb) : "memory");
    if (x[1] == tag && y[1] == tag) break;
    __builtin_amdgcn_s_sleep(1);
  }
  return {__int_as_float(x[0]), __int_as_float(y[0])};
}
__device__ __forceinline__ void ld8i4_sc(const iv4* b0, iv4* v) {
  const iv4 *p0 = b0, *p1 = b0 + 512, *p2 = b0 + 1024, *p3 = b0 + 1536,
            *p4 = b0 + 2048, *p5 = b0 + 2560, *p6 = b0 + 3072, *p7 = b0 + 3584;
  asm volatile(
      "global_load_dwordx4 %0, %8, off sc0 sc1\n\t"
      "global_load_dwordx4 %1, %9, off sc0 sc1\n\t"
      "global_load_dwordx4 %2, %10, off sc0 sc1\n\t"
      "global_load_dwordx4 %3, %11, off sc0 sc1\n\t"
      "global_load_dwordx4 %4, %12, off sc0 sc1\n\t"
      "global_load_dwordx4 %5, %13, off sc0 sc1\n\t"
      "global_load_dwordx4 %6, %14, off sc0 sc1\n\t"
      "global_load_dwordx4 %7, %15, off sc0 sc1\n\t"
      "s_waitcnt vmcnt(0)"
      : "=&v"(v[0]), "=&v"(v[1]), "=&v"(v[2]), "=&v"(v[3]),
        "=&v"(v[4]), "=&v"(v[5]), "=&v"(v[6]), "=&v"(v[7])
      : "v"(p0), "v"(p1), "v"(p2), "v"(p3), "v"(p4), "v"(p5), "v"(p6), "v"(p7)
      : "memory");
}
__device__ __forceinline__ void ld10i4_sc(const iv4* b0, const iv4* z0,
                                          const iv4* z1, iv4* v) {
  const iv4 *p0 = b0, *p1 = b0 + 512, *p2 = b0 + 1024, *p3 = b0 + 1536,
            *p4 = b0 + 2048, *p5 = b0 + 2560, *p6 = b0 + 3072, *p7 = b0 + 3584;
  asm volatile(
      "global_load_dwordx4 %0, %10, off sc0 sc1\n\t"
      "global_load_dwordx4 %1, %11, off sc0 sc1\n\t"
      "global_load_dwordx4 %2, %12, off sc0 sc1\n\t"
      "global_load_dwordx4 %3, %13, off sc0 sc1\n\t"
      "global_load_dwordx4 %4, %14, off sc0 sc1\n\t"
      "global_load_dwordx4 %5, %15, off sc0 sc1\n\t"
      "global_load_dwordx4 %6, %16, off sc0 sc1\n\t"
      "global_load_dwordx4 %7, %17, off sc0 sc1\n\t"
      "global_load_dwordx4 %8, %18, off sc0 sc1\n\t"
      "global_load_dwordx4 %9, %19, off sc0 sc1\n\t"
      "s_waitcnt vmcnt(0)"
      : "=&v"(v[0]), "=&v"(v[1]), "=&v"(v[2]), "=&v"(v[3]), "=&v"(v[4]),
        "=&v"(v[5]), "=&v"(v[6]), "=&v"(v[7]), "=&v"(v[8]), "=&v"(v[9])
      : "v"(p0), "v"(p1), "v"(p2), "v"(p3), "v"(p4), "v"(p5), "v"(p6), "v"(p7),
        "v"(z0), "v"(z1)
      : "memory");
}
// counter poll: sum of 8 lines, single batched round trip
__device__ __forceinline__ int sum8_bar(const int* b) {
  int v0, v1, v2, v3, v4, v5, v6, v7;
  asm volatile(
      "global_load_dword %0, %8, off sc0 sc1\n\t"
      "global_load_dword %1, %9, off sc0 sc1\n\t"
      "global_load_dword %2, %10, off sc0 sc1\n\t"
      "global_load_dword %3, %11, off sc0 sc1\n\t"
      "global_load_dword %4, %12, off sc0 sc1\n\t"
      "global_load_dword %5, %13, off sc0 sc1\n\t"
      "global_load_dword %6, %14, off sc0 sc1\n\t"
      "global_load_dword %7, %15, off sc0 sc1\n\t"
      "s_waitcnt vmcnt(0)"
      : "=&v"(v0), "=&v"(v1), "=&v"(v2), "=&v"(v3),
        "=&v"(v4), "=&v"(v5), "=&v"(v6), "=&v"(v7)
      : "v"(b), "v"(b + 64), "v"(b + 128), "v"(b + 192),
        "v"(b + 256), "v"(b + 320), "v"(b + 384), "v"(b + 448)
      : "memory");
  return ((v0 + v1) + (v2 + v3)) + ((v4 + v5) + (v6 + v7));
}

// ---------------- weight re-layout: gate-interleaved Wx/Wh/bl + k-major Wp ----------------
__global__ __launch_bounds__(256) void prep_kernel(const float* __restrict__ Wx,
                                                   const float* __restrict__ Wh,
                                                   const float* __restrict__ bl,
                                                   const float* __restrict__ Wp,
                                                   float* __restrict__ ws) {
  float* WXI = ws + OFF_WXI;
  float* WHI = ws + OFF_WHI;
  float* BLI = ws + OFF_BLI;
  float* WPT = ws + OFF_WPT;
  const int t0 = 409 * 2048;
  const int t1 = t0 + 512 * 2048;
  const int t2 = t1 + 2048;
  const int total = t2 + 163840;
  for (int idx = blockIdx.x * blockDim.x + threadIdx.x; idx < total;
       idx += gridDim.x * blockDim.x) {
    if (idx < t0) {
      int k = idx >> 11, cc = idx & 2047;
      WXI[idx] = Wx[(size_t)k * 2048 + (cc & 3) * 512 + (cc >> 2)];
    } else if (idx < t1) {
      int j = idx - t0;
      int k = j >> 11, cc = j & 2047;
      WHI[j] = Wh[(size_t)k * 2048 + (cc & 3) * 512 + (cc >> 2)];
    } else if (idx < t2) {
      int cc = idx - t1;
      BLI[cc] = bl[(cc & 3) * 512 + (cc >> 2)];
    } else {
      // WPT[k4][j][ks] = Wp[k4*4+ks][j]
      int e = idx - t2;
      int k4 = e / 1280, r = e - k4 * 1280;
      int j = r >> 2, ks = r & 3;
      WPT[e] = Wp[(size_t)(k4 * 4 + ks) * 320 + j];
    }
  }
}

// ---------------- conv stack (validated) ----------------
__global__ __launch_bounds__(128) void conv_kernel(
    const float* __restrict__ img,
    const float* __restrict__ k1, const float* __restrict__ cb1, const float* __restrict__ g1,
    const float* __restrict__ be1, const float* __restrict__ mm1, const float* __restrict__ mv1,
    const float* __restrict__ k2, const float* __restrict__ cb2, const float* __restrict__ g2,
    const float* __restrict__ be2, const float* __restrict__ mm2, const float* __restrict__ mv2,
    const float* __restrict__ k3, const float* __restrict__ cb3, const float* __restrict__ g3,
    const float* __restrict__ be3, const float* __restrict__ mm3, const float* __restrict__ mv3,
    float* __restrict__ ws) {
  __shared__ float s_in[784];
  __shared__ float s_y1[13 * 13 * 8];
  __shared__ float s_y2[6 * 6 * 16];
  __shared__ float s_k1[72], s_k2[1152], s_k3[4608];
  __shared__ float s_s1[8], s_b1[8], s_s2[16], s_b2[16], s_s3[32], s_b3[32];
  float* FEATP = ws + OFF_FEATP;
  const int n = blockIdx.x, tid = threadIdx.x;
  const float* ip = img + (size_t)n * 784;
  for (int i = tid; i < 784; i += 128) s_in[i] = ip[i];
  for (int i = tid; i < 72; i += 128) s_k1[i] = k1[i];
  for (int i = tid; i < 1152; i += 128) s_k2[i] = k2[i];
  for (int i = tid; i < 4608; i += 128) s_k3[i] = k3[i];
  if (tid < 8) {
    float s = g1[tid] * rsqrtf(mv1[tid] + 1e-3f);
    s_s1[tid] = s; s_b1[tid] = (cb1[tid] - mm1[tid]) * s + be1[tid];
  } else if (tid >= 32 && tid < 48) {
    int c = tid - 32;
    float s = g2[c] * rsqrtf(mv2[c] + 1e-3f);
    s_s2[c] = s; s_b2[c] = (cb2[c] - mm2[c]) * s + be2[c];
  } else if (tid >= 64 && tid < 96) {
    int c = tid - 64;
    float s = g3[c] * rsqrtf(mv3[c] + 1e-3f);
    s_s3[c] = s; s_b3[c] = (cb3[c] - mm3[c]) * s + be3[c];
  }
  __syncthreads();
  for (int idx = tid; idx < 13 * 13 * 8; idx += 128) {
    int co = idx & 7, pos = idx >> 3;
    int j = pos % 13, i = pos / 13;
    float acc = 0.f;
    #pragma unroll
    for (int ky = 0; ky < 3; ++ky)
      #pragma unroll
      for (int kx = 0; kx < 3; ++kx)
        acc += s_in[(2 * i + ky) * 28 + (2 * j + kx)] * s_k1[(ky * 3 + kx) * 8 + co];
    float v = acc * s_s1[co] + s_b1[co];
    s_y1[idx] = v > 0.f ? v : 0.f;
  }
  __syncthreads();
  for (int idx = tid; idx < 6 * 6 * 16; idx += 128) {
    int co = idx & 15, pos = idx >> 4;
    int j = pos % 6, i = pos / 6;
    float acc = 0.f;
    for (int ky = 0; ky < 3; ++ky)
      for (int kx = 0; kx < 3; ++kx) {
        int base = ((2 * i + ky) * 13 + (2 * j + kx)) * 8;
        int kb = (ky * 3 + kx) * 128 + co;
        #pragma unroll
        for (int ci = 0; ci < 8; ++ci) acc += s_y1[base + ci] * s_k2[kb + ci * 16];
      }
    float v = acc * s_s2[co] + s_b2[co];
    s_y2[idx] = v > 0.f ? v : 0.f;
  }
  __syncthreads();
  for (int idx = tid; idx < 128; idx += 128) {
    int co = idx & 31, pos = idx >> 5;
    int j = pos & 1, i = pos >> 1;
    float acc = 0.f;
    for (int ky = 0; ky < 3; ++ky)
      for (int kx = 0; kx < 3; ++kx) {
        int base = ((2 * i + ky) * 6 + (2 * j + kx)) * 16;
        int kb = (ky * 3 + kx) * 512 + co;
        #pragma unroll
        for (int ci = 0; ci < 16; ++ci) acc += s_y2[base + ci] * s_k3[kb + ci * 32];
      }
    float v = acc * s_s3[co] + s_b3[co];
    FEATP[(size_t)n * 128 + idx] = v > 0.f ? v : 0.f;
  }
}

// ---------------- persistent LSTM scan: tagged-pair dataflow ----------------
// Roles: AZ 0-63 | AO 64-79 | ZH 80-143 | OL 144-159 / OHI 160-175 |
// ATT 176-239 | WV 240-243 | COUT 244-251 | 252-255 idle.
// Epochs: h_t/rv_t/ZP_t/OH_t/WVP_t -> tag t+1; OUTPRE (AO step t) -> tag t.
// Zeroed buffers (tag 0) ARE the t=0 zero state.
__global__ __launch_bounds__(512) void lstm_kernel(
    const int* __restrict__ labels,
    const float* __restrict__ Wo, const float* __restrict__ bo,
    const float* __restrict__ Wp, const float* __restrict__ bp,
    const float* __restrict__ Wf, const float* __restrict__ bf,
    float* __restrict__ ws, float* __restrict__ out) {
  extern __shared__ float dyn[];
  const float* FEATP = ws + OFF_FEATP;
  const float* WXI   = ws + OFF_WXI;
  const float* WHI   = ws + OFF_WHI;
  const float* BLI   = ws + OFF_BLI;
  float* ZP2    = ws + OFF_ZP2;     // [2][32][2048]p
  float* OH2A   = ws + OFF_OH2A;    // [2][32][512]p
  float* OH2B   = ws + OFF_OH2B;
  float* OUTPRE2= ws + OFF_OUTPRE2; // [32][512]p
  float* HT2    = ws + OFF_HT2;     // [2][512][32]p
  float* HTT2   = ws + OFF_HTT2;    // [2][32][512]p
  float* RVT2   = ws + OFF_RVT2;    // [2][256][32]p
  float* WVP2   = ws + OFF_WVP2;    // [2][2][32][64]p
  const float* WPT = ws + OFF_WPT;  // [128][320][4]
  int*   BARp   = (int*)(ws + OFF_BAR);

  const int bid = blockIdx.x;
  const int tid = threadIdx.x;

  auto waitC = [&](int base, int target) {
    if (tid == 0) {
      while (sum8_bar(BARp + base) < target) {}
    }
    __syncthreads();
  };
  auto bumpC = [&](int base) {
    asm volatile("s_waitcnt vmcnt(0)" ::: "memory");
    __syncthreads();
    if (tid == 0) atomicAdd(&BARp[base + ((bid & 7) << 6)], 1);
  };

  // spin-stage an 8192-value pair buffer ([256][32]p) into [256][36] LDS tile
  auto stageP = [&](float* dst, const float* srcPairs, int tag) {
    const iv4* sp = (const iv4*)srcPairs + tid;
    iv4 v[8];
    for (;;) {
      ld8i4_sc(sp, v);
      bool ok = true;
      #pragma unroll
      for (int j = 0; j < 8; ++j) ok = ok && (v[j][1] == tag) && (v[j][3] == tag);
      if (ok) break;
      __builtin_amdgcn_s_sleep(2);
    }
    #pragma unroll
    for (int j = 0; j < 8; ++j) {
      int i = (tid + j * 512) << 1;
      float2 f = {__int_as_float(v[j][0]), __int_as_float(v[j][2])};
      *(float2*)&dst[(i >> 5) * 36 + (i & 31)] = f;
    }
  };

  // ---- E32: Y[32c][32b] (validated). K mult of 16.
  auto E32 = [&](const float* Wm, const float* Am, int K, float* part, float2& r) {
    const int wv = tid >> 6, l = tid & 63;
    const int ksub = l & 1, cg = (l >> 1) & 3, bg = l >> 3;
    const int Kp = K >> 4;
    const int kb = wv * (K >> 3) + ksub * Kp;
    const float* wp = Wm + (size_t)kb * 32 + cg * 8;
    const float* ap = Am + (size_t)kb * 36 + bg * 4;
    float4 acc[8];
    #pragma unroll
    for (int i = 0; i < 8; ++i) acc[i] = {0.f, 0.f, 0.f, 0.f};
    #pragma unroll 4
    for (int kk = 0; kk < Kp; ++kk) {
      float4 w0 = *(const float4*)(wp + kk * 32);
      float4 w1 = *(const float4*)(wp + kk * 32 + 4);
      float4 a  = *(const float4*)(ap + kk * 36);
      float wl[8];
      *(float4*)&wl[0] = w0; *(float4*)&wl[4] = w1;
      #pragma unroll
      for (int i = 0; i < 8; ++i) {
        acc[i].x = fmaf(wl[i], a.x, acc[i].x);
        acc[i].y = fmaf(wl[i], a.y, acc[i].y);
        acc[i].z = fmaf(wl[i], a.z, acc[i].z);
        acc[i].w = fmaf(wl[i], a.w, acc[i].w);
      }
    }
    #pragma unroll
    for (int i = 0; i < 8; ++i) {
      acc[i].x += __shfl_xor(acc[i].x, 1, 64);
      acc[i].y += __shfl_xor(acc[i].y, 1, 64);
      acc[i].z += __shfl_xor(acc[i].z, 1, 64);
      acc[i].w += __shfl_xor(acc[i].w, 1, 64);
    }
    const int ob = (cg * 8) * 36 + bg * 4;
    if (ksub == 0 && wv < 4) {
      float* pb = part + wv * 1152 + ob;
      #pragma unroll
      for (int i = 0; i < 8; ++i) *(float4*)(pb + i * 36) = acc[i];
    }
    __syncthreads();
    if (ksub == 0 && wv >= 4) {
      float* pb = part + (wv - 4) * 1152 + ob;
      #pragma unroll
      for (int i = 0; i < 8; ++i) {
        float4 t = *(float4*)(pb + i * 36);
        t.x += acc[i].x; t.y += acc[i].y; t.z += acc[i].z; t.w += acc[i].w;
        *(float4*)(pb + i * 36) = t;
      }
    }
    __syncthreads();
    const int c = tid & 31, b2 = (tid >> 5) * 2;
    const int o = c * 36 + b2;
    float2 s0 = *(float2*)(part + o);
    float2 s1 = *(float2*)(part + 1152 + o);
    float2 s2 = *(float2*)(part + 2304 + o);
    float2 s3 = *(float2*)(part + 3456 + o);
    r.x = (s0.x + s1.x) + (s2.x + s3.x);
    r.y = (s0.y + s1.y) + (s2.y + s3.y);
  };

  // ---------------- one-time init: weights -> LDS ----------------
  if (bid < 64) {            // AZ: Wz (rv part of Wx) + Wxx (x part)
    const int c0 = bid * 32;
    for (int i = tid; i < 8192; i += 512)
      dyn[i] = WXI[(size_t)(153 + (i >> 5)) * 2048 + c0 + (i & 31)];
    for (int i = tid; i < 4096; i += 512)
      dyn[8192 + i] = WXI[(size_t)(i >> 5) * 2048 + c0 + (i & 31)];
    if (tid < 256) dyn[12288 + tid] = 0.f;  // Cst
  } else if (bid < 80) {     // AO: Wo rows 512..768
    const int u0 = (bid - 64) * 32;
    for (int i = tid; i < 8192; i += 512)
      dyn[i] = Wo[(size_t)(512 + (i >> 5)) * 512 + u0 + (i & 31)];
    if (tid < 32) dyn[8192 + tid] = bo[u0 + tid];
  } else if (bid < 144) {    // ZH: full Wh column slab [512][32]
    const int c0 = (bid - 80) * 32;
    for (int i = tid; i < 16384; i += 512)
      dyn[i] = WHI[(size_t)(i >> 5) * 2048 + c0 + (i & 31)];
    if (tid < 32) dyn[16384 + tid] = BLI[c0 + tid];
  } else if (bid < 160) {    // OL: Wo rows 0..256
    const int u0 = (bid - 144) * 32;
    for (int i = tid; i < 8192; i += 512)
      dyn[i] = Wo[(size_t)(i >> 5) * 512 + u0 + (i & 31)];
  } else if (bid < 176) {    // OHI: Wo rows 256..512
    const int u0 = (bid - 160) * 32;
    for (int i = tid; i < 8192; i += 512)
      dyn[i] = Wo[(size_t)(256 + (i >> 5)) * 512 + u0 + (i & 31)];
  } else if (bid < 240) {    // ATT: ring + cached norms + bias slices
    const int hp = (bid - 176) & 1;
    for (int i = tid; i < 17000; i += 512) dyn[i] = 0.f;            // ring[250][68]
    if (tid < 256) dyn[17000 + tid] = rsqrtf(1e-12f);               // rn
    if (tid < 128) dyn[21264 + tid] = bp[64 + hp * 128 + tid];      // bpk
    if (tid < 64)  dyn[21392 + tid] = bp[tid];                      // bpw
  } else if (bid < 244) {    // WV: Wp[kh*256..+256][cp*32..+32]
    const int kh = (bid - 240) >> 1, cp = (bid - 240) & 1;
    for (int i = tid; i < 8192; i += 512) {
      int k = i >> 5, c = i & 31;
      dyn[i] = Wp[(size_t)(kh * 256 + k) * 320 + cp * 32 + c];
    }
  } else if (bid < 252) {    // COUT: Wf + bf
    for (int i = tid; i < 12800; i += 512) dyn[i] = Wf[i];
    if (tid < 25) dyn[12800 + tid] = bf[tid];
  }
  __syncthreads();

  // ================= role bodies =================
  // AZ dyn: Wz[0,8192) Wxx[8192,12288) Cst[12288,12544) rvT[12544,21760)
  //         xT[21760,26368) zx[26368,27392) zf[27392,28416) part[28416,33024)
  auto azPre = [&](int t) {           // ZP_t pairs -> zf (spin)
    const int c0 = bid * 32;
    const float* zpP = ZP2 + (t & 1) * 131072;
    float* zf = dyn + 27392;
    const int bb = tid >> 4, c2 = tid & 15;
    float2 x = spin_pair2(zpP, (size_t)bb * 2048 + c0 + c2 * 2, t + 1);
    *(float2*)&zf[bb * 32 + c2 * 2] = x;
  };
  auto azGatesMain = [&](int t) {
    const float* rvP = RVT2 + ((t + 1) & 1) * 16384;   // rv_{t-1} pairs, tag t
    float* Wz = dyn; float* Cst = dyn + 12288; float* rvT = dyn + 12544;
    float* zx = dyn + 26368; float* zf = dyn + 27392; float* part = dyn + 28416;
    stageP(rvT, rvP, t);
    __syncthreads();
    float2 r;
    E32(Wz, rvT, 256, part, r);
    const int c = tid & 31, b2 = (tid >> 5) * 2;
    zf[b2 * 32 + c] += r.x + zx[b2 * 32 + c];
    zf[(b2 + 1) * 32 + c] += r.y + zx[(b2 + 1) * 32 + c];
    __syncthreads();
    if (tid < 256) {
      int u = tid & 7, b = tid >> 3;
      float4 z = *(float4*)(zf + b * 32 + u * 4);
      float ig = sigm(z.x), fg = sigm(z.y), gg = tanhf(z.z), og = sigm(z.w);
      float cc = fg * Cst[b * 8 + u] + ig * gg;
      Cst[b * 8 + u] = cc;
      float hv = og * tanhf(cc);
      st_pair(HT2 + (t & 1) * 32768, (size_t)(bid * 8 + u) * 32 + b, hv, t + 1);
      st_pair(HTT2 + (t & 1) * 32768, (size_t)b * 512 + bid * 8 + u, hv, t + 1);
    }
  };
  auto azX = [&](int tt) {    // zx = x_{tt}@Wx, local
    float* Wxx = dyn + 8192; float* xT = dyn + 21760;
    float* zx = dyn + 26368; float* part = dyn + 28416;
    for (int i = tid; i < 4096; i += 512) {
      int b = i >> 7, k = i & 127;
      xT[k * 36 + b] = FEATP[((size_t)b * 250 + tt) * 128 + k];
    }
    __syncthreads();
    float2 r;
    E32(Wxx, xT, 128, part, r);
    const int c = tid & 31, b2 = (tid >> 5) * 2;
    zx[b2 * 32 + c] = r.x;
    zx[(b2 + 1) * 32 + c] = r.y;
  };
  // AO dyn: W[0,8192) bo[8192,8224) rvT[8224,17440) of[17440,18464) part[18464,23072)
  auto aoOut = [&](int t) {   // outpre_{t-1}: rv_{t-1} (tag t), OH_{t-1} (tag t)
    const int u0 = (bid - 64) * 32;
    const float* rvP  = RVT2 + ((t + 1) & 1) * 16384;
    const float* ohaP = OH2A + ((t + 1) & 1) * 32768;
    const float* ohbP = OH2B + ((t + 1) & 1) * 32768;
    float* W = dyn; float* bo_l = dyn + 8192; float* rvT = dyn + 8224;
    float* of = dyn + 17440; float* part = dyn + 18464;
    {
      const int b = tid >> 4, c2 = tid & 15;
      const iv4* rp = (const iv4*)rvP + tid;
      const iv4* za = (const iv4*)ohaP + (b * 256 + (u0 >> 1) + c2);
      const iv4* zb = (const iv4*)ohbP + (b * 256 + (u0 >> 1) + c2);
      iv4 v[10];
      for (;;) {
        ld10i4_sc(rp, za, zb, v);
        bool ok = true;
        #pragma unroll
        for (int j = 0; j < 10; ++j) ok = ok && (v[j][1] == t) && (v[j][3] == t);
        if (ok) break;
        __builtin_amdgcn_s_sleep(2);
      }
      #pragma unroll
      for (int j = 0; j < 8; ++j) {
        int i = (tid + j * 512) << 1;
        float2 f = {__int_as_float(v[j][0]), __int_as_float(v[j][2])};
        *(float2*)&rvT[(i >> 5) * 36 + (i & 31)] = f;
      }
      float2 s = {__int_as_float(v[8][0]) + __int_as_float(v[9][0]),
                  __int_as_float(v[8][2]) + __int_as_float(v[9][2])};
      *(float2*)&of[b * 32 + c2 * 2] = s;
    }
    __syncthreads();
    float2 r;
    E32(W, rvT, 256, part, r);
    const int c = tid & 31, b2 = (tid >> 5) * 2;
    float bv = bo_l[c];
    st_pair(OUTPRE2, (size_t)b2 * 512 + u0 + c, r.x + of[b2 * 32 + c] + bv, t);
    st_pair(OUTPRE2, (size_t)(b2 + 1) * 512 + u0 + c, r.y + of[(b2 + 1) * 32 + c] + bv, t);
  };
  // ZH dyn: W[0,16384) blc[16384,16416) slab[16416,16448) A[16448,25664) part[25664,30272)
  auto zhLab = [&](int s) {
    __syncthreads();
    int* slab = (int*)(dyn + 16416);
    if (tid < 32) slab[tid] = labels[tid * 250 + s];
  };
  auto zhGemm = [&](int s) {  // ZP_s = h_{s-1}@Wh + bl + Wx[onehot label_s]
    const int c0 = (bid - 80) * 32;
    const float* htP = HT2 + ((s + 1) & 1) * 32768;  // h_{s-1} pairs, tag s
    float* zpD = ZP2 + (s & 1) * 131072;
    float* W = dyn; float* blc = dyn + 16384; int* slab = (int*)(dyn + 16416);
    float* A = dyn + 16448; float* part = dyn + 25664;
    stageP(A, htP, s);
    __syncthreads();
    float2 r1;
    E32(W, A, 256, part, r1);
    __syncthreads();           // part WAR before second pass
    stageP(A, htP + 16384, s);
    __syncthreads();
    float2 r2;
    E32(W + 8192, A, 256, part, r2);
    const int c = tid & 31, b2 = (tid >> 5) * 2;
    float base = blc[c];
    int l0 = slab[b2], l1 = slab[b2 + 1];
    st_pair(zpD, (size_t)b2 * 2048 + c0 + c,
            r1.x + r2.x + base + WXI[(size_t)(128 + l0) * 2048 + c0 + c], s + 1);
    st_pair(zpD, (size_t)(b2 + 1) * 2048 + c0 + c,
            r1.y + r2.y + base + WXI[(size_t)(128 + l1) * 2048 + c0 + c], s + 1);
  };
  // OL/OHI dyn: W[0,8192) A[8192,17408) part[17408,22016)
  auto p2Gemm = [&](int t) {
    const float* htP = HT2 + (t & 1) * 32768;
    float* W = dyn; float* A = dyn + 8192; float* part = dyn + 17408;
    const bool isOLr = bid < 160;
    stageP(A, isOLr ? htP : (htP + 16384), t + 1);
    __syncthreads();
    float2 r;
    E32(W, A, 256, part, r);
    const int c = tid & 31, b2 = (tid >> 5) * 2;
    const int u0 = (isOLr ? (bid - 144) : (bid - 160)) * 32;
    float* d = (isOLr ? OH2A : OH2B) + (t & 1) * 32768;
    st_pair(d, (size_t)b2 * 512 + u0 + c, r.x, t + 1);
    st_pair(d, (size_t)(b2 + 1) * 512 + u0 + c, r.y, t + 1);
  };
  // COUT dyn: Wf[0,12800) bf[12800,12825) to[12832,13344) lp[13344,13744) lg[13744,13771)
  auto caOutB = [&](int b, int t) {
    float* WfL = dyn; float* bfL = dyn + 12800;
    float* to = dyn + 12832; float* lp = dyn + 13344; float* lg = dyn + 13744;
    to[tid] = tanhf(spin_pair(OUTPRE2, (size_t)b * 512 + tid, t));
    __syncthreads();
    if (tid < 400) {
      int l = tid % 25, p = tid / 25;
      float s = 0.f;
      #pragma unroll
      for (int q = 0; q < 32; ++q) { int k = p * 32 + q; s += to[k] * WfL[k * 25 + l]; }
      lp[p * 25 + l] = s;
    }
    __syncthreads();
    if (tid < 25) {
      float s = bfL[tid];
      #pragma unroll
      for (int p = 0; p < 16; ++p) s += lp[p * 25 + tid];
      lg[tid] = s;
    }
    __syncthreads();
    if (tid == 0) {
      float mx = lg[0];
      for (int l = 1; l < 25; ++l) mx = fmaxf(mx, lg[l]);
      float ss = 0.f;
      for (int l = 0; l < 25; ++l) ss += __expf(lg[l] - mx);
      lg[25] = mx; lg[26] = 1.f / ss;
    }
    __syncthreads();
    if (tid < 25)
      out[((size_t)b * 250 + (t - 1)) * 25 + tid] = __expf(lg[tid] - lg[25]) * lg[26];
    __syncthreads();
  };

  // ---------------- dataflow role loops ----------------
  if (bid < 64) {                       // AZ
    azX(0);
    for (int t = 0; t < 250; ++t) {
      azPre(t);                                  // RAW ZP_t via tags
      if (t >= 2) waitC(COH, 32 * (t - 1));      // HT WAR: OL/OHI_{t-2} read done
      azGatesMain(t);                            // RAW rv_{t-1} via tags; h pairs out
      if (t < 249) azX(t + 1);
    }
  } else if (bid < 80) {                // AO
    for (int t = 1; t <= 250; ++t) {
      if (t >= 2) waitC(CCO, 8 * (t - 1));       // OUTPRE WAR: COUT_{t-1} read done
      aoOut(t);                                  // RAW rv/OH via tags
      bumpC(COP);
    }
  } else if (bid < 144) {               // ZH (pure tag-driven)
    for (int s = 0; s < 250; ++s) {
      zhLab(s);
      zhGemm(s);                                 // RAW h_{s-1} via tags (s=0: zeros)
    }
  } else if (bid < 176) {               // OL / OHI
    for (int t = 0; t < 250; ++t) {
      if (t >= 2) waitC(COP, 16 * (t - 1));      // OH WAR: AO_{t-1} read done
      p2Gemm(t);                                 // RAW h_t via tags
      bumpC(COH);
    }
  } else if (bid < 240) {               // ATT: keys + attention + rv
    float* ring = dyn;
    float* rn   = dyn + 17000;
    float* h_s  = dyn + 17256;
    float* kpart= dyn + 17768;
    float* kv   = dyn + 18280;
    float* kn   = dyn + 18408;
    float* att  = dyn + 18536;
    float* redK = dyn + 19048;
    float* redM = dyn + 19052;
    float* redS = dyn + 19068;
    float* pslab= dyn + 19088;
    float* bpk  = dyn + 21264;
    float* bpw  = dyn + 21392;
    const int b = (bid - 176) >> 1, hp = (bid - 176) & 1;
    const int j = tid & 127, q = tid >> 7;
    const int J = 64 + hp * 128 + j;
    const float4* wbase = (const float4*)WPT + q * 32 * 320 + J;
    for (int t = 0; t < 250; ++t) {
      // prefetch first half of this thread's Wp chunk while waiting for h_t
      float4 pf[16];
      #pragma unroll
      for (int i = 0; i < 16; ++i) pf[i] = wbase[i * 320];
      if (t >= 2) waitC(COP, 16 * (t - 1));      // RVT WAR: AO_{t-1} read done
      h_s[tid] = spin_pair(HTT2 + (t & 1) * 32768, (size_t)b * 512 + tid, t + 1);
      __syncthreads();
      {  // key GEMM
        float a = 0.f;
        #pragma unroll
        for (int i = 0; i < 16; ++i) {
          float4 h4 = *(const float4*)&h_s[q * 128 + i * 4];
          a += pf[i].x * h4.x + pf[i].y * h4.y + pf[i].z * h4.z + pf[i].w * h4.w;
        }
        #pragma unroll 4
        for (int i = 16; i < 32; ++i) {
          float4 w = wbase[i * 320];
          float4 h4 = *(const float4*)&h_s[q * 128 + i * 4];
          a += w.x * h4.x + w.y * h4.y + w.z * h4.z + w.w * h4.w;
        }
        kpart[q * 128 + j] = a;
      }
      __syncthreads();
      if (tid < 128) {
        float kr = kpart[tid] + kpart[128 + tid] + kpart[256 + tid] +
                   kpart[384 + tid] + bpk[tid];
        float v = tanhf(kr);
        kv[tid] = v;
        float pq = v * v;
        #pragma unroll
        for (int off = 32; off; off >>= 1) pq += __shfl_xor(pq, off, 64);
        if ((tid & 63) == 0) redK[tid >> 6] = rsqrtf(fmaxf(pq, 1e-12f));
      }
      __syncthreads();
      if (tid < 128) kn[tid] = kv[tid] * redK[tid >> 6];
      __syncthreads();
      const int start = (250 - t) % 250;
      const int m = tid >> 1, hh = tid & 1;
      {  // dots + softmax (cell norms cached in rn)
        float v;
        if (m < 250) {
          int p = start + m; if (p >= 250) p -= 250;
          const float4* c4 = (const float4*)ring + p * 17;
          const float4* k4 = (const float4*)kn + hh * 16;
          float d = 0.f;
          #pragma unroll
          for (int s4 = 0; s4 < 16; ++s4) {
            float4 cc = c4[s4], kk = k4[s4];
            d += cc.x * kk.x + cc.y * kk.y + cc.z * kk.z + cc.w * kk.w;
          }
          v = d * rn[p];
        } else v = -3.0e38f;
        float mx = v;
        #pragma unroll
        for (int off = 2; off <= 32; off <<= 1) mx = fmaxf(mx, __shfl_xor(mx, off, 64));
        if ((tid & 63) < 2) redM[(tid >> 6) * 2 + (tid & 1)] = mx;
        __syncthreads();
        float MX = redM[hh];
        #pragma unroll
        for (int w = 1; w < 8; ++w) MX = fmaxf(MX, redM[w * 2 + hh]);
        float e = (m < 250) ? __expf(v - MX) : 0.f;
        if (m < 250) att[hh * 256 + m] = e;
        float sm = e;
        #pragma unroll
        for (int off = 2; off <= 32; off <<= 1) sm += __shfl_xor(sm, off, 64);
        if ((tid & 63) < 2) redS[(tid >> 6) * 2 + (tid & 1)] = sm;
      }
      __syncthreads();
      {  // weighted sum into padded partial slabs
        int hh2 = tid >> 8, s4 = (tid >> 4) & 15, g = tid & 15;
        float4 a4 = {0.f, 0.f, 0.f, 0.f};
        for (int mm = g; mm < 250; mm += 16) {
          int p = start + mm; if (p >= 250) p -= 250;
          float w = att[hh2 * 256 + mm];
          float4 cc = ((const float4*)ring)[p * 17 + s4];
          a4.x = fmaf(w, cc.x, a4.x); a4.y = fmaf(w, cc.y, a4.y);
          a4.z = fmaf(w, cc.z, a4.z); a4.w = fmaf(w, cc.w, a4.w);
        }
        *(float4*)&pslab[(hh2 * 16 + s4) * 68 + g * 4] = a4;
      }
      __syncthreads();
      if (tid < 128) {
        int hh3 = tid >> 6, s = tid & 63;
        float denom = redS[hh3];
        #pragma unroll
        for (int w = 1; w < 8; ++w) denom += redS[w * 2 + hh3];
        float sum = 0.f;
        #pragma unroll
        for (int g = 0; g < 16; ++g)
          sum += pslab[(hh3 * 16 + (s >> 2)) * 68 + g * 4 + (s & 3)];
        st_pair(RVT2 + (t & 1) * 16384,
                (size_t)((2 * hp + hh3) * 64 + s) * 32 + b, sum / denom, t + 1);
      }
      __syncthreads();                            // ring readers done before update
      {  // ring update with wv_t (tags; off critical path)
        int ip = start + 249; if (ip >= 250) ip -= 250;
        if (tid < 64) {
          float2 p01 = spin_pair_2addr(
              WVP2 + (t & 1) * 8192 + 2 * ((size_t)b * 64 + tid),
              WVP2 + (t & 1) * 8192 + 4096 + 2 * ((size_t)b * 64 + tid), t + 1);
          float nv = tanhf(p01.x + p01.y + bpw[tid]);
          ring[ip * 68 + tid] = nv;
          float n2 = nv * nv;
          #pragma unroll
          for (int off = 32; off; off >>= 1) n2 += __shfl_xor(n2, off, 64);
          if (tid == 0) rn[ip] = rsqrtf(fmaxf(n2, 1e-12f));
        }
      }
      bumpC(CRING);
    }
  } else if (bid < 244) {               // WV: wv partials
    // dyn: W[0,8192) A[8192,17408) part[17408,22016)
    const int kh = (bid - 240) >> 1, cp = (bid - 240) & 1;
    float* W = dyn; float* A = dyn + 8192; float* part = dyn + 17408;
    for (int t = 0; t < 250; ++t) {
      if (t >= 2) waitC(CRING, 64 * (t - 1));    // WVP WAR: ring-update_{t-2} done
      stageP(A, HT2 + (t & 1) * 32768 + kh * 16384, t + 1);  // RAW h_t via tags
      __syncthreads();
      float2 r;
      E32(W, A, 256, part, r);
      const int c = tid & 31, b2 = (tid >> 5) * 2;
      float* d = WVP2 + (t & 1) * 8192 + kh * 4096;
      st_pair(d, (size_t)b2 * 64 + cp * 32 + c, r.x, t + 1);
      st_pair(d, (size_t)(b2 + 1) * 64 + cp * 32 + c, r.y, t + 1);
    }
  } else if (bid < 252) {               // COUT
    const int b0 = (bid - 244) * 4;
    for (int t = 1; t <= 250; ++t) {
      caOutB(b0 + 0, t);                         // RAW outpre via tags
      caOutB(b0 + 1, t);
      caOutB(b0 + 2, t);
      caOutB(b0 + 3, t);
      bumpC(CCO);
    }
  }
}

extern "C" void kernel_launch(void* const* d_in, const int* in_sizes, int n_in,
                              void* d_out, int out_size, void* d_ws, size_t ws_size,
                              hipStream_t stream) {
  const float* images = (const float*)d_in[0];
  const int* labels = (const int*)d_in[1];
  const float* k1  = (const float*)d_in[2];
  const float* cb1 = (const float*)d_in[3];
  const float* g1  = (const float*)d_in[4];
  const float* be1 = (const float*)d_in[5];
  const float* mm1 = (const float*)d_in[6];
  const float* mv1 = (const float*)d_in[7];
  const float* k2  = (const float*)d_in[8];
  const float* cb2 = (const float*)d_in[9];
  const float* g2  = (const float*)d_in[10];
  const float* be2 = (const float*)d_in[11];
  const float* mm2 = (const float*)d_in[12];
  const float* mv2 = (const float*)d_in[13];
  const float* k3  = (const float*)d_in[14];
  const float* cb3 = (const float*)d_in[15];
  const float* g3  = (const float*)d_in[16];
  const float* be3 = (const float*)d_in[17];
  const float* mm3 = (const float*)d_in[18];
  const float* mv3 = (const float*)d_in[19];
  const float* Wx  = (const float*)d_in[20];
  const float* Wh  = (const float*)d_in[21];
  const float* bl  = (const float*)d_in[22];
  const float* Wp  = (const float*)d_in[23];
  const float* bp  = (const float*)d_in[24];
  const float* Wo  = (const float*)d_in[25];
  const float* bo  = (const float*)d_in[26];
  const float* Wf  = (const float*)d_in[27];
  const float* bf  = (const float*)d_in[28];
  float* ws = (float*)d_ws;

  hipFuncSetAttribute((const void*)lstm_kernel,
                      hipFuncAttributeMaxDynamicSharedMemorySize, DYN_BYTES);

  // zero all pair buffers + counters (tags -> 0 = step-0 zero state)
  hipMemsetAsync((char*)d_ws + OFF_ZP2 * sizeof(float), 0,
                 (OFF_WPT - OFF_ZP2) * sizeof(float), stream);
  prep_kernel<<<1024, 256, 0, stream>>>(Wx, Wh, bl, Wp, ws);
  conv_kernel<<<8000, 128, 0, stream>>>(images,
      k1, cb1, g1, be1, mm1, mv1,
      k2, cb2, g2, be2, mm2, mv2,
      k3, cb3, g3, be3, mm3, mv3, ws);
  lstm_kernel<<<256, 512, DYN_BYTES, stream>>>(labels, Wo, bo, Wp, bp, Wf, bf, ws,
                                               (float*)d_out);
}

// Round 4
// 3844.001 us; speedup vs baseline: 1.5543x; 1.0237x over previous
//
#include <hip/hip_runtime.h>

// ---------------- problem constants ----------------
// B=32, T=250, FEAT=128, CLASSES=25, UNITS=512, CELL=64, HEADS=4, IN_LSTM=409

// ---------------- scratch layout (floats) ----------------
// All inter-block activations are (value,epoch) PAIRS (2 floats / 8 B, stored
// atomically): no producer drain, no separate flag, consumer spin = 1 LLC RTT.
constexpr size_t OFF_FEATP  = 0;                              // [8000][128]
constexpr size_t OFF_WXI    = OFF_FEATP + (size_t)8000 * 128; // [409][2048] gate-interleaved
constexpr size_t OFF_WHI    = OFF_WXI + (size_t)409 * 2048;   // [512][2048]
constexpr size_t OFF_BLI    = OFF_WHI + (size_t)512 * 2048;   // [2048]
constexpr size_t OFF_ZP2A   = OFF_BLI + 2048;                 // [2][32][2048]p (k-half 0 + bias/label)
constexpr size_t OFF_ZP2B   = OFF_ZP2A + 262144;              // [2][32][2048]p (k-half 1)
constexpr size_t OFF_OH2A   = OFF_ZP2B + 262144;              // [2][32][512]p
constexpr size_t OFF_OH2B   = OFF_OH2A + 65536;               // [2][32][512]p
constexpr size_t OFF_OUTPRE2= OFF_OH2B + 65536;               // [32][512]p
constexpr size_t OFF_HT2    = OFF_OUTPRE2 + 32768;            // [2][512][32]p
constexpr size_t OFF_HTT2   = OFF_HT2 + 65536;                // [2][32][512]p
constexpr size_t OFF_RVT2   = OFF_HTT2 + 65536;               // [2][256][32]p
constexpr size_t OFF_WVP2   = OFF_RVT2 + 32768;               // [2][2][32][64]p
constexpr size_t OFF_BAR    = OFF_WVP2 + 16384;               // counters (4096 ints)
constexpr size_t OFF_WPT    = OFF_BAR + 4096;                 // [128][320][4] k-major Wp
constexpr size_t WS_FLOATS  = OFF_WPT + (size_t)163840;

constexpr int DYN_FLOATS = 34816;                 // 136 KB dynamic LDS
constexpr int DYN_BYTES  = DYN_FLOATS * 4;

// WAR-slack counters only (8 lines x 64-int stride each). RAW sync is via tags.
constexpr int COH = 0, COP = 512, CCO = 1024, CRING = 1536;

__device__ __forceinline__ float sigm(float x) { return 1.f / (1.f + __expf(-x)); }

typedef int iv2 __attribute__((ext_vector_type(2)));
typedef int iv4 __attribute__((ext_vector_type(4)));

// ---- LLC-coherent accesses (bypass L1+L2). Batched loads with the waitcnt
// inside the asm so they are one round trip.
__device__ __forceinline__ void st_pair(float* base, size_t pidx, float v, int tag) {
  unsigned long long u = (unsigned long long)__float_as_uint(v) |
                         ((unsigned long long)(unsigned)tag << 32);
  __hip_atomic_store((unsigned long long*)(base + 2 * pidx), u,
                     __ATOMIC_RELAXED, __HIP_MEMORY_SCOPE_AGENT);
}
__device__ __forceinline__ float spin_pair(const float* base, size_t pidx, int tag) {
  const iv2* p = (const iv2*)(base + 2 * pidx);
  iv2 v;
  for (;;) {
    asm volatile("global_load_dwordx2 %0, %1, off sc0 sc1\n\ts_waitcnt vmcnt(0)"
                 : "=&v"(v) : "v"(p) : "memory");
    if (v[1] == tag) break;
    __builtin_amdgcn_s_sleep(1);
  }
  return __int_as_float(v[0]);
}
// two pairs at separate addresses (summed): ZP partial merge
__device__ __forceinline__ float2 spin_pair2_sum2(const float* a, const float* b, int tag) {
  const iv4* pa = (const iv4*)a;
  const iv4* pb = (const iv4*)b;
  iv4 x, y;
  for (;;) {
    asm volatile(
        "global_load_dwordx4 %0, %2, off sc0 sc1\n\t"
        "global_load_dwordx4 %1, %3, off sc0 sc1\n\t"
        "s_waitcnt vmcnt(0)"
        : "=&v"(x), "=&v"(y) : "v"(pa), "v"(pb) : "memory");
    if (x[1] == tag && x[3] == tag && y[1] == tag && y[3] == tag) break;
    __builtin_amdgcn_s_sleep(1);
  }
  return {__int_as_float(x[0]) + __int_as_float(y[0]),
          __int_as_float(x[2]) + __int_as_float(y[2])};
}
// two pairs at separate addresses
__device__ __forceinline__ float2 spin_pair_2addr(const float* a, const float* b, int tag) {
  const iv2* pa = (const iv2*)a;
  const iv2* pb = (const iv2*)b;
  iv2 x, y;
  for (;;) {
    asm volatile(
        "global_load_dwordx2 %0, %2, off sc0 sc1\n\t"
        "global_load_dwordx2 %1, %3, off sc0 sc1\n\t"
        "s_waitcnt vmcnt(0)"
        : "=&v"(x), "=&v"(y) : "v"(pa), "v"(pb) : "memory");
    if (x[1] == tag && y[1] == tag) break;
    __builtin_amdgcn_s_sleep(1);
  }
  return {__int_as_float(x[0]), __int_as_float(y[0])};
}
// four pairs at separate addresses (COUT quad spin)
__device__ __forceinline__ void ld4x2_sc(const iv2* a, const iv2* b, const iv2* c,
                                         const iv2* d, iv2& x, iv2& y, iv2& z, iv2& w) {
  asm volatile(
      "global_load_dwordx2 %0, %4, off sc0 sc1\n\t"
      "global_load_dwordx2 %1, %5, off sc0 sc1\n\t"
      "global_load_dwordx2 %2, %6, off sc0 sc1\n\t"
      "global_load_dwordx2 %3, %7, off sc0 sc1\n\t"
      "s_waitcnt vmcnt(0)"
      : "=&v"(x), "=&v"(y), "=&v"(z), "=&v"(w)
      : "v"(a), "v"(b), "v"(c), "v"(d) : "memory");
}
__device__ __forceinline__ void ld8i4_sc(const iv4* b0, iv4* v) {
  const iv4 *p0 = b0, *p1 = b0 + 512, *p2 = b0 + 1024, *p3 = b0 + 1536,
            *p4 = b0 + 2048, *p5 = b0 + 2560, *p6 = b0 + 3072, *p7 = b0 + 3584;
  asm volatile(
      "global_load_dwordx4 %0, %8, off sc0 sc1\n\t"
      "global_load_dwordx4 %1, %9, off sc0 sc1\n\t"
      "global_load_dwordx4 %2, %10, off sc0 sc1\n\t"
      "global_load_dwordx4 %3, %11, off sc0 sc1\n\t"
      "global_load_dwordx4 %4, %12, off sc0 sc1\n\t"
      "global_load_dwordx4 %5, %13, off sc0 sc1\n\t"
      "global_load_dwordx4 %6, %14, off sc0 sc1\n\t"
      "global_load_dwordx4 %7, %15, off sc0 sc1\n\t"
      "s_waitcnt vmcnt(0)"
      : "=&v"(v[0]), "=&v"(v[1]), "=&v"(v[2]), "=&v"(v[3]),
        "=&v"(v[4]), "=&v"(v[5]), "=&v"(v[6]), "=&v"(v[7])
      : "v"(p0), "v"(p1), "v"(p2), "v"(p3), "v"(p4), "v"(p5), "v"(p6), "v"(p7)
      : "memory");
}
__device__ __forceinline__ void ld10i4_sc(const iv4* b0, const iv4* z0,
                                          const iv4* z1, iv4* v) {
  const iv4 *p0 = b0, *p1 = b0 + 512, *p2 = b0 + 1024, *p3 = b0 + 1536,
            *p4 = b0 + 2048, *p5 = b0 + 2560, *p6 = b0 + 3072, *p7 = b0 + 3584;
  asm volatile(
      "global_load_dwordx4 %0, %10, off sc0 sc1\n\t"
      "global_load_dwordx4 %1, %11, off sc0 sc1\n\t"
      "global_load_dwordx4 %2, %12, off sc0 sc1\n\t"
      "global_load_dwordx4 %3, %13, off sc0 sc1\n\t"
      "global_load_dwordx4 %4, %14, off sc0 sc1\n\t"
      "global_load_dwordx4 %5, %15, off sc0 sc1\n\t"
      "global_load_dwordx4 %6, %16, off sc0 sc1\n\t"
      "global_load_dwordx4 %7, %17, off sc0 sc1\n\t"
      "global_load_dwordx4 %8, %18, off sc0 sc1\n\t"
      "global_load_dwordx4 %9, %19, off sc0 sc1\n\t"
      "s_waitcnt vmcnt(0)"
      : "=&v"(v[0]), "=&v"(v[1]), "=&v"(v[2]), "=&v"(v[3]), "=&v"(v[4]),
        "=&v"(v[5]), "=&v"(v[6]), "=&v"(v[7]), "=&v"(v[8]), "=&v"(v[9])
      : "v"(p0), "v"(p1), "v"(p2), "v"(p3), "v"(p4), "v"(p5), "v"(p6), "v"(p7),
        "v"(z0), "v"(z1)
      : "memory");
}
// counter poll: sum of 8 lines, single batched round trip
__device__ __forceinline__ int sum8_bar(const int* b) {
  int v0, v1, v2, v3, v4, v5, v6, v7;
  asm volatile(
      "global_load_dword %0, %8, off sc0 sc1\n\t"
      "global_load_dword %1, %9, off sc0 sc1\n\t"
      "global_load_dword %2, %10, off sc0 sc1\n\t"
      "global_load_dword %3, %11, off sc0 sc1\n\t"
      "global_load_dword %4, %12, off sc0 sc1\n\t"
      "global_load_dword %5, %13, off sc0 sc1\n\t"
      "global_load_dword %6, %14, off sc0 sc1\n\t"
      "global_load_dword %7, %15, off sc0 sc1\n\t"
      "s_waitcnt vmcnt(0)"
      : "=&v"(v0), "=&v"(v1), "=&v"(v2), "=&v"(v3),
        "=&v"(v4), "=&v"(v5), "=&v"(v6), "=&v"(v7)
      : "v"(b), "v"(b + 64), "v"(b + 128), "v"(b + 192),
        "v"(b + 256), "v"(b + 320), "v"(b + 384), "v"(b + 448)
      : "memory");
  return ((v0 + v1) + (v2 + v3)) + ((v4 + v5) + (v6 + v7));
}

// ---------------- weight re-layout: gate-interleaved Wx/Wh/bl + k-major Wp ----------------
__global__ __launch_bounds__(256) void prep_kernel(const float* __restrict__ Wx,
                                                   const float* __restrict__ Wh,
                                                   const float* __restrict__ bl,
                                                   const float* __restrict__ Wp,
                                                   float* __restrict__ ws) {
  float* WXI = ws + OFF_WXI;
  float* WHI = ws + OFF_WHI;
  float* BLI = ws + OFF_BLI;
  float* WPT = ws + OFF_WPT;
  const int t0 = 409 * 2048;
  const int t1 = t0 + 512 * 2048;
  const int t2 = t1 + 2048;
  const int total = t2 + 163840;
  for (int idx = blockIdx.x * blockDim.x + threadIdx.x; idx < total;
       idx += gridDim.x * blockDim.x) {
    if (idx < t0) {
      int k = idx >> 11, cc = idx & 2047;
      WXI[idx] = Wx[(size_t)k * 2048 + (cc & 3) * 512 + (cc >> 2)];
    } else if (idx < t1) {
      int j = idx - t0;
      int k = j >> 11, cc = j & 2047;
      WHI[j] = Wh[(size_t)k * 2048 + (cc & 3) * 512 + (cc >> 2)];
    } else if (idx < t2) {
      int cc = idx - t1;
      BLI[cc] = bl[(cc & 3) * 512 + (cc >> 2)];
    } else {
      // WPT[k4][j][ks] = Wp[k4*4+ks][j]
      int e = idx - t2;
      int k4 = e / 1280, r = e - k4 * 1280;
      int j = r >> 2, ks = r & 3;
      WPT[e] = Wp[(size_t)(k4 * 4 + ks) * 320 + j];
    }
  }
}

// ---------------- conv stack (validated) ----------------
__global__ __launch_bounds__(128) void conv_kernel(
    const float* __restrict__ img,
    const float* __restrict__ k1, const float* __restrict__ cb1, const float* __restrict__ g1,
    const float* __restrict__ be1, const float* __restrict__ mm1, const float* __restrict__ mv1,
    const float* __restrict__ k2, const float* __restrict__ cb2, const float* __restrict__ g2,
    const float* __restrict__ be2, const float* __restrict__ mm2, const float* __restrict__ mv2,
    const float* __restrict__ k3, const float* __restrict__ cb3, const float* __restrict__ g3,
    const float* __restrict__ be3, const float* __restrict__ mm3, const float* __restrict__ mv3,
    float* __restrict__ ws) {
  __shared__ float s_in[784];
  __shared__ float s_y1[13 * 13 * 8];
  __shared__ float s_y2[6 * 6 * 16];
  __shared__ float s_k1[72], s_k2[1152], s_k3[4608];
  __shared__ float s_s1[8], s_b1[8], s_s2[16], s_b2[16], s_s3[32], s_b3[32];
  float* FEATP = ws + OFF_FEATP;
  const int n = blockIdx.x, tid = threadIdx.x;
  const float* ip = img + (size_t)n * 784;
  for (int i = tid; i < 784; i += 128) s_in[i] = ip[i];
  for (int i = tid; i < 72; i += 128) s_k1[i] = k1[i];
  for (int i = tid; i < 1152; i += 128) s_k2[i] = k2[i];
  for (int i = tid; i < 4608; i += 128) s_k3[i] = k3[i];
  if (tid < 8) {
    float s = g1[tid] * rsqrtf(mv1[tid] + 1e-3f);
    s_s1[tid] = s; s_b1[tid] = (cb1[tid] - mm1[tid]) * s + be1[tid];
  } else if (tid >= 32 && tid < 48) {
    int c = tid - 32;
    float s = g2[c] * rsqrtf(mv2[c] + 1e-3f);
    s_s2[c] = s; s_b2[c] = (cb2[c] - mm2[c]) * s + be2[c];
  } else if (tid >= 64 && tid < 96) {
    int c = tid - 64;
    float s = g3[c] * rsqrtf(mv3[c] + 1e-3f);
    s_s3[c] = s; s_b3[c] = (cb3[c] - mm3[c]) * s + be3[c];
  }
  __syncthreads();
  for (int idx = tid; idx < 13 * 13 * 8; idx += 128) {
    int co = idx & 7, pos = idx >> 3;
    int j = pos % 13, i = pos / 13;
    float acc = 0.f;
    #pragma unroll
    for (int ky = 0; ky < 3; ++ky)
      #pragma unroll
      for (int kx = 0; kx < 3; ++kx)
        acc += s_in[(2 * i + ky) * 28 + (2 * j + kx)] * s_k1[(ky * 3 + kx) * 8 + co];
    float v = acc * s_s1[co] + s_b1[co];
    s_y1[idx] = v > 0.f ? v : 0.f;
  }
  __syncthreads();
  for (int idx = tid; idx < 6 * 6 * 16; idx += 128) {
    int co = idx & 15, pos = idx >> 4;
    int j = pos % 6, i = pos / 6;
    float acc = 0.f;
    for (int ky = 0; ky < 3; ++ky)
      for (int kx = 0; kx < 3; ++kx) {
        int base = ((2 * i + ky) * 13 + (2 * j + kx)) * 8;
        int kb = (ky * 3 + kx) * 128 + co;
        #pragma unroll
        for (int ci = 0; ci < 8; ++ci) acc += s_y1[base + ci] * s_k2[kb + ci * 16];
      }
    float v = acc * s_s2[co] + s_b2[co];
    s_y2[idx] = v > 0.f ? v : 0.f;
  }
  __syncthreads();
  for (int idx = tid; idx < 128; idx += 128) {
    int co = idx & 31, pos = idx >> 5;
    int j = pos & 1, i = pos >> 1;
    float acc = 0.f;
    for (int ky = 0; ky < 3; ++ky)
      for (int kx = 0; kx < 3; ++kx) {
        int base = ((2 * i + ky) * 6 + (2 * j + kx)) * 16;
        int kb = (ky * 3 + kx) * 512 + co;
        #pragma unroll
        for (int ci = 0; ci < 16; ++ci) acc += s_y2[base + ci] * s_k3[kb + ci * 32];
      }
    float v = acc * s_s3[co] + s_b3[co];
    FEATP[(size_t)n * 128 + idx] = v > 0.f ? v : 0.f;
  }
}

// ---------------- persistent LSTM scan: tagged-pair dataflow ----------------
// Roles: AZ 0-63 | AO 64-79 | ZH 80-143 (E64, K-halves) | OL 144-159 /
// OHI 160-175 | ATT 176-239 | WV 240-243 | COUT 244-251 | 252-255 idle.
// Epochs: h_t/rv_t/ZP_t/OH_t/WVP_t -> tag t+1; OUTPRE (AO step t) -> tag t.
// Zeroed buffers (tag 0) ARE the t=0 zero state.
__global__ __launch_bounds__(512) void lstm_kernel(
    const int* __restrict__ labels,
    const float* __restrict__ Wo, const float* __restrict__ bo,
    const float* __restrict__ Wp, const float* __restrict__ bp,
    const float* __restrict__ Wf, const float* __restrict__ bf,
    float* __restrict__ ws, float* __restrict__ out) {
  extern __shared__ float dyn[];
  const float* FEATP = ws + OFF_FEATP;
  const float* WXI   = ws + OFF_WXI;
  const float* WHI   = ws + OFF_WHI;
  const float* BLI   = ws + OFF_BLI;
  float* ZP2A   = ws + OFF_ZP2A;    // [2][32][2048]p
  float* ZP2B   = ws + OFF_ZP2B;
  float* OH2A   = ws + OFF_OH2A;    // [2][32][512]p
  float* OH2B   = ws + OFF_OH2B;
  float* OUTPRE2= ws + OFF_OUTPRE2; // [32][512]p
  float* HT2    = ws + OFF_HT2;     // [2][512][32]p
  float* HTT2   = ws + OFF_HTT2;    // [2][32][512]p
  float* RVT2   = ws + OFF_RVT2;    // [2][256][32]p
  float* WVP2   = ws + OFF_WVP2;    // [2][2][32][64]p
  const float* WPT = ws + OFF_WPT;  // [128][320][4]
  int*   BARp   = (int*)(ws + OFF_BAR);

  const int bid = blockIdx.x;
  const int tid = threadIdx.x;

  // cached WAR wait: skip the LLC poll when the cached read already covers it.
  // bcast slots live at dyn[34808..34812) -- below every role's data usage
  // except ZH, which never calls waitC.
  int* bc = (int*)(dyn + 34808);
  auto waitC = [&](int base, int target, int& cache) {
    if (cache >= target) return;
    if (tid == 0) {
      int v = sum8_bar(BARp + base);
      while (v < target) v = sum8_bar(BARp + base);
      bc[base >> 9] = v;
    }
    __syncthreads();
    cache = bc[base >> 9];
    __syncthreads();
  };
  auto bumpC = [&](int base) {
    asm volatile("s_waitcnt vmcnt(0)" ::: "memory");
    __syncthreads();
    if (tid == 0) atomicAdd(&BARp[base + ((bid & 7) << 6)], 1);
  };

  // spin-stage an 8192-value pair buffer ([256][32]p) into [256][36] LDS tile
  auto stageP = [&](float* dst, const float* srcPairs, int tag) {
    const iv4* sp = (const iv4*)srcPairs + tid;
    iv4 v[8];
    for (;;) {
      ld8i4_sc(sp, v);
      bool ok = true;
      #pragma unroll
      for (int j = 0; j < 8; ++j) ok = ok && (v[j][1] == tag) && (v[j][3] == tag);
      if (ok) break;
      __builtin_amdgcn_s_sleep(2);
    }
    #pragma unroll
    for (int j = 0; j < 8; ++j) {
      int i = (tid + j * 512) << 1;
      float2 f = {__int_as_float(v[j][0]), __int_as_float(v[j][2])};
      *(float2*)&dst[(i >> 5) * 36 + (i & 31)] = f;
    }
  };

  // ---- E32: Y[32c][32b] (validated). K mult of 16.
  auto E32 = [&](const float* Wm, const float* Am, int K, float* part, float2& r) {
    const int wv = tid >> 6, l = tid & 63;
    const int ksub = l & 1, cg = (l >> 1) & 3, bg = l >> 3;
    const int Kp = K >> 4;
    const int kb = wv * (K >> 3) + ksub * Kp;
    const float* wp = Wm + (size_t)kb * 32 + cg * 8;
    const float* ap = Am + (size_t)kb * 36 + bg * 4;
    float4 acc[8];
    #pragma unroll
    for (int i = 0; i < 8; ++i) acc[i] = {0.f, 0.f, 0.f, 0.f};
    #pragma unroll 4
    for (int kk = 0; kk < Kp; ++kk) {
      float4 w0 = *(const float4*)(wp + kk * 32);
      float4 w1 = *(const float4*)(wp + kk * 32 + 4);
      float4 a  = *(const float4*)(ap + kk * 36);
      float wl[8];
      *(float4*)&wl[0] = w0; *(float4*)&wl[4] = w1;
      #pragma unroll
      for (int i = 0; i < 8; ++i) {
        acc[i].x = fmaf(wl[i], a.x, acc[i].x);
        acc[i].y = fmaf(wl[i], a.y, acc[i].y);
        acc[i].z = fmaf(wl[i], a.z, acc[i].z);
        acc[i].w = fmaf(wl[i], a.w, acc[i].w);
      }
    }
    #pragma unroll
    for (int i = 0; i < 8; ++i) {
      acc[i].x += __shfl_xor(acc[i].x, 1, 64);
      acc[i].y += __shfl_xor(acc[i].y, 1, 64);
      acc[i].z += __shfl_xor(acc[i].z, 1, 64);
      acc[i].w += __shfl_xor(acc[i].w, 1, 64);
    }
    const int ob = (cg * 8) * 36 + bg * 4;
    if (ksub == 0 && wv < 4) {
      float* pb = part + wv * 1152 + ob;
      #pragma unroll
      for (int i = 0; i < 8; ++i) *(float4*)(pb + i * 36) = acc[i];
    }
    __syncthreads();
    if (ksub == 0 && wv >= 4) {
      float* pb = part + (wv - 4) * 1152 + ob;
      #pragma unroll
      for (int i = 0; i < 8; ++i) {
        float4 t = *(float4*)(pb + i * 36);
        t.x += acc[i].x; t.y += acc[i].y; t.z += acc[i].z; t.w += acc[i].w;
        *(float4*)(pb + i * 36) = t;
      }
    }
    __syncthreads();
    const int c = tid & 31, b2 = (tid >> 5) * 2;
    const int o = c * 36 + b2;
    float2 s0 = *(float2*)(part + o);
    float2 s1 = *(float2*)(part + 1152 + o);
    float2 s2 = *(float2*)(part + 2304 + o);
    float2 s3 = *(float2*)(part + 3456 + o);
    r.x = (s0.x + s1.x) + (s2.x + s3.x);
    r.y = (s0.y + s1.y) + (s2.y + s3.y);
  };

  // ---- E64: Y[64c][32b], K=256, rotated weight slab (R0-validated).
  auto E64 = [&](const float* Wm, const float* Am, float* part, float4& r) {
    const int wv = tid >> 6, l = tid & 63;
    const int ksub = l & 1, cg = (l >> 1) & 7, bg = l >> 4;
    const int kb = wv * 32 + ksub * 16;
    const float* wp0 = Wm + (size_t)kb * 64 + ((cg * 8 + ksub * 4) & 63);
    const float* wp1 = Wm + (size_t)kb * 64 + ((cg * 8 + 4 + ksub * 4) & 63);
    const float* ap = Am + (size_t)kb * 36 + bg * 8;
    float4 acc[8][2];
    #pragma unroll
    for (int i = 0; i < 8; ++i) { acc[i][0] = {0.f,0.f,0.f,0.f}; acc[i][1] = {0.f,0.f,0.f,0.f}; }
    #pragma unroll 2
    for (int kk = 0; kk < 16; ++kk) {
      float4 w0 = *(const float4*)(wp0 + kk * 64);
      float4 w1 = *(const float4*)(wp1 + kk * 64);
      float4 a0 = *(const float4*)(ap + kk * 36);
      float4 a1 = *(const float4*)(ap + kk * 36 + 4);
      float wl[8];
      *(float4*)&wl[0] = w0; *(float4*)&wl[4] = w1;
      #pragma unroll
      for (int i = 0; i < 8; ++i) {
        acc[i][0].x = fmaf(wl[i], a0.x, acc[i][0].x);
        acc[i][0].y = fmaf(wl[i], a0.y, acc[i][0].y);
        acc[i][0].z = fmaf(wl[i], a0.z, acc[i][0].z);
        acc[i][0].w = fmaf(wl[i], a0.w, acc[i][0].w);
        acc[i][1].x = fmaf(wl[i], a1.x, acc[i][1].x);
        acc[i][1].y = fmaf(wl[i], a1.y, acc[i][1].y);
        acc[i][1].z = fmaf(wl[i], a1.z, acc[i][1].z);
        acc[i][1].w = fmaf(wl[i], a1.w, acc[i][1].w);
      }
    }
    #pragma unroll
    for (int i = 0; i < 8; ++i) {
      #pragma unroll
      for (int j = 0; j < 2; ++j) {
        acc[i][j].x += __shfl_xor(acc[i][j].x, 1, 64);
        acc[i][j].y += __shfl_xor(acc[i][j].y, 1, 64);
        acc[i][j].z += __shfl_xor(acc[i][j].z, 1, 64);
        acc[i][j].w += __shfl_xor(acc[i][j].w, 1, 64);
      }
    }
    const int ob = (cg * 8) * 36 + bg * 8;
    if (ksub == 0 && wv < 4) {
      float* pb = part + wv * 2304 + ob;
      #pragma unroll
      for (int i = 0; i < 8; ++i) {
        *(float4*)(pb + i * 36) = acc[i][0];
        *(float4*)(pb + i * 36 + 4) = acc[i][1];
      }
    }
    __syncthreads();
    if (ksub == 0 && wv >= 4) {
      float* pb = part + (wv - 4) * 2304 + ob;
      #pragma unroll
      for (int i = 0; i < 8; ++i) {
        float4 t0 = *(float4*)(pb + i * 36);
        float4 t1 = *(float4*)(pb + i * 36 + 4);
        t0.x += acc[i][0].x; t0.y += acc[i][0].y; t0.z += acc[i][0].z; t0.w += acc[i][0].w;
        t1.x += acc[i][1].x; t1.y += acc[i][1].y; t1.z += acc[i][1].z; t1.w += acc[i][1].w;
        *(float4*)(pb + i * 36) = t0;
        *(float4*)(pb + i * 36 + 4) = t1;
      }
    }
    __syncthreads();
    const int c = tid & 63, b4 = (tid >> 6) * 4;
    const int o = c * 36 + b4;
    float4 s0 = *(float4*)(part + o);
    float4 s1 = *(float4*)(part + 2304 + o);
    float4 s2 = *(float4*)(part + 4608 + o);
    float4 s3 = *(float4*)(part + 6912 + o);
    r.x = (s0.x + s1.x) + (s2.x + s3.x);
    r.y = (s0.y + s1.y) + (s2.y + s3.y);
    r.z = (s0.z + s1.z) + (s2.z + s3.z);
    r.w = (s0.w + s1.w) + (s2.w + s3.w);
  };

  // ---------------- one-time init: weights -> LDS ----------------
  if (bid < 64) {            // AZ: Wz (rv part of Wx) + Wxx (x part)
    const int c0 = bid * 32;
    for (int i = tid; i < 8192; i += 512)
      dyn[i] = WXI[(size_t)(153 + (i >> 5)) * 2048 + c0 + (i & 31)];
    for (int i = tid; i < 4096; i += 512)
      dyn[8192 + i] = WXI[(size_t)(i >> 5) * 2048 + c0 + (i & 31)];
    if (tid < 256) dyn[12288 + tid] = 0.f;  // Cst
  } else if (bid < 80) {     // AO: Wo rows 512..768
    const int u0 = (bid - 64) * 32;
    for (int i = tid; i < 8192; i += 512)
      dyn[i] = Wo[(size_t)(512 + (i >> 5)) * 512 + u0 + (i & 31)];
    if (tid < 32) dyn[8192 + tid] = bo[u0 + tid];
  } else if (bid < 144) {    // ZH: rotated E64 slab Wh[kh*256..+256][j0..j0+64]
    const int r = bid - 80;
    const int j0 = (r & 31) * 64, kh = r >> 5;
    for (int i = tid; i < 16384; i += 512) {
      int k = i >> 6, cc = i & 63;
      int cr = (cc + ((k >> 4) & 1) * 4) & 63;
      dyn[k * 64 + cr] = WHI[(size_t)(kh * 256 + k) * 2048 + j0 + cc];
    }
  } else if (bid < 160) {    // OL: Wo rows 0..256
    const int u0 = (bid - 144) * 32;
    for (int i = tid; i < 8192; i += 512)
      dyn[i] = Wo[(size_t)(i >> 5) * 512 + u0 + (i & 31)];
  } else if (bid < 176) {    // OHI: Wo rows 256..512
    const int u0 = (bid - 160) * 32;
    for (int i = tid; i < 8192; i += 512)
      dyn[i] = Wo[(size_t)(256 + (i >> 5)) * 512 + u0 + (i & 31)];
  } else if (bid < 240) {    // ATT: ring + cached norms + bias slices
    const int hp = (bid - 176) & 1;
    for (int i = tid; i < 17000; i += 512) dyn[i] = 0.f;            // ring[250][68]
    if (tid < 256) dyn[17000 + tid] = rsqrtf(1e-12f);               // rn
    if (tid < 128) dyn[21264 + tid] = bp[64 + hp * 128 + tid];      // bpk
    if (tid < 64)  dyn[21392 + tid] = bp[tid];                      // bpw
  } else if (bid < 244) {    // WV: Wp[kh*256..+256][cp*32..+32]
    const int kh = (bid - 240) >> 1, cp = (bid - 240) & 1;
    for (int i = tid; i < 8192; i += 512) {
      int k = i >> 5, c = i & 31;
      dyn[i] = Wp[(size_t)(kh * 256 + k) * 320 + cp * 32 + c];
    }
  } else if (bid < 252) {    // COUT: Wf + bf
    for (int i = tid; i < 12800; i += 512) dyn[i] = Wf[i];
    if (tid < 25) dyn[12800 + tid] = bf[tid];
  }
  __syncthreads();

  // ================= role bodies =================
  // AZ dyn: Wz[0,8192) Wxx[8192,12288) Cst[12288,12544) rvT[12544,21760)
  //         xT[21760,26368) zx[26368,27392) zf[27392,28416) part[28416,33024)
  auto azPre = [&](int t) {           // ZP_t partial pairs (A+B) -> zf (spin)
    const int c0 = bid * 32;
    const float* zaP = ZP2A + (t & 1) * 131072;
    const float* zbP = ZP2B + (t & 1) * 131072;
    float* zf = dyn + 27392;
    const int bb = tid >> 4, c2 = tid & 15;
    size_t pidx = (size_t)bb * 2048 + c0 + c2 * 2;
    float2 s = spin_pair2_sum2(zaP + 2 * pidx, zbP + 2 * pidx, t + 1);
    *(float2*)&zf[bb * 32 + c2 * 2] = s;
  };
  auto azGatesMain = [&](int t) {
    const float* rvP = RVT2 + ((t + 1) & 1) * 16384;   // rv_{t-1} pairs, tag t
    float* Wz = dyn; float* Cst = dyn + 12288; float* rvT = dyn + 12544;
    float* zx = dyn + 26368; float* zf = dyn + 27392; float* part = dyn + 28416;
    stageP(rvT, rvP, t);
    __syncthreads();
    float2 r;
    E32(Wz, rvT, 256, part, r);
    const int c = tid & 31, b2 = (tid >> 5) * 2;
    zf[b2 * 32 + c] += r.x + zx[b2 * 32 + c];
    zf[(b2 + 1) * 32 + c] += r.y + zx[(b2 + 1) * 32 + c];
    __syncthreads();
    if (tid < 256) {
      int u = tid & 7, b = tid >> 3;
      float4 z = *(float4*)(zf + b * 32 + u * 4);
      float ig = sigm(z.x), fg = sigm(z.y), gg = tanhf(z.z), og = sigm(z.w);
      float cc = fg * Cst[b * 8 + u] + ig * gg;
      Cst[b * 8 + u] = cc;
      float hv = og * tanhf(cc);
      st_pair(HT2 + (t & 1) * 32768, (size_t)(bid * 8 + u) * 32 + b, hv, t + 1);
      st_pair(HTT2 + (t & 1) * 32768, (size_t)b * 512 + bid * 8 + u, hv, t + 1);
    }
  };
  auto azX = [&](int tt) {    // zx = x_{tt}@Wx, local
    float* Wxx = dyn + 8192; float* xT = dyn + 21760;
    float* zx = dyn + 26368; float* part = dyn + 28416;
    for (int i = tid; i < 4096; i += 512) {
      int b = i >> 7, k = i & 127;
      xT[k * 36 + b] = FEATP[((size_t)b * 250 + tt) * 128 + k];
    }
    __syncthreads();
    float2 r;
    E32(Wxx, xT, 128, part, r);
    const int c = tid & 31, b2 = (tid >> 5) * 2;
    zx[b2 * 32 + c] = r.x;
    zx[(b2 + 1) * 32 + c] = r.y;
  };
  // AO dyn: W[0,8192) bo[8192,8224) rvT[8224,17440) of[17440,18464) part[18464,23072)
  auto aoOut = [&](int t) {   // outpre_{t-1}: rv_{t-1} (tag t), OH_{t-1} (tag t)
    const int u0 = (bid - 64) * 32;
    const float* rvP  = RVT2 + ((t + 1) & 1) * 16384;
    const float* ohaP = OH2A + ((t + 1) & 1) * 32768;
    const float* ohbP = OH2B + ((t + 1) & 1) * 32768;
    float* W = dyn; float* bo_l = dyn + 8192; float* rvT = dyn + 8224;
    float* of = dyn + 17440; float* part = dyn + 18464;
    {
      const int b = tid >> 4, c2 = tid & 15;
      const iv4* rp = (const iv4*)rvP + tid;
      const iv4* za = (const iv4*)ohaP + (b * 256 + (u0 >> 1) + c2);
      const iv4* zb = (const iv4*)ohbP + (b * 256 + (u0 >> 1) + c2);
      iv4 v[10];
      for (;;) {
        ld10i4_sc(rp, za, zb, v);
        bool ok = true;
        #pragma unroll
        for (int j = 0; j < 10; ++j) ok = ok && (v[j][1] == t) && (v[j][3] == t);
        if (ok) break;
        __builtin_amdgcn_s_sleep(2);
      }
      #pragma unroll
      for (int j = 0; j < 8; ++j) {
        int i = (tid + j * 512) << 1;
        float2 f = {__int_as_float(v[j][0]), __int_as_float(v[j][2])};
        *(float2*)&rvT[(i >> 5) * 36 + (i & 31)] = f;
      }
      float2 s = {__int_as_float(v[8][0]) + __int_as_float(v[9][0]),
                  __int_as_float(v[8][2]) + __int_as_float(v[9][2])};
      *(float2*)&of[b * 32 + c2 * 2] = s;
    }
    __syncthreads();
    float2 r;
    E32(W, rvT, 256, part, r);
    const int c = tid & 31, b2 = (tid >> 5) * 2;
    float bv = bo_l[c];
    st_pair(OUTPRE2, (size_t)b2 * 512 + u0 + c, r.x + of[b2 * 32 + c] + bv, t);
    st_pair(OUTPRE2, (size_t)(b2 + 1) * 512 + u0 + c, r.y + of[(b2 + 1) * 32 + c] + bv, t);
  };
  // OL/OHI dyn: W[0,8192) A[8192,17408) part[17408,22016)
  auto p2Gemm = [&](int t) {
    const float* htP = HT2 + (t & 1) * 32768;
    float* W = dyn; float* A = dyn + 8192; float* part = dyn + 17408;
    const bool isOLr = bid < 160;
    stageP(A, isOLr ? htP : (htP + 16384), t + 1);
    __syncthreads();
    float2 r;
    E32(W, A, 256, part, r);
    const int c = tid & 31, b2 = (tid >> 5) * 2;
    const int u0 = (isOLr ? (bid - 144) : (bid - 160)) * 32;
    float* d = (isOLr ? OH2A : OH2B) + (t & 1) * 32768;
    st_pair(d, (size_t)b2 * 512 + u0 + c, r.x, t + 1);
    st_pair(d, (size_t)(b2 + 1) * 512 + u0 + c, r.y, t + 1);
  };

  // ---------------- dataflow role loops ----------------
  if (bid < 64) {                       // AZ
    int cCOH = 0;
    azX(0);
    for (int t = 0; t < 250; ++t) {
      azPre(t);                                  // RAW ZP_t (A+B) via tags
      if (t >= 2) waitC(COH, 32 * (t - 1), cCOH);// HT WAR: OL/OHI_{t-2} read done
      azGatesMain(t);                            // RAW rv_{t-1} via tags; h out
      if (t < 249) azX(t + 1);
    }
  } else if (bid < 80) {                // AO
    int cCCO = 0;
    for (int t = 1; t <= 250; ++t) {
      if (t >= 2) waitC(CCO, 8 * (t - 1), cCCO); // OUTPRE WAR: COUT_{t-1} done
      aoOut(t);                                  // RAW rv/OH via tags
      bumpC(COP);
    }
  } else if (bid < 144) {               // ZH: E64 k-half partial of h@Wh
    const int r = bid - 80;
    const int j0 = (r & 31) * 64, kh = r >> 5;
    const int c = tid & 63, b4 = (tid >> 6) * 4;
    float* W = dyn; float* A = dyn + 16384; float* part = dyn + 25600;
    float* zpBase = kh ? ZP2B : ZP2A;
    const float blv = (kh == 0) ? BLI[j0 + c] : 0.f;
    for (int s = 0; s < 250; ++s) {
      float wx0 = 0.f, wx1 = 0.f, wx2 = 0.f, wx3 = 0.f;
      if (kh == 0) {     // label-row prefetch (input-dependent only; hides under h spin)
        int l0 = labels[(b4 + 0) * 250 + s], l1 = labels[(b4 + 1) * 250 + s];
        int l2 = labels[(b4 + 2) * 250 + s], l3 = labels[(b4 + 3) * 250 + s];
        wx0 = WXI[(size_t)(128 + l0) * 2048 + j0 + c];
        wx1 = WXI[(size_t)(128 + l1) * 2048 + j0 + c];
        wx2 = WXI[(size_t)(128 + l2) * 2048 + j0 + c];
        wx3 = WXI[(size_t)(128 + l3) * 2048 + j0 + c];
      }
      stageP(A, HT2 + ((s + 1) & 1) * 32768 + kh * 16384, s);  // h_{s-1} half
      __syncthreads();
      float4 rr;
      E64(W, A, part, rr);
      float* zpD = zpBase + (s & 1) * 131072;
      st_pair(zpD, (size_t)(b4 + 0) * 2048 + j0 + c, rr.x + blv + wx0, s + 1);
      st_pair(zpD, (size_t)(b4 + 1) * 2048 + j0 + c, rr.y + blv + wx1, s + 1);
      st_pair(zpD, (size_t)(b4 + 2) * 2048 + j0 + c, rr.z + blv + wx2, s + 1);
      st_pair(zpD, (size_t)(b4 + 3) * 2048 + j0 + c, rr.w + blv + wx3, s + 1);
    }
  } else if (bid < 176) {               // OL / OHI
    int cCOP = 0;
    for (int t = 0; t < 250; ++t) {
      if (t >= 2) waitC(COP, 16 * (t - 1), cCOP);// OH WAR: AO_{t-1} read done
      p2Gemm(t);                                 // RAW h_t via tags
      bumpC(COH);
    }
  } else if (bid < 240) {               // ATT: keys + attention + rv
    float* ring = dyn;
    float* rn   = dyn + 17000;
    float* h_s  = dyn + 17256;
    float* kpart= dyn + 17768;
    float* kn   = dyn + 18408;
    float* att  = dyn + 18536;
    float* redS = dyn + 19068;
    float* pslab= dyn + 19088;
    float* bpk  = dyn + 21264;
    float* bpw  = dyn + 21392;
    const int b = (bid - 176) >> 1, hp = (bid - 176) & 1;
    const int j = tid & 127, q = tid >> 7;
    const int J = 64 + hp * 128 + j;
    const float4* wbase = (const float4*)WPT + q * 32 * 320 + J;
    int cCOP = 0;
    for (int t = 0; t < 250; ++t) {
      // prefetch ALL of this thread's Wp chunk; completes under the h wait
      float4 pf[32];
      #pragma unroll
      for (int i = 0; i < 32; ++i) pf[i] = wbase[i * 320];
      if (t >= 2) waitC(COP, 16 * (t - 1), cCOP);// RVT WAR: AO_{t-1} read done
      h_s[tid] = spin_pair(HTT2 + (t & 1) * 32768, (size_t)b * 512 + tid, t + 1);
      __syncthreads();
      {  // key GEMM, pure-register weights
        float a = 0.f;
        #pragma unroll
        for (int i = 0; i < 32; ++i) {
          float4 h4 = *(const float4*)&h_s[q * 128 + i * 4];
          a += pf[i].x * h4.x + pf[i].y * h4.y + pf[i].z * h4.z + pf[i].w * h4.w;
        }
        kpart[q * 128 + j] = a;
      }
      __syncthreads();
      if (tid < 128) {  // fused reduce + tanh + per-head L2 norm (wave-local)
        float kr = kpart[tid] + kpart[128 + tid] + kpart[256 + tid] +
                   kpart[384 + tid] + bpk[tid];
        float v = tanhf(kr);
        float pq = v * v;
        #pragma unroll
        for (int off = 32; off; off >>= 1) pq += __shfl_xor(pq, off, 64);
        kn[tid] = v * rsqrtf(fmaxf(pq, 1e-12f));
      }
      __syncthreads();
      const int start = (250 - t) % 250;
      const int m = tid >> 1, hh = tid & 1;
      {  // dots + softmax WITHOUT max-pass (cosine scores bounded by 1)
        float e = 0.f;
        if (m < 250) {
          int p = start + m; if (p >= 250) p -= 250;
          const float4* c4 = (const float4*)ring + p * 17;
          const float4* k4 = (const float4*)kn + hh * 16;
          float d = 0.f;
          #pragma unroll
          for (int s4 = 0; s4 < 16; ++s4) {
            float4 cc = c4[s4], kk = k4[s4];
            d += cc.x * kk.x + cc.y * kk.y + cc.z * kk.z + cc.w * kk.w;
          }
          e = __expf(d * rn[p]);
          att[hh * 256 + m] = e;
        }
        float sm = e;
        #pragma unroll
        for (int off = 2; off <= 32; off <<= 1) sm += __shfl_xor(sm, off, 64);
        if ((tid & 63) < 2) redS[(tid >> 6) * 2 + (tid & 1)] = sm;
      }
      __syncthreads();
      {  // weighted sum into padded partial slabs
        int hh2 = tid >> 8, s4 = (tid >> 4) & 15, g = tid & 15;
        float4 a4 = {0.f, 0.f, 0.f, 0.f};
        for (int mm = g; mm < 250; mm += 16) {
          int p = start + mm; if (p >= 250) p -= 250;
          float w = att[hh2 * 256 + mm];
          float4 cc = ((const float4*)ring)[p * 17 + s4];
          a4.x = fmaf(w, cc.x, a4.x); a4.y = fmaf(w, cc.y, a4.y);
          a4.z = fmaf(w, cc.z, a4.z); a4.w = fmaf(w, cc.w, a4.w);
        }
        *(float4*)&pslab[(hh2 * 16 + s4) * 68 + g * 4] = a4;
      }
      __syncthreads();
      if (tid < 128) {
        int hh3 = tid >> 6, s = tid & 63;
        float denom = redS[hh3];
        #pragma unroll
        for (int w = 1; w < 8; ++w) denom += redS[w * 2 + hh3];
        float sum = 0.f;
        #pragma unroll
        for (int g = 0; g < 16; ++g)
          sum += pslab[(hh3 * 16 + (s >> 2)) * 68 + g * 4 + (s & 3)];
        st_pair(RVT2 + (t & 1) * 16384,
                (size_t)((2 * hp + hh3) * 64 + s) * 32 + b, sum / denom, t + 1);
      }
      __syncthreads();                            // ring readers done before update
      {  // ring update with wv_t (tags; off critical path)
        int ip = start + 249; if (ip >= 250) ip -= 250;
        if (tid < 64) {
          float2 p01 = spin_pair_2addr(
              WVP2 + (t & 1) * 8192 + 2 * ((size_t)b * 64 + tid),
              WVP2 + (t & 1) * 8192 + 4096 + 2 * ((size_t)b * 64 + tid), t + 1);
          float nv = tanhf(p01.x + p01.y + bpw[tid]);
          ring[ip * 68 + tid] = nv;
          float n2 = nv * nv;
          #pragma unroll
          for (int off = 32; off; off >>= 1) n2 += __shfl_xor(n2, off, 64);
          if (tid == 0) rn[ip] = rsqrtf(fmaxf(n2, 1e-12f));
        }
      }
      bumpC(CRING);
    }
  } else if (bid < 244) {               // WV: wv partials
    // dyn: W[0,8192) A[8192,17408) part[17408,22016)
    const int kh = (bid - 240) >> 1, cp = (bid - 240) & 1;
    float* W = dyn; float* A = dyn + 8192; float* part = dyn + 17408;
    int cCR = 0;
    for (int t = 0; t < 250; ++t) {
      if (t >= 2) waitC(CRING, 64 * (t - 1), cCR);// WVP WAR: ring-update done
      stageP(A, HT2 + (t & 1) * 32768 + kh * 16384, t + 1);  // RAW h_t via tags
      __syncthreads();
      float2 r;
      E32(W, A, 256, part, r);
      const int c = tid & 31, b2 = (tid >> 5) * 2;
      float* d = WVP2 + (t & 1) * 8192 + kh * 4096;
      st_pair(d, (size_t)b2 * 64 + cp * 32 + c, r.x, t + 1);
      st_pair(d, (size_t)(b2 + 1) * 64 + cp * 32 + c, r.y, t + 1);
    }
  } else if (bid < 252) {               // COUT: 4 batches, one quad spin per step
    const int b0 = (bid - 244) * 4;
    float* WfL = dyn; float* bfL = dyn + 12800;
    float* to4 = dyn + 12832;           // [4][512]
    float* lp  = dyn + 14880;           // [400]
    float* lg  = dyn + 15280;           // [27]
    for (int t = 1; t <= 250; ++t) {
      {
        const iv2* p0 = (const iv2*)(OUTPRE2 + 2 * ((size_t)(b0 + 0) * 512 + tid));
        const iv2* p1 = (const iv2*)(OUTPRE2 + 2 * ((size_t)(b0 + 1) * 512 + tid));
        const iv2* p2 = (const iv2*)(OUTPRE2 + 2 * ((size_t)(b0 + 2) * 512 + tid));
        const iv2* p3 = (const iv2*)(OUTPRE2 + 2 * ((size_t)(b0 + 3) * 512 + tid));
        iv2 v0, v1, v2, v3;
        for (;;) {
          ld4x2_sc(p0, p1, p2, p3, v0, v1, v2, v3);
          if (v0[1] == t && v1[1] == t && v2[1] == t && v3[1] == t) break;
          __builtin_amdgcn_s_sleep(2);
        }
        to4[tid]        = tanhf(__int_as_float(v0[0]));
        to4[512 + tid]  = tanhf(__int_as_float(v1[0]));
        to4[1024 + tid] = tanhf(__int_as_float(v2[0]));
        to4[1536 + tid] = tanhf(__int_as_float(v3[0]));
      }
      __syncthreads();
      for (int i = 0; i < 4; ++i) {
        float* to = to4 + i * 512;
        if (tid < 400) {
          int l = tid % 25, p = tid / 25;
          float s = 0.f;
          #pragma unroll
          for (int q = 0; q < 32; ++q) { int k = p * 32 + q; s += to[k] * WfL[k * 25 + l]; }
          lp[p * 25 + l] = s;
        }
        __syncthreads();
        if (tid < 25) {
          float s = bfL[tid];
          #pragma unroll
          for (int p = 0; p < 16; ++p) s += lp[p * 25 + tid];
          lg[tid] = s;
        }
        __syncthreads();
        if (tid == 0) {
          float mx = lg[0];
          for (int l = 1; l < 25; ++l) mx = fmaxf(mx, lg[l]);
          float ss = 0.f;
          for (int l = 0; l < 25; ++l) ss += __expf(lg[l] - mx);
          lg[25] = mx; lg[26] = 1.f / ss;
        }
        __syncthreads();
        if (tid < 25)
          out[((size_t)(b0 + i) * 250 + (t - 1)) * 25 + tid] =
              __expf(lg[tid] - lg[25]) * lg[26];
        __syncthreads();
      }
      bumpC(CCO);
    }
  }
}

extern "C" void kernel_launch(void* const* d_in, const int* in_sizes, int n_in,
                              void* d_out, int out_size, void* d_ws, size_t ws_size,
                              hipStream_t stream) {
  const float* images = (const float*)d_in[0];
  const int* labels = (const int*)d_in[1];
  const float* k1  = (const float*)d_in[2];
  const float* cb1 = (const float*)d_in[3];
  const float* g1  = (const float*)d_in[4];
  const float* be1 = (const float*)d_in[5];
  const float* mm1 = (const float*)d_in[6];
  const float* mv1 = (const float*)d_in[7];
  const float* k2  = (const float*)d_in[8];
  const float* cb2 = (const float*)d_in[9];
  const float* g2  = (const float*)d_in[10];
  const float* be2 = (const float*)d_in[11];
  const float* mm2 = (const float*)d_in[12];
  const float* mv2 = (const float*)d_in[13];
  const float* k3  = (const float*)d_in[14];
  const float* cb3 = (const float*)d_in[15];
  const float* g3  = (const float*)d_in[16];
  const float* be3 = (const float*)d_in[17];
  const float* mm3 = (const float*)d_in[18];
  const float* mv3 = (const float*)d_in[19];
  const float* Wx  = (const float*)d_in[20];
  const float* Wh  = (const float*)d_in[21];
  const float* bl  = (const float*)d_in[22];
  const float* Wp  = (const float*)d_in[23];
  const float* bp  = (const float*)d_in[24];
  const float* Wo  = (const float*)d_in[25];
  const float* bo  = (const float*)d_in[26];
  const float* Wf  = (const float*)d_in[27];
  const float* bf  = (const float*)d_in[28];
  float* ws = (float*)d_ws;

  hipFuncSetAttribute((const void*)lstm_kernel,
                      hipFuncAttributeMaxDynamicSharedMemorySize, DYN_BYTES);

  // zero all pair buffers + counters (tags -> 0 = step-0 zero state)
  hipMemsetAsync((char*)d_ws + OFF_ZP2A * sizeof(float), 0,
                 (OFF_WPT - OFF_ZP2A) * sizeof(float), stream);
  prep_kernel<<<1024, 256, 0, stream>>>(Wx, Wh, bl, Wp, ws);
  conv_kernel<<<8000, 128, 0, stream>>>(images,
      k1, cb1, g1, be1, mm1, mv1,
      k2, cb2, g2, be2, mm2, mv2,
      k3, cb3, g3, be3, mm3, mv3, ws);
  lstm_kernel<<<256, 512, DYN_BYTES, stream>>>(labels, Wo, bo, Wp, bp, Wf, bf, ws,
                                               (float*)d_out);
}

// Round 6
// 3824.966 us; speedup vs baseline: 1.5620x; 1.0050x over previous
//
#include <hip/hip_runtime.h>

// ---------------- problem constants ----------------
// B=32, T=250, FEAT=128, CLASSES=25, UNITS=512, CELL=64, HEADS=4, IN_LSTM=409

// ---------------- scratch layout (floats) ----------------
// All inter-block activations are (value,epoch) PAIRS (8 B, stored atomically).
constexpr size_t OFF_FEATP  = 0;                              // [8000][128]
constexpr size_t OFF_WXI    = OFF_FEATP + (size_t)8000 * 128; // [409][2048] gate-interleaved
constexpr size_t OFF_WHI    = OFF_WXI + (size_t)409 * 2048;   // [512][2048]
constexpr size_t OFF_BLI    = OFF_WHI + (size_t)512 * 2048;   // [2048]
constexpr size_t OFF_ZP2A   = OFF_BLI + 2048;                 // [2][32][2048]p (k-half 0 + bias/label)
constexpr size_t OFF_ZP2B   = OFF_ZP2A + 262144;              // [2][32][2048]p (k-half 1)
constexpr size_t OFF_OH2A   = OFF_ZP2B + 262144;              // [2][32][512]p
constexpr size_t OFF_OH2B   = OFF_OH2A + 65536;               // [2][32][512]p
constexpr size_t OFF_OUTPRE2= OFF_OH2B + 65536;               // [32][512]p
constexpr size_t OFF_HT2    = OFF_OUTPRE2 + 32768;            // [2][512][32]p
constexpr size_t OFF_HTT2   = OFF_HT2 + 65536;                // [2][32][512]p
constexpr size_t OFF_RVT2   = OFF_HTT2 + 65536;               // [2][256][32]p
constexpr size_t OFF_WVP2   = OFF_RVT2 + 32768;               // [2][2][32][64]p
constexpr size_t OFF_BAR    = OFF_WVP2 + 16384;               // counters (4096 ints)
constexpr size_t OFF_WPT    = OFF_BAR + 4096;                 // [128][320][4] k-major Wp
constexpr size_t WS_FLOATS  = OFF_WPT + (size_t)163840;

constexpr int DYN_FLOATS = 34816;                 // 136 KB dynamic LDS
constexpr int DYN_BYTES  = DYN_FLOATS * 4;

// WAR-slack counters only (8 lines x 64-int stride each). RAW sync is via tags.
constexpr int COH = 0, COP = 512, CCO = 1024, CRING = 1536;

__device__ __forceinline__ float sigm(float x) { return 1.f / (1.f + __expf(-x)); }

typedef int iv2 __attribute__((ext_vector_type(2)));
typedef int iv4 __attribute__((ext_vector_type(4)));
typedef float fv4 __attribute__((ext_vector_type(4)));

// ---- LLC-coherent accesses (bypass L1+L2). Batched loads with the waitcnt
// inside the asm so they are one round trip.
__device__ __forceinline__ void st_pair(float* base, size_t pidx, float v, int tag) {
  unsigned long long u = (unsigned long long)__float_as_uint(v) |
                         ((unsigned long long)(unsigned)tag << 32);
  __hip_atomic_store((unsigned long long*)(base + 2 * pidx), u,
                     __ATOMIC_RELAXED, __HIP_MEMORY_SCOPE_AGENT);
}
__device__ __forceinline__ float spin_pair(const float* base, size_t pidx, int tag) {
  const iv2* p = (const iv2*)(base + 2 * pidx);
  iv2 v;
  for (;;) {
    asm volatile("global_load_dwordx2 %0, %1, off sc0 sc1\n\ts_waitcnt vmcnt(0)"
                 : "=&v"(v) : "v"(p) : "memory");
    if (v[1] == tag) break;
    __builtin_amdgcn_s_sleep(1);
  }
  return __int_as_float(v[0]);
}
// two pairs at separate addresses
__device__ __forceinline__ float2 spin_pair_2addr(const float* a, const float* b, int tag) {
  const iv2* pa = (const iv2*)a;
  const iv2* pb = (const iv2*)b;
  iv2 x, y;
  for (;;) {
    asm volatile(
        "global_load_dwordx2 %0, %2, off sc0 sc1\n\t"
        "global_load_dwordx2 %1, %3, off sc0 sc1\n\t"
        "s_waitcnt vmcnt(0)"
        : "=&v"(x), "=&v"(y) : "v"(pa), "v"(pb) : "memory");
    if (x[1] == tag && y[1] == tag) break;
    __builtin_amdgcn_s_sleep(1);
  }
  return {__int_as_float(x[0]), __int_as_float(y[0])};
}
// four pairs at separate addresses (COUT quad spin)
__device__ __forceinline__ void ld4x2_sc(const iv2* a, const iv2* b, const iv2* c,
                                         const iv2* d, iv2& x, iv2& y, iv2& z, iv2& w) {
  asm volatile(
      "global_load_dwordx2 %0, %4, off sc0 sc1\n\t"
      "global_load_dwordx2 %1, %5, off sc0 sc1\n\t"
      "global_load_dwordx2 %2, %6, off sc0 sc1\n\t"
      "global_load_dwordx2 %3, %7, off sc0 sc1\n\t"
      "s_waitcnt vmcnt(0)"
      : "=&v"(x), "=&v"(y), "=&v"(z), "=&v"(w)
      : "v"(a), "v"(b), "v"(c), "v"(d) : "memory");
}
__device__ __forceinline__ void ld8i4_sc(const iv4* b0, iv4* v) {
  const iv4 *p0 = b0, *p1 = b0 + 512, *p2 = b0 + 1024, *p3 = b0 + 1536,
            *p4 = b0 + 2048, *p5 = b0 + 2560, *p6 = b0 + 3072, *p7 = b0 + 3584;
  asm volatile(
      "global_load_dwordx4 %0, %8, off sc0 sc1\n\t"
      "global_load_dwordx4 %1, %9, off sc0 sc1\n\t"
      "global_load_dwordx4 %2, %10, off sc0 sc1\n\t"
      "global_load_dwordx4 %3, %11, off sc0 sc1\n\t"
      "global_load_dwordx4 %4, %12, off sc0 sc1\n\t"
      "global_load_dwordx4 %5, %13, off sc0 sc1\n\t"
      "global_load_dwordx4 %6, %14, off sc0 sc1\n\t"
      "global_load_dwordx4 %7, %15, off sc0 sc1\n\t"
      "s_waitcnt vmcnt(0)"
      : "=&v"(v[0]), "=&v"(v[1]), "=&v"(v[2]), "=&v"(v[3]),
        "=&v"(v[4]), "=&v"(v[5]), "=&v"(v[6]), "=&v"(v[7])
      : "v"(p0), "v"(p1), "v"(p2), "v"(p3), "v"(p4), "v"(p5), "v"(p6), "v"(p7)
      : "memory");
}
// 8 strided dwordx4 (rv) + 2 dwordx4 at free addresses, one waitcnt
__device__ __forceinline__ void ld10i4_sc(const iv4* b0, const iv4* z0,
                                          const iv4* z1, iv4* v) {
  const iv4 *p0 = b0, *p1 = b0 + 512, *p2 = b0 + 1024, *p3 = b0 + 1536,
            *p4 = b0 + 2048, *p5 = b0 + 2560, *p6 = b0 + 3072, *p7 = b0 + 3584;
  asm volatile(
      "global_load_dwordx4 %0, %10, off sc0 sc1\n\t"
      "global_load_dwordx4 %1, %11, off sc0 sc1\n\t"
      "global_load_dwordx4 %2, %12, off sc0 sc1\n\t"
      "global_load_dwordx4 %3, %13, off sc0 sc1\n\t"
      "global_load_dwordx4 %4, %14, off sc0 sc1\n\t"
      "global_load_dwordx4 %5, %15, off sc0 sc1\n\t"
      "global_load_dwordx4 %6, %16, off sc0 sc1\n\t"
      "global_load_dwordx4 %7, %17, off sc0 sc1\n\t"
      "global_load_dwordx4 %8, %18, off sc0 sc1\n\t"
      "global_load_dwordx4 %9, %19, off sc0 sc1\n\t"
      "s_waitcnt vmcnt(0)"
      : "=&v"(v[0]), "=&v"(v[1]), "=&v"(v[2]), "=&v"(v[3]), "=&v"(v[4]),
        "=&v"(v[5]), "=&v"(v[6]), "=&v"(v[7]), "=&v"(v[8]), "=&v"(v[9])
      : "v"(p0), "v"(p1), "v"(p2), "v"(p3), "v"(p4), "v"(p5), "v"(p6), "v"(p7),
        "v"(z0), "v"(z1)
      : "memory");
}
// counter poll: sum of 8 lines, single batched round trip
__device__ __forceinline__ int sum8_bar(const int* b) {
  int v0, v1, v2, v3, v4, v5, v6, v7;
  asm volatile(
      "global_load_dword %0, %8, off sc0 sc1\n\t"
      "global_load_dword %1, %9, off sc0 sc1\n\t"
      "global_load_dword %2, %10, off sc0 sc1\n\t"
      "global_load_dword %3, %11, off sc0 sc1\n\t"
      "global_load_dword %4, %12, off sc0 sc1\n\t"
      "global_load_dword %5, %13, off sc0 sc1\n\t"
      "global_load_dword %6, %14, off sc0 sc1\n\t"
      "global_load_dword %7, %15, off sc0 sc1\n\t"
      "s_waitcnt vmcnt(0)"
      : "=&v"(v0), "=&v"(v1), "=&v"(v2), "=&v"(v3),
        "=&v"(v4), "=&v"(v5), "=&v"(v6), "=&v"(v7)
      : "v"(b), "v"(b + 64), "v"(b + 128), "v"(b + 192),
        "v"(b + 256), "v"(b + 320), "v"(b + 384), "v"(b + 448)
      : "memory");
  return ((v0 + v1) + (v2 + v3)) + ((v4 + v5) + (v6 + v7));
}

// ---------------- weight re-layout: gate-interleaved Wx/Wh/bl + k-major Wp ----------------
__global__ __launch_bounds__(256) void prep_kernel(const float* __restrict__ Wx,
                                                   const float* __restrict__ Wh,
                                                   const float* __restrict__ bl,
                                                   const float* __restrict__ Wp,
                                                   float* __restrict__ ws) {
  float* WXI = ws + OFF_WXI;
  float* WHI = ws + OFF_WHI;
  float* BLI = ws + OFF_BLI;
  float* WPT = ws + OFF_WPT;
  const int t0 = 409 * 2048;
  const int t1 = t0 + 512 * 2048;
  const int t2 = t1 + 2048;
  const int total = t2 + 163840;
  for (int idx = blockIdx.x * blockDim.x + threadIdx.x; idx < total;
       idx += gridDim.x * blockDim.x) {
    if (idx < t0) {
      int k = idx >> 11, cc = idx & 2047;
      WXI[idx] = Wx[(size_t)k * 2048 + (cc & 3) * 512 + (cc >> 2)];
    } else if (idx < t1) {
      int j = idx - t0;
      int k = j >> 11, cc = j & 2047;
      WHI[j] = Wh[(size_t)k * 2048 + (cc & 3) * 512 + (cc >> 2)];
    } else if (idx < t2) {
      int cc = idx - t1;
      BLI[cc] = bl[(cc & 3) * 512 + (cc >> 2)];
    } else {
      // WPT[k4][j][ks] = Wp[k4*4+ks][j]
      int e = idx - t2;
      int k4 = e / 1280, r = e - k4 * 1280;
      int j = r >> 2, ks = r & 3;
      WPT[e] = Wp[(size_t)(k4 * 4 + ks) * 320 + j];
    }
  }
}

// ---------------- conv stack (validated) ----------------
__global__ __launch_bounds__(128) void conv_kernel(
    const float* __restrict__ img,
    const float* __restrict__ k1, const float* __restrict__ cb1, const float* __restrict__ g1,
    const float* __restrict__ be1, const float* __restrict__ mm1, const float* __restrict__ mv1,
    const float* __restrict__ k2, const float* __restrict__ cb2, const float* __restrict__ g2,
    const float* __restrict__ be2, const float* __restrict__ mm2, const float* __restrict__ mv2,
    const float* __restrict__ k3, const float* __restrict__ cb3, const float* __restrict__ g3,
    const float* __restrict__ be3, const float* __restrict__ mm3, const float* __restrict__ mv3,
    float* __restrict__ ws) {
  __shared__ float s_in[784];
  __shared__ float s_y1[13 * 13 * 8];
  __shared__ float s_y2[6 * 6 * 16];
  __shared__ float s_k1[72], s_k2[1152], s_k3[4608];
  __shared__ float s_s1[8], s_b1[8], s_s2[16], s_b2[16], s_s3[32], s_b3[32];
  float* FEATP = ws + OFF_FEATP;
  const int n = blockIdx.x, tid = threadIdx.x;
  const float* ip = img + (size_t)n * 784;
  for (int i = tid; i < 784; i += 128) s_in[i] = ip[i];
  for (int i = tid; i < 72; i += 128) s_k1[i] = k1[i];
  for (int i = tid; i < 1152; i += 128) s_k2[i] = k2[i];
  for (int i = tid; i < 4608; i += 128) s_k3[i] = k3[i];
  if (tid < 8) {
    float s = g1[tid] * rsqrtf(mv1[tid] + 1e-3f);
    s_s1[tid] = s; s_b1[tid] = (cb1[tid] - mm1[tid]) * s + be1[tid];
  } else if (tid >= 32 && tid < 48) {
    int c = tid - 32;
    float s = g2[c] * rsqrtf(mv2[c] + 1e-3f);
    s_s2[c] = s; s_b2[c] = (cb2[c] - mm2[c]) * s + be2[c];
  } else if (tid >= 64 && tid < 96) {
    int c = tid - 64;
    float s = g3[c] * rsqrtf(mv3[c] + 1e-3f);
    s_s3[c] = s; s_b3[c] = (cb3[c] - mm3[c]) * s + be3[c];
  }
  __syncthreads();
  for (int idx = tid; idx < 13 * 13 * 8; idx += 128) {
    int co = idx & 7, pos = idx >> 3;
    int j = pos % 13, i = pos / 13;
    float acc = 0.f;
    #pragma unroll
    for (int ky = 0; ky < 3; ++ky)
      #pragma unroll
      for (int kx = 0; kx < 3; ++kx)
        acc += s_in[(2 * i + ky) * 28 + (2 * j + kx)] * s_k1[(ky * 3 + kx) * 8 + co];
    float v = acc * s_s1[co] + s_b1[co];
    s_y1[idx] = v > 0.f ? v : 0.f;
  }
  __syncthreads();
  for (int idx = tid; idx < 6 * 6 * 16; idx += 128) {
    int co = idx & 15, pos = idx >> 4;
    int j = pos % 6, i = pos / 6;
    float acc = 0.f;
    for (int ky = 0; ky < 3; ++ky)
      for (int kx = 0; kx < 3; ++kx) {
        int base = ((2 * i + ky) * 13 + (2 * j + kx)) * 8;
        int kb = (ky * 3 + kx) * 128 + co;
        #pragma unroll
        for (int ci = 0; ci < 8; ++ci) acc += s_y1[base + ci] * s_k2[kb + ci * 16];
      }
    float v = acc * s_s2[co] + s_b2[co];
    s_y2[idx] = v > 0.f ? v : 0.f;
  }
  __syncthreads();
  for (int idx = tid; idx < 128; idx += 128) {
    int co = idx & 31, pos = idx >> 5;
    int j = pos & 1, i = pos >> 1;
    float acc = 0.f;
    for (int ky = 0; ky < 3; ++ky)
      for (int kx = 0; kx < 3; ++kx) {
        int base = ((2 * i + ky) * 6 + (2 * j + kx)) * 16;
        int kb = (ky * 3 + kx) * 512 + co;
        #pragma unroll
        for (int ci = 0; ci < 16; ++ci) acc += s_y2[base + ci] * s_k3[kb + ci * 32];
      }
    float v = acc * s_s3[co] + s_b3[co];
    FEATP[(size_t)n * 128 + idx] = v > 0.f ? v : 0.f;
  }
}

// ---------------- persistent LSTM scan: tagged-pair dataflow ----------------
// Roles: AZ 0-63 | AO 64-79 | ZH 80-143 (E64, K-halves) | OL 144-159 /
// OHI 160-175 | ATT 176-239 | WV 240-243 | COUT 244-251 | 252-255 idle.
// Epochs: h_t/rv_t/ZP_t/OH_t/WVP_t -> tag t+1; OUTPRE (AO step t) -> tag t.
// Zeroed buffers (tag 0) ARE the t=0 zero state.
__global__ __launch_bounds__(512) void lstm_kernel(
    const int* __restrict__ labels,
    const float* __restrict__ Wo, const float* __restrict__ bo,
    const float* __restrict__ Wp, const float* __restrict__ bp,
    const float* __restrict__ Wf, const float* __restrict__ bf,
    float* __restrict__ ws, float* __restrict__ out) {
  extern __shared__ float dyn[];
  const float* FEATP = ws + OFF_FEATP;
  const float* WXI   = ws + OFF_WXI;
  const float* WHI   = ws + OFF_WHI;
  const float* BLI   = ws + OFF_BLI;
  float* ZP2A   = ws + OFF_ZP2A;
  float* ZP2B   = ws + OFF_ZP2B;
  float* OH2A   = ws + OFF_OH2A;
  float* OH2B   = ws + OFF_OH2B;
  float* OUTPRE2= ws + OFF_OUTPRE2;
  float* HT2    = ws + OFF_HT2;     // [2][512][32]p
  float* HTT2   = ws + OFF_HTT2;    // [2][32][512]p
  float* RVT2   = ws + OFF_RVT2;    // [2][256][32]p
  float* WVP2   = ws + OFF_WVP2;    // [2][2][32][64]p
  const float* WPT = ws + OFF_WPT;  // [128][320][4]
  int*   BARp   = (int*)(ws + OFF_BAR);

  const int bid = blockIdx.x;
  const int tid = threadIdx.x;

  // cached WAR wait: skip the LLC poll when the cached read already covers it.
  int* bc = (int*)(dyn + 34808);
  auto waitC = [&](int base, int target, int& cache) {
    if (cache >= target) return;
    if (tid == 0) {
      int v = sum8_bar(BARp + base);
      while (v < target) v = sum8_bar(BARp + base);
      bc[base >> 9] = v;
    }
    __syncthreads();
    cache = bc[base >> 9];
    __syncthreads();
  };
  auto bumpC = [&](int base) {
    asm volatile("s_waitcnt vmcnt(0)" ::: "memory");
    __syncthreads();
    if (tid == 0) atomicAdd(&BARp[base + ((bid & 7) << 6)], 1);
  };

  // spin-stage an 8192-value pair buffer ([256][32]p) into [256][36]-padded LDS
  auto stageP = [&](float* dst, const float* srcPairs, int tag) {
    const iv4* sp = (const iv4*)srcPairs + tid;
    iv4 v[8];
    for (;;) {
      ld8i4_sc(sp, v);
      bool ok = true;
      #pragma unroll
      for (int j = 0; j < 8; ++j) ok = ok && (v[j][1] == tag) && (v[j][3] == tag);
      if (ok) break;
      __builtin_amdgcn_s_sleep(2);
    }
    #pragma unroll
    for (int j = 0; j < 8; ++j) {
      int i = (tid + j * 512) << 1;
      float2 f = {__int_as_float(v[j][0]), __int_as_float(v[j][2])};
      *(float2*)&dst[(i >> 5) * 36 + (i & 31)] = f;
    }
  };

  // ---- E32: Y[32c][32b] (validated). K mult of 16.
  auto E32 = [&](const float* Wm, const float* Am, int K, float* part, float2& r) {
    const int wv = tid >> 6, l = tid & 63;
    const int ksub = l & 1, cg = (l >> 1) & 3, bg = l >> 3;
    const int Kp = K >> 4;
    const int kb = wv * (K >> 3) + ksub * Kp;
    const float* wp = Wm + (size_t)kb * 32 + cg * 8;
    const float* ap = Am + (size_t)kb * 36 + bg * 4;
    float4 acc[8];
    #pragma unroll
    for (int i = 0; i < 8; ++i) acc[i] = {0.f, 0.f, 0.f, 0.f};
    #pragma unroll 4
    for (int kk = 0; kk < Kp; ++kk) {
      float4 w0 = *(const float4*)(wp + kk * 32);
      float4 w1 = *(const float4*)(wp + kk * 32 + 4);
      float4 a  = *(const float4*)(ap + kk * 36);
      float wl[8];
      *(float4*)&wl[0] = w0; *(float4*)&wl[4] = w1;
      #pragma unroll
      for (int i = 0; i < 8; ++i) {
        acc[i].x = fmaf(wl[i], a.x, acc[i].x);
        acc[i].y = fmaf(wl[i], a.y, acc[i].y);
        acc[i].z = fmaf(wl[i], a.z, acc[i].z);
        acc[i].w = fmaf(wl[i], a.w, acc[i].w);
      }
    }
    #pragma unroll
    for (int i = 0; i < 8; ++i) {
      acc[i].x += __shfl_xor(acc[i].x, 1, 64);
      acc[i].y += __shfl_xor(acc[i].y, 1, 64);
      acc[i].z += __shfl_xor(acc[i].z, 1, 64);
      acc[i].w += __shfl_xor(acc[i].w, 1, 64);
    }
    const int ob = (cg * 8) * 36 + bg * 4;
    if (ksub == 0 && wv < 4) {
      float* pb = part + wv * 1152 + ob;
      #pragma unroll
      for (int i = 0; i < 8; ++i) *(float4*)(pb + i * 36) = acc[i];
    }
    __syncthreads();
    if (ksub == 0 && wv >= 4) {
      float* pb = part + (wv - 4) * 1152 + ob;
      #pragma unroll
      for (int i = 0; i < 8; ++i) {
        float4 t = *(float4*)(pb + i * 36);
        t.x += acc[i].x; t.y += acc[i].y; t.z += acc[i].z; t.w += acc[i].w;
        *(float4*)(pb + i * 36) = t;
      }
    }
    __syncthreads();
    const int c = tid & 31, b2 = (tid >> 5) * 2;
    const int o = c * 36 + b2;
    float2 s0 = *(float2*)(part + o);
    float2 s1 = *(float2*)(part + 1152 + o);
    float2 s2 = *(float2*)(part + 2304 + o);
    float2 s3 = *(float2*)(part + 3456 + o);
    r.x = (s0.x + s1.x) + (s2.x + s3.x);
    r.y = (s0.y + s1.y) + (s2.y + s3.y);
  };

  // ---- E64: Y[64c][32b], K=256, rotated weight slab (validated).
  auto E64 = [&](const float* Wm, const float* Am, float* part, float4& r) {
    const int wv = tid >> 6, l = tid & 63;
    const int ksub = l & 1, cg = (l >> 1) & 7, bg = l >> 4;
    const int kb = wv * 32 + ksub * 16;
    const float* wp0 = Wm + (size_t)kb * 64 + ((cg * 8 + ksub * 4) & 63);
    const float* wp1 = Wm + (size_t)kb * 64 + ((cg * 8 + 4 + ksub * 4) & 63);
    const float* ap = Am + (size_t)kb * 36 + bg * 8;
    float4 acc[8][2];
    #pragma unroll
    for (int i = 0; i < 8; ++i) { acc[i][0] = {0.f,0.f,0.f,0.f}; acc[i][1] = {0.f,0.f,0.f,0.f}; }
    #pragma unroll 2
    for (int kk = 0; kk < 16; ++kk) {
      float4 w0 = *(const float4*)(wp0 + kk * 64);
      float4 w1 = *(const float4*)(wp1 + kk * 64);
      float4 a0 = *(const float4*)(ap + kk * 36);
      float4 a1 = *(const float4*)(ap + kk * 36 + 4);
      float wl[8];
      *(float4*)&wl[0] = w0; *(float4*)&wl[4] = w1;
      #pragma unroll
      for (int i = 0; i < 8; ++i) {
        acc[i][0].x = fmaf(wl[i], a0.x, acc[i][0].x);
        acc[i][0].y = fmaf(wl[i], a0.y, acc[i][0].y);
        acc[i][0].z = fmaf(wl[i], a0.z, acc[i][0].z);
        acc[i][0].w = fmaf(wl[i], a0.w, acc[i][0].w);
        acc[i][1].x = fmaf(wl[i], a1.x, acc[i][1].x);
        acc[i][1].y = fmaf(wl[i], a1.y, acc[i][1].y);
        acc[i][1].z = fmaf(wl[i], a1.z, acc[i][1].z);
        acc[i][1].w = fmaf(wl[i], a1.w, acc[i][1].w);
      }
    }
    #pragma unroll
    for (int i = 0; i < 8; ++i) {
      #pragma unroll
      for (int j = 0; j < 2; ++j) {
        acc[i][j].x += __shfl_xor(acc[i][j].x, 1, 64);
        acc[i][j].y += __shfl_xor(acc[i][j].y, 1, 64);
        acc[i][j].z += __shfl_xor(acc[i][j].z, 1, 64);
        acc[i][j].w += __shfl_xor(acc[i][j].w, 1, 64);
      }
    }
    const int ob = (cg * 8) * 36 + bg * 8;
    if (ksub == 0 && wv < 4) {
      float* pb = part + wv * 2304 + ob;
      #pragma unroll
      for (int i = 0; i < 8; ++i) {
        *(float4*)(pb + i * 36) = acc[i][0];
        *(float4*)(pb + i * 36 + 4) = acc[i][1];
      }
    }
    __syncthreads();
    if (ksub == 0 && wv >= 4) {
      float* pb = part + (wv - 4) * 2304 + ob;
      #pragma unroll
      for (int i = 0; i < 8; ++i) {
        float4 t0 = *(float4*)(pb + i * 36);
        float4 t1 = *(float4*)(pb + i * 36 + 4);
        t0.x += acc[i][0].x; t0.y += acc[i][0].y; t0.z += acc[i][0].z; t0.w += acc[i][0].w;
        t1.x += acc[i][1].x; t1.y += acc[i][1].y; t1.z += acc[i][1].z; t1.w += acc[i][1].w;
        *(float4*)(pb + i * 36) = t0;
        *(float4*)(pb + i * 36 + 4) = t1;
      }
    }
    __syncthreads();
    const int c = tid & 63, b4 = (tid >> 6) * 4;
    const int o = c * 36 + b4;
    float4 s0 = *(float4*)(part + o);
    float4 s1 = *(float4*)(part + 2304 + o);
    float4 s2 = *(float4*)(part + 4608 + o);
    float4 s3 = *(float4*)(part + 6912 + o);
    r.x = (s0.x + s1.x) + (s2.x + s3.x);
    r.y = (s0.y + s1.y) + (s2.y + s3.y);
    r.z = (s0.z + s1.z) + (s2.z + s3.z);
    r.w = (s0.w + s1.w) + (s2.w + s3.w);
  };

  // ---------------- one-time init: weights -> LDS ----------------
  if (bid < 64) {            // AZ: Wz (rv part of Wx) + Wxx (x part)
    const int c0 = bid * 32;
    for (int i = tid; i < 8192; i += 512)
      dyn[i] = WXI[(size_t)(153 + (i >> 5)) * 2048 + c0 + (i & 31)];
    for (int i = tid; i < 4096; i += 512)
      dyn[8192 + i] = WXI[(size_t)(i >> 5) * 2048 + c0 + (i & 31)];
    if (tid < 256) dyn[12288 + tid] = 0.f;  // Cst
  } else if (bid < 80) {     // AO: Wo rows 512..768
    const int u0 = (bid - 64) * 32;
    for (int i = tid; i < 8192; i += 512)
      dyn[i] = Wo[(size_t)(512 + (i >> 5)) * 512 + u0 + (i & 31)];
    if (tid < 32) dyn[8192 + tid] = bo[u0 + tid];
  } else if (bid < 144) {    // ZH: rotated E64 slab Wh[kh*256..+256][j0..j0+64]
    const int r = bid - 80;
    const int j0 = (r & 31) * 64, kh = r >> 5;
    for (int i = tid; i < 16384; i += 512) {
      int k = i >> 6, cc = i & 63;
      int cr = (cc + ((k >> 4) & 1) * 4) & 63;
      dyn[k * 64 + cr] = WHI[(size_t)(kh * 256 + k) * 2048 + j0 + cc];
    }
  } else if (bid < 160) {    // OL: Wo rows 0..256
    const int u0 = (bid - 144) * 32;
    for (int i = tid; i < 8192; i += 512)
      dyn[i] = Wo[(size_t)(i >> 5) * 512 + u0 + (i & 31)];
  } else if (bid < 176) {    // OHI: Wo rows 256..512
    const int u0 = (bid - 160) * 32;
    for (int i = tid; i < 8192; i += 512)
      dyn[i] = Wo[(size_t)(256 + (i >> 5)) * 512 + u0 + (i & 31)];
  } else if (bid < 240) {    // ATT: ring + cached norms + bias slices
    const int hp = (bid - 176) & 1;
    for (int i = tid; i < 17000; i += 512) dyn[i] = 0.f;            // ring[250][68]
    if (tid < 256) dyn[17000 + tid] = rsqrtf(1e-12f);               // rn
    if (tid < 128) dyn[21264 + tid] = bp[64 + hp * 128 + tid];      // bpk
    if (tid < 64)  dyn[21392 + tid] = bp[tid];                      // bpw
  } else if (bid < 244) {    // WV: Wp[kh*256..+256][cp*32..+32]
    const int kh = (bid - 240) >> 1, cp = (bid - 240) & 1;
    for (int i = tid; i < 8192; i += 512) {
      int k = i >> 5, c = i & 31;
      dyn[i] = Wp[(size_t)(kh * 256 + k) * 320 + cp * 32 + c];
    }
  } else if (bid < 252) {    // COUT: Wf + bf
    for (int i = tid; i < 12800; i += 512) dyn[i] = Wf[i];
    if (tid < 25) dyn[12800 + tid] = bf[tid];
  }
  __syncthreads();

  // ================= role bodies =================
  // AZ dyn: Wz[0,8192) Wxx[8192,12288) Cst[12288,12544) rvT[12544,21760)
  //         xT[21760,26368) zx[26368,27392) zf[27392,28416) part[28416,33024)
  // Combined spin: rv_{t-1} (8 iv4, tag t) + ZP_t A/B (2 iv4, tag t+1) in ONE
  // LLC round trip (AO-validated load shape).
  auto azStage = [&](int t) {
    const float* rvP = RVT2 + ((t + 1) & 1) * 16384;
    const float* zaP = ZP2A + (t & 1) * 131072;
    const float* zbP = ZP2B + (t & 1) * 131072;
    float* rvT = dyn + 12544; float* zf = dyn + 27392;
    const int bb = tid >> 4, c2 = tid & 15;
    const iv4* rp = (const iv4*)rvP + tid;
    const size_t zi = (size_t)bb * 1024 + bid * 16 + c2;
    const iv4* za = (const iv4*)zaP + zi;
    const iv4* zb = (const iv4*)zbP + zi;
    iv4 v[10];
    for (;;) {
      ld10i4_sc(rp, za, zb, v);
      bool ok = true;
      #pragma unroll
      for (int j = 0; j < 8; ++j) ok = ok && (v[j][1] == t) && (v[j][3] == t);
      ok = ok && (v[8][1] == t + 1) && (v[8][3] == t + 1) &&
                 (v[9][1] == t + 1) && (v[9][3] == t + 1);
      if (ok) break;
      __builtin_amdgcn_s_sleep(1);
    }
    #pragma unroll
    for (int j = 0; j < 8; ++j) {
      int i = (tid + j * 512) << 1;
      float2 f = {__int_as_float(v[j][0]), __int_as_float(v[j][2])};
      *(float2*)&rvT[(i >> 5) * 36 + (i & 31)] = f;
    }
    float2 s = {__int_as_float(v[8][0]) + __int_as_float(v[9][0]),
                __int_as_float(v[8][2]) + __int_as_float(v[9][2])};
    *(float2*)&zf[bb * 32 + c2 * 2] = s;
  };
  auto azX = [&](int tt) {    // zx = x_{tt}@Wx, local
    float* Wxx = dyn + 8192; float* xT = dyn + 21760;
    float* zx = dyn + 26368; float* part = dyn + 28416;
    for (int i = tid; i < 4096; i += 512) {
      int b = i >> 7, k = i & 127;
      xT[k * 36 + b] = FEATP[((size_t)b * 250 + tt) * 128 + k];
    }
    __syncthreads();
    float2 r;
    E32(Wxx, xT, 128, part, r);
    const int c = tid & 31, b2 = (tid >> 5) * 2;
    zx[b2 * 32 + c] = r.x;
    zx[(b2 + 1) * 32 + c] = r.y;
  };
  // AO dyn: W[0,8192) bo[8192,8224) rvT[8224,17440) of[17440,18464) part[18464,23072)
  auto aoOut = [&](int t) {   // outpre_{t-1}: rv_{t-1} (tag t), OH_{t-1} (tag t)
    const int u0 = (bid - 64) * 32;
    const float* rvP  = RVT2 + ((t + 1) & 1) * 16384;
    const float* ohaP = OH2A + ((t + 1) & 1) * 32768;
    const float* ohbP = OH2B + ((t + 1) & 1) * 32768;
    float* W = dyn; float* bo_l = dyn + 8192; float* rvT = dyn + 8224;
    float* of = dyn + 17440; float* part = dyn + 18464;
    {
      const int b = tid >> 4, c2 = tid & 15;
      const iv4* rp = (const iv4*)rvP + tid;
      const iv4* za = (const iv4*)ohaP + (b * 256 + (u0 >> 1) + c2);
      const iv4* zb = (const iv4*)ohbP + (b * 256 + (u0 >> 1) + c2);
      iv4 v[10];
      for (;;) {
        ld10i4_sc(rp, za, zb, v);
        bool ok = true;
        #pragma unroll
        for (int j = 0; j < 10; ++j) ok = ok && (v[j][1] == t) && (v[j][3] == t);
        if (ok) break;
        __builtin_amdgcn_s_sleep(2);
      }
      #pragma unroll
      for (int j = 0; j < 8; ++j) {
        int i = (tid + j * 512) << 1;
        float2 f = {__int_as_float(v[j][0]), __int_as_float(v[j][2])};
        *(float2*)&rvT[(i >> 5) * 36 + (i & 31)] = f;
      }
      float2 s = {__int_as_float(v[8][0]) + __int_as_float(v[9][0]),
                  __int_as_float(v[8][2]) + __int_as_float(v[9][2])};
      *(float2*)&of[b * 32 + c2 * 2] = s;
    }
    __syncthreads();
    float2 r;
    E32(W, rvT, 256, part, r);
    const int c = tid & 31, b2 = (tid >> 5) * 2;
    float bv = bo_l[c];
    st_pair(OUTPRE2, (size_t)b2 * 512 + u0 + c, r.x + of[b2 * 32 + c] + bv, t);
    st_pair(OUTPRE2, (size_t)(b2 + 1) * 512 + u0 + c, r.y + of[(b2 + 1) * 32 + c] + bv, t);
  };
  // OL/OHI dyn: W[0,8192) A[8192,17408) part[17408,22016)
  auto p2Gemm = [&](int t) {
    const float* htP = HT2 + (t & 1) * 32768;
    float* W = dyn; float* A = dyn + 8192; float* part = dyn + 17408;
    const bool isOLr = bid < 160;
    stageP(A, isOLr ? htP : (htP + 16384), t + 1);
    __syncthreads();
    float2 r;
    E32(W, A, 256, part, r);
    const int c = tid & 31, b2 = (tid >> 5) * 2;
    const int u0 = (isOLr ? (bid - 144) : (bid - 160)) * 32;
    float* d = (isOLr ? OH2A : OH2B) + (t & 1) * 32768;
    st_pair(d, (size_t)b2 * 512 + u0 + c, r.x, t + 1);
    st_pair(d, (size_t)(b2 + 1) * 512 + u0 + c, r.y, t + 1);
  };

  // ---------------- dataflow role loops ----------------
  if (bid < 64) {                       // AZ
    int cCOH = 0;
    float* Wz = dyn; float* Cst = dyn + 12288; float* rvT = dyn + 12544;
    float* zx = dyn + 26368; float* zf = dyn + 27392; float* part = dyn + 28416;
    azX(0);
    for (int t = 0; t < 250; ++t) {
      azStage(t);                                // RAW ZP_t + rv_{t-1}, one RTT
      if (t >= 2) waitC(COH, 32 * (t - 1), cCOH);// HT WAR: OL/OHI_{t-2} read done
      __syncthreads();
      float2 r;
      E32(Wz, rvT, 256, part, r);
      const int c = tid & 31, b2 = (tid >> 5) * 2;
      zf[b2 * 32 + c] += r.x + zx[b2 * 32 + c];
      zf[(b2 + 1) * 32 + c] += r.y + zx[(b2 + 1) * 32 + c];
      __syncthreads();
      if (tid < 256) {
        int u = tid & 7, b = tid >> 3;
        float4 z = *(float4*)(zf + b * 32 + u * 4);
        float ig = sigm(z.x), fg = sigm(z.y), gg = tanhf(z.z), og = sigm(z.w);
        float cc = fg * Cst[b * 8 + u] + ig * gg;
        Cst[b * 8 + u] = cc;
        float hv = og * tanhf(cc);
        st_pair(HT2 + (t & 1) * 32768, (size_t)(bid * 8 + u) * 32 + b, hv, t + 1);
        st_pair(HTT2 + (t & 1) * 32768, (size_t)b * 512 + bid * 8 + u, hv, t + 1);
      }
      if (t < 249) azX(t + 1);
    }
  } else if (bid < 80) {                // AO
    int cCCO = 0;
    for (int t = 1; t <= 250; ++t) {
      if (t >= 2) waitC(CCO, 8 * (t - 1), cCCO); // OUTPRE WAR: COUT_{t-1} done
      aoOut(t);                                  // RAW rv/OH via tags
      bumpC(COP);
    }
  } else if (bid < 144) {               // ZH: E64 k-half partial of h@Wh
    const int r = bid - 80;
    const int j0 = (r & 31) * 64, kh = r >> 5;
    const int c = tid & 63, b4 = (tid >> 6) * 4;
    float* W = dyn; float* A = dyn + 16384; float* part = dyn + 25600;
    float* zpBase = kh ? ZP2B : ZP2A;
    const float blv = (kh == 0) ? BLI[j0 + c] : 0.f;
    for (int s = 0; s < 250; ++s) {
      float wx0 = 0.f, wx1 = 0.f, wx2 = 0.f, wx3 = 0.f;
      if (kh == 0) {     // label-row prefetch (input-dependent only)
        int l0 = labels[(b4 + 0) * 250 + s], l1 = labels[(b4 + 1) * 250 + s];
        int l2 = labels[(b4 + 2) * 250 + s], l3 = labels[(b4 + 3) * 250 + s];
        wx0 = WXI[(size_t)(128 + l0) * 2048 + j0 + c];
        wx1 = WXI[(size_t)(128 + l1) * 2048 + j0 + c];
        wx2 = WXI[(size_t)(128 + l2) * 2048 + j0 + c];
        wx3 = WXI[(size_t)(128 + l3) * 2048 + j0 + c];
      }
      stageP(A, HT2 + ((s + 1) & 1) * 32768 + kh * 16384, s);  // h_{s-1} half
      __syncthreads();
      float4 rr;
      E64(W, A, part, rr);
      float* zpD = zpBase + (s & 1) * 131072;
      st_pair(zpD, (size_t)(b4 + 0) * 2048 + j0 + c, rr.x + blv + wx0, s + 1);
      st_pair(zpD, (size_t)(b4 + 1) * 2048 + j0 + c, rr.y + blv + wx1, s + 1);
      st_pair(zpD, (size_t)(b4 + 2) * 2048 + j0 + c, rr.z + blv + wx2, s + 1);
      st_pair(zpD, (size_t)(b4 + 3) * 2048 + j0 + c, rr.w + blv + wx3, s + 1);
    }
  } else if (bid < 176) {               // OL / OHI
    int cCOP = 0;
    for (int t = 0; t < 250; ++t) {
      if (t >= 2) waitC(COP, 16 * (t - 1), cCOP);// OH WAR: AO_{t-1} read done
      p2Gemm(t);                                 // RAW h_t via tags
      bumpC(COH);
    }
  } else if (bid < 240) {               // ATT: keys + attention + rv
    float* ring = dyn;
    float* rn   = dyn + 17000;
    float* h_s  = dyn + 17256;
    float* kpart= dyn + 17768;
    float* kn   = dyn + 18408;
    float* att  = dyn + 18536;
    float* redS = dyn + 19068;
    float* pslab= dyn + 19088;
    float* bpk  = dyn + 21264;
    float* bpw  = dyn + 21392;
    const int b = (bid - 176) >> 1, hp = (bid - 176) & 1;
    const int j = tid & 127, q = tid >> 7;
    const int J = 64 + hp * 128 + j;
    const fv4* wbase = (const fv4*)WPT + q * 32 * 320 + J;
    int cCOP = 0;
    for (int t = 0; t < 250; ++t) {
      // prefetch HALF this thread's Wp chunk; keep-alive asm pins the loads
      // BEFORE the spin so the compiler cannot sink them past it.
      fv4 pf[16];
      #pragma unroll
      for (int i = 0; i < 16; ++i) pf[i] = wbase[i * 320];
      asm volatile("" :: "v"(pf[0]), "v"(pf[1]), "v"(pf[2]), "v"(pf[3]),
                         "v"(pf[4]), "v"(pf[5]), "v"(pf[6]), "v"(pf[7]),
                         "v"(pf[8]), "v"(pf[9]), "v"(pf[10]), "v"(pf[11]),
                         "v"(pf[12]), "v"(pf[13]), "v"(pf[14]), "v"(pf[15]));
      if (t >= 2) waitC(COP, 16 * (t - 1), cCOP);// RVT WAR: AO_{t-1} read done
      h_s[tid] = spin_pair(HTT2 + (t & 1) * 32768, (size_t)b * 512 + tid, t + 1);
      __syncthreads();
      {  // key GEMM: half from registers, half streamed from L2/LLC
        float a = 0.f;
        #pragma unroll
        for (int i = 0; i < 16; ++i) {
          fv4 h4 = *(const fv4*)&h_s[q * 128 + i * 4];
          a += pf[i].x * h4.x + pf[i].y * h4.y + pf[i].z * h4.z + pf[i].w * h4.w;
        }
        #pragma unroll 4
        for (int i = 16; i < 32; ++i) {
          fv4 w4 = wbase[i * 320];
          fv4 h4 = *(const fv4*)&h_s[q * 128 + i * 4];
          a += w4.x * h4.x + w4.y * h4.y + w4.z * h4.z + w4.w * h4.w;
        }
        kpart[q * 128 + j] = a;
      }
      __syncthreads();
      if (tid < 128) {  // fused reduce + tanh + per-head L2 norm (wave-local)
        float kr = kpart[tid] + kpart[128 + tid] + kpart[256 + tid] +
                   kpart[384 + tid] + bpk[tid];
        float v = tanhf(kr);
        float pq = v * v;
        #pragma unroll
        for (int off = 32; off; off >>= 1) pq += __shfl_xor(pq, off, 64);
        kn[tid] = v * rsqrtf(fmaxf(pq, 1e-12f));
      }
      __syncthreads();
      const int start = 250 - t;          // live cells: m < t at p = start+m (no wrap)
      const int m = tid >> 1, hh = tid & 1;
      {  // dots + exp. Dead cells (t <= m < 250) are zero vectors -> e = 1
         // exactly (cosine score 0), no dot needed.
        float e = 0.f;
        if (m < t) {
          const float4* c4 = (const float4*)ring + (start + m) * 17;
          const float4* k4 = (const float4*)kn + hh * 16;
          float d = 0.f;
          #pragma unroll
          for (int s4 = 0; s4 < 16; ++s4) {
            float4 cc = c4[s4], kk = k4[s4];
            d += cc.x * kk.x + cc.y * kk.y + cc.z * kk.z + cc.w * kk.w;
          }
          e = __expf(d * rn[start + m]);
          att[hh * 256 + m] = e;
        } else if (m < 250) {
          e = 1.f;
        }
        float sm = e;
        #pragma unroll
        for (int off = 2; off <= 32; off <<= 1) sm += __shfl_xor(sm, off, 64);
        if ((tid & 63) < 2) redS[(tid >> 6) * 2 + (tid & 1)] = sm;
      }
      __syncthreads();
      {  // weighted sum over LIVE cells only (dead cells contribute 0)
        int hh2 = tid >> 8, s4 = (tid >> 4) & 15, g = tid & 15;
        float4 a4 = {0.f, 0.f, 0.f, 0.f};
        for (int mm = g; mm < t; mm += 16) {
          float w = att[hh2 * 256 + mm];
          float4 cc = ((const float4*)ring)[(start + mm) * 17 + s4];
          a4.x = fmaf(w, cc.x, a4.x); a4.y = fmaf(w, cc.y, a4.y);
          a4.z = fmaf(w, cc.z, a4.z); a4.w = fmaf(w, cc.w, a4.w);
        }
        *(float4*)&pslab[(hh2 * 16 + s4) * 68 + g * 4] = a4;
      }
      __syncthreads();
      if (tid < 128) {
        int hh3 = tid >> 6, s = tid & 63;
        float denom = redS[hh3];
        #pragma unroll
        for (int w = 1; w < 8; ++w) denom += redS[w * 2 + hh3];
        float sum = 0.f;
        #pragma unroll
        for (int g = 0; g < 16; ++g)
          sum += pslab[(hh3 * 16 + (s >> 2)) * 68 + g * 4 + (s & 3)];
        st_pair(RVT2 + (t & 1) * 16384,
                (size_t)((2 * hp + hh3) * 64 + s) * 32 + b, sum / denom, t + 1);
      }
      __syncthreads();                            // ring readers done before update
      {  // ring update with wv_t (tags; off critical path)
        const int ip = 249 - t;
        if (tid < 64) {
          float2 p01 = spin_pair_2addr(
              WVP2 + (t & 1) * 8192 + 2 * ((size_t)b * 64 + tid),
              WVP2 + (t & 1) * 8192 + 4096 + 2 * ((size_t)b * 64 + tid), t + 1);
          float nv = tanhf(p01.x + p01.y + bpw[tid]);
          ring[ip * 68 + tid] = nv;
          float n2 = nv * nv;
          #pragma unroll
          for (int off = 32; off; off >>= 1) n2 += __shfl_xor(n2, off, 64);
          if (tid == 0) rn[ip] = rsqrtf(fmaxf(n2, 1e-12f));
        }
      }
      bumpC(CRING);
    }
  } else if (bid < 244) {               // WV: wv partials
    // dyn: W[0,8192) A[8192,17408) part[17408,22016)
    const int kh = (bid - 240) >> 1, cp = (bid - 240) & 1;
    float* W = dyn; float* A = dyn + 8192; float* part = dyn + 17408;
    int cCR = 0;
    for (int t = 0; t < 250; ++t) {
      if (t >= 2) waitC(CRING, 64 * (t - 1), cCR);// WVP WAR: ring-update done
      stageP(A, HT2 + (t & 1) * 32768 + kh * 16384, t + 1);  // RAW h_t via tags
      __syncthreads();
      float2 r;
      E32(W, A, 256, part, r);
      const int c = tid & 31, b2 = (tid >> 5) * 2;
      float* d = WVP2 + (t & 1) * 8192 + kh * 4096;
      st_pair(d, (size_t)b2 * 64 + cp * 32 + c, r.x, t + 1);
      st_pair(d, (size_t)(b2 + 1) * 64 + cp * 32 + c, r.y, t + 1);
    }
  } else if (bid < 252) {               // COUT: 4 batches, one quad spin per step
    const int b0 = (bid - 244) * 4;
    float* WfL = dyn; float* bfL = dyn + 12800;
    float* to4 = dyn + 12832;           // [4][512]
    float* lp  = dyn + 14880;           // [400]
    float* lg  = dyn + 15280;           // [27]
    for (int t = 1; t <= 250; ++t) {
      {
        const iv2* p0 = (const iv2*)(OUTPRE2 + 2 * ((size_t)(b0 + 0) * 512 + tid));
        const iv2* p1 = (const iv2*)(OUTPRE2 + 2 * ((size_t)(b0 + 1) * 512 + tid));
        const iv2* p2 = (const iv2*)(OUTPRE2 + 2 * ((size_t)(b0 + 2) * 512 + tid));
        const iv2* p3 = (const iv2*)(OUTPRE2 + 2 * ((size_t)(b0 + 3) * 512 + tid));
        iv2 v0, v1, v2, v3;
        for (;;) {
          ld4x2_sc(p0, p1, p2, p3, v0, v1, v2, v3);
          if (v0[1] == t && v1[1] == t && v2[1] == t && v3[1] == t) break;
          __builtin_amdgcn_s_sleep(2);
        }
        to4[tid]        = tanhf(__int_as_float(v0[0]));
        to4[512 + tid]  = tanhf(__int_as_float(v1[0]));
        to4[1024 + tid] = tanhf(__int_as_float(v2[0]));
        to4[1536 + tid] = tanhf(__int_as_float(v3[0]));
      }
      __syncthreads();
      for (int i = 0; i < 4; ++i) {
        float* to = to4 + i * 512;
        if (tid < 400) {
          int l = tid % 25, p = tid / 25;
          float s = 0.f;
          #pragma unroll
          for (int q = 0; q < 32; ++q) { int k = p * 32 + q; s += to[k] * WfL[k * 25 + l]; }
          lp[p * 25 + l] = s;
        }
        __syncthreads();
        if (tid < 25) {
          float s = bfL[tid];
          #pragma unroll
          for (int p = 0; p < 16; ++p) s += lp[p * 25 + tid];
          lg[tid] = s;
        }
        __syncthreads();
        if (tid == 0) {
          float mx = lg[0];
          for (int l = 1; l < 25; ++l) mx = fmaxf(mx, lg[l]);
          float ss = 0.f;
          for (int l = 0; l < 25; ++l) ss += __expf(lg[l] - mx);
          lg[25] = mx; lg[26] = 1.f / ss;
        }
        __syncthreads();
        if (tid < 25)
          out[((size_t)(b0 + i) * 250 + (t - 1)) * 25 + tid] =
              __expf(lg[tid] - lg[25]) * lg[26];
        __syncthreads();
      }
      bumpC(CCO);
    }
  }
}

extern "C" void kernel_launch(void* const* d_in, const int* in_sizes, int n_in,
                              void* d_out, int out_size, void* d_ws, size_t ws_size,
                              hipStream_t stream) {
  const float* images = (const float*)d_in[0];
  const int* labels = (const int*)d_in[1];
  const float* k1  = (const float*)d_in[2];
  const float* cb1 = (const float*)d_in[3];
  const float* g1  = (const float*)d_in[4];
  const float* be1 = (const float*)d_in[5];
  const float* mm1 = (const float*)d_in[6];
  const float* mv1 = (const float*)d_in[7];
  const float* k2  = (const float*)d_in[8];
  const float* cb2 = (const float*)d_in[9];
  const float* g2  = (const float*)d_in[10];
  const float* be2 = (const float*)d_in[11];
  const float* mm2 = (const float*)d_in[12];
  const float* mv2 = (const float*)d_in[13];
  const float* k3  = (const float*)d_in[14];
  const float* cb3 = (const float*)d_in[15];
  const float* g3  = (const float*)d_in[16];
  const float* be3 = (const float*)d_in[17];
  const float* mm3 = (const float*)d_in[18];
  const float* mv3 = (const float*)d_in[19];
  const float* Wx  = (const float*)d_in[20];
  const float* Wh  = (const float*)d_in[21];
  const float* bl  = (const float*)d_in[22];
  const float* Wp  = (const float*)d_in[23];
  const float* bp  = (const float*)d_in[24];
  const float* Wo  = (const float*)d_in[25];
  const float* bo  = (const float*)d_in[26];
  const float* Wf  = (const float*)d_in[27];
  const float* bf  = (const float*)d_in[28];
  float* ws = (float*)d_ws;

  hipFuncSetAttribute((const void*)lstm_kernel,
                      hipFuncAttributeMaxDynamicSharedMemorySize, DYN_BYTES);

  // zero all pair buffers + counters (tags -> 0 = step-0 zero state)
  hipMemsetAsync((char*)d_ws + OFF_ZP2A * sizeof(float), 0,
                 (OFF_WPT - OFF_ZP2A) * sizeof(float), stream);
  prep_kernel<<<1024, 256, 0, stream>>>(Wx, Wh, bl, Wp, ws);
  conv_kernel<<<8000, 128, 0, stream>>>(images,
      k1, cb1, g1, be1, mm1, mv1,
      k2, cb2, g2, be2, mm2, mv2,
      k3, cb3, g3, be3, mm3, mv3, ws);
  lstm_kernel<<<256, 512, DYN_BYTES, stream>>>(labels, Wo, bo, Wp, bp, Wf, bf, ws,
                                               (float*)d_out);
}